// Round 1
// baseline (4255.823 us; speedup 1.0000x reference)
//
#include <hip/hip_runtime.h>
#include <hip/hip_bf16.h>

// Problem constants
#define BB 64
#define SS 512
#define DD 128
#define NROW (BB * SS)          // 32768
#define SZ ((size_t)NROW * DD)  // 4,194,304 floats per [B,S,128] buffer

__device__ __forceinline__ float sigmoidf_(float x) { return 1.f / (1.f + __expf(-x)); }
__device__ __forceinline__ float tanhf_(float x) {
  x = fminf(fmaxf(x, -15.f), 15.f);
  float e = __expf(2.f * x);
  return (e - 1.f) / (e + 1.f);
}

// ---------------------------------------------------------------------------
// Generic tiled GEMM: C[M,N] = A[M,K] @ W + bias.  W is [K,N] (wtrans=0) or
// [N,K] accessed transposed (wtrans=1).  Output fp32 (Cf) or bf16 (Cb).
// grid = (M/64, N/64), block = 256.  M % 64 == 0, N % 64 == 0, K arbitrary.
// ---------------------------------------------------------------------------
__global__ __launch_bounds__(256) void gemm64(
    const float* __restrict__ A, const float* __restrict__ W,
    const float* __restrict__ bias, float* __restrict__ Cf,
    __hip_bfloat16* __restrict__ Cb, int K, int N, int wtrans) {
  __shared__ float As[16][68];
  __shared__ float Ws[16][68];
  const int t = threadIdx.x;
  const int m0 = blockIdx.x * 64, n0 = blockIdx.y * 64;
  const int tx = t & 15, ty = t >> 4;
  float acc[4][4] = {{0.f, 0.f, 0.f, 0.f}, {0.f, 0.f, 0.f, 0.f},
                     {0.f, 0.f, 0.f, 0.f}, {0.f, 0.f, 0.f, 0.f}};
  for (int k0 = 0; k0 < K; k0 += 16) {
#pragma unroll
    for (int i = 0; i < 4; ++i) {
      int idx = t + i * 256;
      int m = idx >> 4, kk = idx & 15;
      int kg = k0 + kk;
      As[kk][m] = (kg < K) ? A[(size_t)(m0 + m) * K + kg] : 0.f;
    }
#pragma unroll
    for (int i = 0; i < 4; ++i) {
      int idx = t + i * 256;
      int kk = idx >> 6, n = idx & 63;
      int kg = k0 + kk;
      float w = 0.f;
      if (kg < K)
        w = wtrans ? W[(size_t)(n0 + n) * K + kg] : W[(size_t)kg * N + (n0 + n)];
      Ws[kk][n] = w;
    }
    __syncthreads();
#pragma unroll
    for (int kk = 0; kk < 16; ++kk) {
      float4 av = *reinterpret_cast<const float4*>(&As[kk][ty * 4]);
      float4 wv = *reinterpret_cast<const float4*>(&Ws[kk][tx * 4]);
      float am[4] = {av.x, av.y, av.z, av.w};
      float wn[4] = {wv.x, wv.y, wv.z, wv.w};
#pragma unroll
      for (int i = 0; i < 4; ++i)
#pragma unroll
        for (int j = 0; j < 4; ++j) acc[i][j] += am[i] * wn[j];
    }
    __syncthreads();
  }
#pragma unroll
  for (int i = 0; i < 4; ++i) {
    int m = m0 + ty * 4 + i;
    int n = n0 + tx * 4;
#pragma unroll
    for (int j = 0; j < 4; ++j) {
      float v = acc[i][j] + bias[n + j];
      if (Cb)
        Cb[(size_t)m * N + n + j] = __float2bfloat16(v);
      else
        Cf[(size_t)m * N + n + j] = v;
    }
  }
}

// ---------------------------------------------------------------------------
// V column sums per (b): VS[b][128] = sum_s V[b][s][:]
// grid = 64, block = 128
// ---------------------------------------------------------------------------
__global__ __launch_bounds__(128) void vsum_kernel(const float* __restrict__ V,
                                                   float* __restrict__ VS) {
  int b = blockIdx.x, d = threadIdx.x;
  const float* p = V + (size_t)b * SS * DD + d;
  float s = 0.f;
  for (int k = 0; k < SS; ++k) s += p[(size_t)k * DD];
  VS[b * DD + d] = s;
}

// ---------------------------------------------------------------------------
// Attention with probs = 1 - softmax:  ctx = Vsum - softmax(QK^T/8) @ V
// grid = (8 qtiles, 128 = b*2+h), block = 256.
// Thread t: query row qr = t>>2 (64 rows), dim group d0 = (t&3)*16 (16 dims).
// Scores: thread computes kc = j*4 + (t&3), j<16 (bank-conflict-free reads).
// No max subtraction: |scores| < ~3 for this data scale (weights are 0.05x).
// ---------------------------------------------------------------------------
__global__ __launch_bounds__(256) void attn64(
    const float* __restrict__ Q, const float* __restrict__ Kb,
    const float* __restrict__ Vb, const float* __restrict__ VS,
    float* __restrict__ CTX) {
  __shared__ float Kt[64][68];
  __shared__ float Vt[64][68];
  __shared__ float St[64][65];
  const int t = threadIdx.x;
  const int bh = blockIdx.y, b = bh >> 1, h = bh & 1;
  const int q0 = blockIdx.x * 64;
  const int qr = t >> 2, g4 = t & 3, d0 = g4 * 16;
  const float* qp = Q + ((size_t)(b * SS + q0 + qr)) * DD + h * 64;
  float qreg[64];
#pragma unroll
  for (int i = 0; i < 16; ++i) {
    float4 f = *reinterpret_cast<const float4*>(qp + i * 4);
    qreg[i * 4] = f.x; qreg[i * 4 + 1] = f.y;
    qreg[i * 4 + 2] = f.z; qreg[i * 4 + 3] = f.w;
  }
  const float* Kg = Kb + (size_t)b * SS * DD + h * 64;
  const float* Vg = Vb + (size_t)b * SS * DD + h * 64;
  float o[16];
#pragma unroll
  for (int i = 0; i < 16; ++i) o[i] = 0.f;
  float l = 0.f;
  for (int kt = 0; kt < 8; ++kt) {
    const int k0 = kt * 64;
    __syncthreads();
#pragma unroll
    for (int i = 0; i < 4; ++i) {
      int idx = t + i * 256;
      int row = idx >> 4, c4 = (idx & 15) * 4;
      *reinterpret_cast<float4*>(&Kt[row][c4]) =
          *reinterpret_cast<const float4*>(Kg + (size_t)(k0 + row) * DD + c4);
      *reinterpret_cast<float4*>(&Vt[row][c4]) =
          *reinterpret_cast<const float4*>(Vg + (size_t)(k0 + row) * DD + c4);
    }
    __syncthreads();
    float sv[16];
#pragma unroll
    for (int j = 0; j < 16; ++j) sv[j] = 0.f;
#pragma unroll
    for (int ch = 0; ch < 16; ++ch) {
      const float qa = qreg[ch * 4], qb = qreg[ch * 4 + 1];
      const float qc = qreg[ch * 4 + 2], qd = qreg[ch * 4 + 3];
#pragma unroll
      for (int j = 0; j < 16; ++j) {
        float4 kv = *reinterpret_cast<const float4*>(&Kt[j * 4 + g4][ch * 4]);
        sv[j] += qa * kv.x + qb * kv.y + qc * kv.z + qd * kv.w;
      }
    }
#pragma unroll
    for (int j = 0; j < 16; ++j) St[qr][j * 4 + g4] = sv[j] * 0.125f;
    __syncthreads();
#pragma unroll 4
    for (int k = 0; k < 64; ++k) {
      float p = __expf(St[qr][k]);
      l += p;
      float4 v0 = *reinterpret_cast<const float4*>(&Vt[k][d0]);
      float4 v1 = *reinterpret_cast<const float4*>(&Vt[k][d0 + 4]);
      float4 v2 = *reinterpret_cast<const float4*>(&Vt[k][d0 + 8]);
      float4 v3 = *reinterpret_cast<const float4*>(&Vt[k][d0 + 12]);
      o[0] += p * v0.x;  o[1] += p * v0.y;  o[2] += p * v0.z;  o[3] += p * v0.w;
      o[4] += p * v1.x;  o[5] += p * v1.y;  o[6] += p * v1.z;  o[7] += p * v1.w;
      o[8] += p * v2.x;  o[9] += p * v2.y;  o[10] += p * v2.z; o[11] += p * v2.w;
      o[12] += p * v3.x; o[13] += p * v3.y; o[14] += p * v3.z; o[15] += p * v3.w;
    }
  }
  float invl = 1.f / l;
  float* cp = CTX + ((size_t)(b * SS + q0 + qr)) * DD + h * 64 + d0;
  const float* vsp = VS + b * DD + h * 64 + d0;
#pragma unroll
  for (int i = 0; i < 4; ++i) {
    float4 r;
    r.x = vsp[i * 4 + 0] - o[i * 4 + 0] * invl;
    r.y = vsp[i * 4 + 1] - o[i * 4 + 1] * invl;
    r.z = vsp[i * 4 + 2] - o[i * 4 + 2] * invl;
    r.w = vsp[i * 4 + 3] - o[i * 4 + 3] * invl;
    *reinterpret_cast<float4*>(cp + i * 4) = r;
  }
}

// ---------------------------------------------------------------------------
// LayerNorm over 128 dims then OUT += 0.5 * LN(x).  grid = 32768, block = 64.
// ---------------------------------------------------------------------------
__global__ __launch_bounds__(64) void ln_add64(const float* __restrict__ X,
                                               const float* __restrict__ g,
                                               const float* __restrict__ lb,
                                               float* __restrict__ OUT) {
  const int row = blockIdx.x, t = threadIdx.x;
  const float* x = X + (size_t)row * DD;
  float a = x[t], c = x[t + 64];
  float s = a + c, sq = a * a + c * c;
#pragma unroll
  for (int off = 32; off > 0; off >>= 1) {
    s += __shfl_down(s, off);
    sq += __shfl_down(sq, off);
  }
  s = __shfl(s, 0);
  sq = __shfl(sq, 0);
  float mean = s * (1.f / 128.f);
  float var = sq * (1.f / 128.f) - mean * mean;
  float rs = rsqrtf(var + 1e-5f);
  float* op = OUT + (size_t)row * DD;
  op[t] += 0.5f * ((a - mean) * rs * g[t] + lb[t]);
  op[t + 64] += 0.5f * ((c - mean) * rs * g[t + 64] + lb[t + 64]);
}

// ---------------------------------------------------------------------------
// GRU recurrence.  grid = (64 batch, 6 rec), block = 384.
// rec = gru*2 + dir.  Thread o holds Whh row o (128 fp32) in VGPRs.
// h lives in LDS (broadcast ds_read_b128 in the dot).  gx precomputed (bf16).
// Output hidden states written bf16 into G[gru][b][t][dir*128 + d].
// ---------------------------------------------------------------------------
__global__ __launch_bounds__(384) void gru_kernel(
    const __hip_bfloat16* __restrict__ GX, const float* __restrict__ Whh,
    const float* __restrict__ bhh, __hip_bfloat16* __restrict__ G) {
  __shared__ float hL[128];
  __shared__ float ghL[384];
  const int b = blockIdx.x, rec = blockIdx.y;
  const int g = rec >> 1, dir = rec & 1;
  const int o = threadIdx.x;
  float w[128];
  const float4* wp =
      reinterpret_cast<const float4*>(Whh + ((size_t)rec * 384 + o) * 128);
#pragma unroll
  for (int i = 0; i < 32; ++i) {
    float4 f = wp[i];
    w[i * 4] = f.x; w[i * 4 + 1] = f.y; w[i * 4 + 2] = f.z; w[i * 4 + 3] = f.w;
  }
  const float bh = bhh[rec * 384 + o];
  if (o < 128) hL[o] = 0.f;
  const __hip_bfloat16* gxb = GX + ((size_t)rec * BB + b) * SS * 384;
  __hip_bfloat16* gb = G + ((size_t)g * BB + b) * SS * 256 + dir * 128;
  const float4* h4 = reinterpret_cast<const float4*>(hL);
  for (int s = 0; s < SS; ++s) {
    const int tt = dir ? (SS - 1 - s) : s;
    __syncthreads();  // h ready
    float acc = bh;
#pragma unroll
    for (int i = 0; i < 32; ++i) {
      float4 hv = h4[i];
      acc += w[i * 4] * hv.x + w[i * 4 + 1] * hv.y + w[i * 4 + 2] * hv.z +
             w[i * 4 + 3] * hv.w;
    }
    ghL[o] = acc;
    __syncthreads();  // gh ready; all h reads done
    if (o < 128) {
      const __hip_bfloat16* gx = gxb + (size_t)tt * 384;
      float xr = __bfloat162float(gx[o]);
      float xz = __bfloat162float(gx[128 + o]);
      float xn = __bfloat162float(gx[256 + o]);
      float r = sigmoidf_(xr + ghL[o]);
      float z = sigmoidf_(xz + ghL[128 + o]);
      float n = tanhf_(xn + r * ghL[256 + o]);
      float hnew = (1.f - z) * n + z * hL[o];
      hL[o] = hnew;
      gb[(size_t)tt * 256 + o] = __float2bfloat16(hnew);
    }
  }
}

// ---------------------------------------------------------------------------
// pooled[b][j] = mean_t (cat[b,t,j] + cat[b,t,j+384]) / 2,  cat = [g0|g1|g2].
// grid = 64, block = 384.
// ---------------------------------------------------------------------------
__global__ __launch_bounds__(384) void pool_kernel(
    const __hip_bfloat16* __restrict__ G, float* __restrict__ P) {
  int b = blockIdx.x, j = threadIdx.x;
  int g1 = j >> 8, c1 = j & 255;
  int jr = j + 384;
  int g2 = jr >> 8, c2 = jr & 255;
  const __hip_bfloat16* p1 = G + ((size_t)(g1 * BB + b) * SS) * 256 + c1;
  const __hip_bfloat16* p2 = G + ((size_t)(g2 * BB + b) * SS) * 256 + c2;
  float s = 0.f;
  for (int tstep = 0; tstep < SS; ++tstep)
    s += __bfloat162float(p1[(size_t)tstep * 256]) +
         __bfloat162float(p2[(size_t)tstep * 256]);
  P[b * 384 + j] = s * (0.5f / 512.f);
}

// ---------------------------------------------------------------------------
// Head: h = clip( (pooled@fW1+fb1) * rsqrt(1+eps) * bn_g + bn_b, 0, 6 );
//       out = h @ fW2 + fb2.   grid = 64, block = 256.
// ---------------------------------------------------------------------------
__global__ __launch_bounds__(256) void head_kernel(
    const float* __restrict__ P, const float* __restrict__ fW1,
    const float* __restrict__ fb1, const float* __restrict__ bng,
    const float* __restrict__ bnb, const float* __restrict__ fW2,
    const float* __restrict__ fb2, float* __restrict__ out) {
  __shared__ float pl[384];
  __shared__ float h1[256];
  int b = blockIdx.x, n = threadIdx.x;
  pl[n] = P[b * 384 + n];
  if (n < 128) pl[256 + n] = P[b * 384 + 256 + n];
  __syncthreads();
  float acc = fb1[n];
  for (int k = 0; k < 384; ++k) acc += pl[k] * fW1[k * 256 + n];
  float hv = acc * rsqrtf(1.f + 1e-5f) * bng[n] + bnb[n];
  hv = fminf(fmaxf(hv, 0.f), 6.f);
  h1[n] = hv;
  __syncthreads();
  if (n < 8) {
    float a2 = fb2[n];
    for (int k = 0; k < 256; ++k) a2 += h1[k] * fW2[k * 8 + n];
    out[b * 8 + n] = a2;
  }
}

// ---------------------------------------------------------------------------
extern "C" void kernel_launch(void* const* d_in, const int* in_sizes, int n_in,
                              void* d_out, int out_size, void* d_ws,
                              size_t ws_size, hipStream_t stream) {
  (void)in_sizes; (void)n_in; (void)out_size; (void)ws_size;
  const float* text = (const float*)d_in[0];
  const float* vis  = (const float*)d_in[1];
  const float* aud  = (const float*)d_in[2];
  const float* fc1W = (const float*)d_in[3];
  const float* fc1b = (const float*)d_in[4];
  const float* fc2W = (const float*)d_in[5];
  const float* fc2b = (const float*)d_in[6];
  const float* fc3W = (const float*)d_in[7];
  const float* fc3b = (const float*)d_in[8];
  const float* Wq = (const float*)d_in[9];
  const float* bq = (const float*)d_in[10];
  const float* Wk = (const float*)d_in[11];
  const float* bk = (const float*)d_in[12];
  const float* Wv = (const float*)d_in[13];
  const float* bv = (const float*)d_in[14];
  const float* Wd = (const float*)d_in[15];
  const float* bd = (const float*)d_in[16];
  const float* lng = (const float*)d_in[17];
  const float* lnb = (const float*)d_in[18];
  const float* gWih = (const float*)d_in[19];
  const float* gWhh = (const float*)d_in[20];
  const float* gbih = (const float*)d_in[21];
  const float* gbhh = (const float*)d_in[22];
  const float* fW1 = (const float*)d_in[23];
  const float* fb1 = (const float*)d_in[24];
  const float* bng = (const float*)d_in[25];
  const float* bnb = (const float*)d_in[26];
  const float* fW2 = (const float*)d_in[27];
  const float* fb2 = (const float*)d_in[28];
  float* out = (float*)d_out;

  // Workspace layout (bytes):
  //   [0, 160 MB)  : phase A/B fp32 buffers (8*SZ + vsum = 134.3 MB)
  //                  later overlaid by GX bf16 [6][32768][384] (151 MB)
  //   [160, +48MB) : GRUIN fp32 [3][32768][128]; later overlaid by G bf16
  //   then         : POOLED [64][384] fp32
  float* ws = (float*)d_ws;
  float* T    = ws;
  float* Vv   = ws + SZ;
  float* Aa   = ws + 2 * SZ;
  float* Qb   = ws + 3 * SZ;
  float* Kb_  = ws + 4 * SZ;
  float* Vb_  = ws + 5 * SZ;
  float* CTX  = ws + 6 * SZ;
  float* DOUT = ws + 7 * SZ;
  float* VSUM = ws + 8 * SZ;  // 8192 floats
  __hip_bfloat16* GX = (__hip_bfloat16*)d_ws;  // phase C overlay
  char* base2 = (char*)d_ws + (size_t)160 * 1024 * 1024;
  float* GRUIN = (float*)base2;                 // 3*SZ floats
  __hip_bfloat16* G = (__hip_bfloat16*)base2;   // phase D overlay (same size)
  float* POOLED = (float*)(base2 + 3 * SZ * sizeof(float));

  hipMemsetAsync(GRUIN, 0, 3 * SZ * sizeof(float), stream);

  dim3 blk(256);
  // Input projections
  gemm64<<<dim3(NROW / 64, 2), blk, 0, stream>>>(text, fc1W, fc1b, T, nullptr, 300, 128, 0);
  gemm64<<<dim3(NROW / 64, 2), blk, 0, stream>>>(vis,  fc2W, fc2b, Vv, nullptr, 35, 128, 0);
  gemm64<<<dim3(NROW / 64, 2), blk, 0, stream>>>(aud,  fc3W, fc3b, Aa, nullptr, 74, 128, 0);

  const float* qin[6]  = {T, Aa, T, Vv, Vv, Aa};
  const float* kvin[6] = {Aa, T, Vv, T, Aa, Vv};
  const int tgt[6] = {2, 0, 1, 0, 2, 1};  // audio, text, visual, text, audio, visual

  for (int u = 0; u < 6; ++u) {
    const size_t wo = (size_t)u * 128 * 128;
    const size_t bo = (size_t)u * 128;
    gemm64<<<dim3(NROW / 64, 2), blk, 0, stream>>>(qin[u],  Wq + wo, bq + bo, Qb,  nullptr, 128, 128, 0);
    gemm64<<<dim3(NROW / 64, 2), blk, 0, stream>>>(kvin[u], Wk + wo, bk + bo, Kb_, nullptr, 128, 128, 0);
    gemm64<<<dim3(NROW / 64, 2), blk, 0, stream>>>(kvin[u], Wv + wo, bv + bo, Vb_, nullptr, 128, 128, 0);
    vsum_kernel<<<dim3(BB), dim3(128), 0, stream>>>(Vb_, VSUM);
    attn64<<<dim3(8, 128), blk, 0, stream>>>(Qb, Kb_, Vb_, VSUM, CTX);
    gemm64<<<dim3(NROW / 64, 2), blk, 0, stream>>>(CTX, Wd + wo, bd + bo, DOUT, nullptr, 128, 128, 0);
    ln_add64<<<dim3(NROW), dim3(64), 0, stream>>>(DOUT, lng + bo, lnb + bo, GRUIN + (size_t)tgt[u] * SZ);
  }

  // gx = GRUIN[g] @ Wih[g][dir]^T + bih  -> bf16 [rec][32768][384]
  for (int r = 0; r < 6; ++r) {
    int g = r >> 1;
    gemm64<<<dim3(NROW / 64, 6), blk, 0, stream>>>(
        GRUIN + (size_t)g * SZ, gWih + (size_t)r * 384 * 128, gbih + (size_t)r * 384,
        nullptr, GX + (size_t)r * NROW * 384, 128, 384, 1);
  }

  gru_kernel<<<dim3(BB, 6), dim3(384), 0, stream>>>(GX, gWhh, gbhh, G);
  pool_kernel<<<dim3(BB), dim3(384), 0, stream>>>(G, POOLED);
  head_kernel<<<dim3(BB), dim3(256), 0, stream>>>(POOLED, fW1, fb1, bng, bnb, fW2, fb2, out);
}

// Round 2
// 3490.200 us; speedup vs baseline: 1.2194x; 1.2194x over previous
//
#include <hip/hip_runtime.h>
#include <hip/hip_bf16.h>

// Problem constants
#define BB 64
#define SS 512
#define DD 128
#define NROW (BB * SS)          // 32768
#define SZ ((size_t)NROW * DD)  // 4,194,304 floats per [B,S,128] buffer

typedef __attribute__((ext_vector_type(8))) short short8;
typedef __attribute__((ext_vector_type(4))) float f32x4;

__device__ __forceinline__ float sigmoidf_(float x) { return 1.f / (1.f + __expf(-x)); }
__device__ __forceinline__ float tanhf_(float x) {
  x = fminf(fmaxf(x, -15.f), 15.f);
  float e = __expf(2.f * x);
  return (e - 1.f) / (e + 1.f);
}
__device__ __forceinline__ short f2bf_s(float f) {
  __hip_bfloat16 b = __float2bfloat16(f);
  return *reinterpret_cast<short*>(&b);
}

// ---------------------------------------------------------------------------
// Generic tiled GEMM: C[M,N] = A[M,K] @ W + bias.  W is [K,N] (wtrans=0) or
// [N,K] accessed transposed (wtrans=1).  Output fp32 (Cf) or bf16 (Cb).
// grid = (M/64, N/64), block = 256.
// ---------------------------------------------------------------------------
__global__ __launch_bounds__(256) void gemm64(
    const float* __restrict__ A, const float* __restrict__ W,
    const float* __restrict__ bias, float* __restrict__ Cf,
    __hip_bfloat16* __restrict__ Cb, int K, int N, int wtrans) {
  __shared__ float As[16][68];
  __shared__ float Ws[16][68];
  const int t = threadIdx.x;
  const int m0 = blockIdx.x * 64, n0 = blockIdx.y * 64;
  const int tx = t & 15, ty = t >> 4;
  float acc[4][4] = {{0.f, 0.f, 0.f, 0.f}, {0.f, 0.f, 0.f, 0.f},
                     {0.f, 0.f, 0.f, 0.f}, {0.f, 0.f, 0.f, 0.f}};
  for (int k0 = 0; k0 < K; k0 += 16) {
#pragma unroll
    for (int i = 0; i < 4; ++i) {
      int idx = t + i * 256;
      int m = idx >> 4, kk = idx & 15;
      int kg = k0 + kk;
      As[kk][m] = (kg < K) ? A[(size_t)(m0 + m) * K + kg] : 0.f;
    }
#pragma unroll
    for (int i = 0; i < 4; ++i) {
      int idx = t + i * 256;
      int kk = idx >> 6, n = idx & 63;
      int kg = k0 + kk;
      float w = 0.f;
      if (kg < K)
        w = wtrans ? W[(size_t)(n0 + n) * K + kg] : W[(size_t)kg * N + (n0 + n)];
      Ws[kk][n] = w;
    }
    __syncthreads();
#pragma unroll
    for (int kk = 0; kk < 16; ++kk) {
      float4 av = *reinterpret_cast<const float4*>(&As[kk][ty * 4]);
      float4 wv = *reinterpret_cast<const float4*>(&Ws[kk][tx * 4]);
      float am[4] = {av.x, av.y, av.z, av.w};
      float wn[4] = {wv.x, wv.y, wv.z, wv.w};
#pragma unroll
      for (int i = 0; i < 4; ++i)
#pragma unroll
        for (int j = 0; j < 4; ++j) acc[i][j] += am[i] * wn[j];
    }
    __syncthreads();
  }
#pragma unroll
  for (int i = 0; i < 4; ++i) {
    int m = m0 + ty * 4 + i;
    int n = n0 + tx * 4;
#pragma unroll
    for (int j = 0; j < 4; ++j) {
      float v = acc[i][j] + bias[n + j];
      if (Cb)
        Cb[(size_t)m * N + n + j] = __float2bfloat16(v);
      else
        Cf[(size_t)m * N + n + j] = v;
    }
  }
}

// ---------------------------------------------------------------------------
// V column sums per (b): VS[b][128] = sum_s V[b][s][:]
// ---------------------------------------------------------------------------
__global__ __launch_bounds__(128) void vsum_kernel(const float* __restrict__ V,
                                                   float* __restrict__ VS) {
  int b = blockIdx.x, d = threadIdx.x;
  const float* p = V + (size_t)b * SS * DD + d;
  float s = 0.f;
  for (int k = 0; k < SS; ++k) s += p[(size_t)k * DD];
  VS[b * DD + d] = s;
}

// ---------------------------------------------------------------------------
// Attention with probs = 1 - softmax:  ctx = Vsum - softmax(QK^T/8) @ V
// grid = (8 qtiles, 128 = b*2+h), block = 256.
// ---------------------------------------------------------------------------
__global__ __launch_bounds__(256) void attn64(
    const float* __restrict__ Q, const float* __restrict__ Kb,
    const float* __restrict__ Vb, const float* __restrict__ VS,
    float* __restrict__ CTX) {
  __shared__ float Kt[64][68];
  __shared__ float Vt[64][68];
  __shared__ float St[64][65];
  const int t = threadIdx.x;
  const int bh = blockIdx.y, b = bh >> 1, h = bh & 1;
  const int q0 = blockIdx.x * 64;
  const int qr = t >> 2, g4 = t & 3, d0 = g4 * 16;
  const float* qp = Q + ((size_t)(b * SS + q0 + qr)) * DD + h * 64;
  float qreg[64];
#pragma unroll
  for (int i = 0; i < 16; ++i) {
    float4 f = *reinterpret_cast<const float4*>(qp + i * 4);
    qreg[i * 4] = f.x; qreg[i * 4 + 1] = f.y;
    qreg[i * 4 + 2] = f.z; qreg[i * 4 + 3] = f.w;
  }
  const float* Kg = Kb + (size_t)b * SS * DD + h * 64;
  const float* Vg = Vb + (size_t)b * SS * DD + h * 64;
  float o[16];
#pragma unroll
  for (int i = 0; i < 16; ++i) o[i] = 0.f;
  float l = 0.f;
  for (int kt = 0; kt < 8; ++kt) {
    const int k0 = kt * 64;
    __syncthreads();
#pragma unroll
    for (int i = 0; i < 4; ++i) {
      int idx = t + i * 256;
      int row = idx >> 4, c4 = (idx & 15) * 4;
      *reinterpret_cast<float4*>(&Kt[row][c4]) =
          *reinterpret_cast<const float4*>(Kg + (size_t)(k0 + row) * DD + c4);
      *reinterpret_cast<float4*>(&Vt[row][c4]) =
          *reinterpret_cast<const float4*>(Vg + (size_t)(k0 + row) * DD + c4);
    }
    __syncthreads();
    float sv[16];
#pragma unroll
    for (int j = 0; j < 16; ++j) sv[j] = 0.f;
#pragma unroll
    for (int ch = 0; ch < 16; ++ch) {
      const float qa = qreg[ch * 4], qb = qreg[ch * 4 + 1];
      const float qc = qreg[ch * 4 + 2], qd = qreg[ch * 4 + 3];
#pragma unroll
      for (int j = 0; j < 16; ++j) {
        float4 kv = *reinterpret_cast<const float4*>(&Kt[j * 4 + g4][ch * 4]);
        sv[j] += qa * kv.x + qb * kv.y + qc * kv.z + qd * kv.w;
      }
    }
#pragma unroll
    for (int j = 0; j < 16; ++j) St[qr][j * 4 + g4] = sv[j] * 0.125f;
    __syncthreads();
#pragma unroll 4
    for (int k = 0; k < 64; ++k) {
      float p = __expf(St[qr][k]);
      l += p;
      float4 v0 = *reinterpret_cast<const float4*>(&Vt[k][d0]);
      float4 v1 = *reinterpret_cast<const float4*>(&Vt[k][d0 + 4]);
      float4 v2 = *reinterpret_cast<const float4*>(&Vt[k][d0 + 8]);
      float4 v3 = *reinterpret_cast<const float4*>(&Vt[k][d0 + 12]);
      o[0] += p * v0.x;  o[1] += p * v0.y;  o[2] += p * v0.z;  o[3] += p * v0.w;
      o[4] += p * v1.x;  o[5] += p * v1.y;  o[6] += p * v1.z;  o[7] += p * v1.w;
      o[8] += p * v2.x;  o[9] += p * v2.y;  o[10] += p * v2.z; o[11] += p * v2.w;
      o[12] += p * v3.x; o[13] += p * v3.y; o[14] += p * v3.z; o[15] += p * v3.w;
    }
  }
  float invl = 1.f / l;
  float* cp = CTX + ((size_t)(b * SS + q0 + qr)) * DD + h * 64 + d0;
  const float* vsp = VS + b * DD + h * 64 + d0;
#pragma unroll
  for (int i = 0; i < 4; ++i) {
    float4 r;
    r.x = vsp[i * 4 + 0] - o[i * 4 + 0] * invl;
    r.y = vsp[i * 4 + 1] - o[i * 4 + 1] * invl;
    r.z = vsp[i * 4 + 2] - o[i * 4 + 2] * invl;
    r.w = vsp[i * 4 + 3] - o[i * 4 + 3] * invl;
    *reinterpret_cast<float4*>(cp + i * 4) = r;
  }
}

// ---------------------------------------------------------------------------
// LayerNorm over 128 dims then OUT += 0.5 * LN(x).  grid = 32768, block = 64.
// ---------------------------------------------------------------------------
__global__ __launch_bounds__(64) void ln_add64(const float* __restrict__ X,
                                               const float* __restrict__ g,
                                               const float* __restrict__ lb,
                                               float* __restrict__ OUT) {
  const int row = blockIdx.x, t = threadIdx.x;
  const float* x = X + (size_t)row * DD;
  float a = x[t], c = x[t + 64];
  float s = a + c, sq = a * a + c * c;
#pragma unroll
  for (int off = 32; off > 0; off >>= 1) {
    s += __shfl_down(s, off);
    sq += __shfl_down(sq, off);
  }
  s = __shfl(s, 0);
  sq = __shfl(sq, 0);
  float mean = s * (1.f / 128.f);
  float var = sq * (1.f / 128.f) - mean * mean;
  float rs = rsqrtf(var + 1e-5f);
  float* op = OUT + (size_t)row * DD;
  op[t] += 0.5f * ((a - mean) * rs * g[t] + lb[t]);
  op[t + 64] += 0.5f * ((c - mean) * rs * g[t + 64] + lb[t + 64]);
}

// ---------------------------------------------------------------------------
// GRU recurrence via per-step batched MFMA.
// grid = (4 batch-groups of 16, 6 recs), block = 512 (8 waves).
// Per step: GH[16,384] = bf16(H)[16,128] @ Whh^T + bhh via mfma 16x16x32.
// Wave w owns N-tiles {w, w+8, w+16} = (r,z,n) columns of hidden unit
// o = 16w + (lane&15)  -> gates computed fully in-register (C-frag layout:
// col=lane&15, row=quad*4+reg => lane handles batches m=quad*4+{0..3}).
// h fp32 persists in regs; bf16 copy double-buffered in LDS (1 barrier/step).
// Output: HS[rec][64][128] = sum_t h  (pooling folded in).
// ---------------------------------------------------------------------------
#define AST 136  // A-buf row stride in bf16 elems (128 + 8 pad)

__global__ __launch_bounds__(512) void gru_mfma(
    const __hip_bfloat16* __restrict__ GX, const float* __restrict__ Whh,
    const float* __restrict__ bhh, float* __restrict__ HS) {
  __shared__ __hip_bfloat16 Abuf[2][16 * AST];
  const int rec = blockIdx.y, bg = blockIdx.x;
  const int dir = rec & 1;
  const int t = threadIdx.x;
  const int w = t >> 6;
  const int lane = t & 63;
  const int q = lane >> 4, lm = lane & 15;
  const int q4 = q * 4;
  const int o = w * 16 + lm;  // hidden unit 0..127

  // Preload B fragments: B[k][n] = Whh[n][k], n = g*128 + o, k = c*32+q*8+j
  short8 Bf[3][4];
  const float* wbase = Whh + (size_t)rec * 384 * 128;
#pragma unroll
  for (int g = 0; g < 3; ++g)
#pragma unroll
    for (int c = 0; c < 4; ++c) {
      const float* wp = wbase + (size_t)(g * 128 + o) * 128 + c * 32 + q * 8;
      short8 s;
#pragma unroll
      for (int j = 0; j < 8; ++j) s[j] = f2bf_s(wp[j]);
      Bf[g][c] = s;
    }
  const float bhr = bhh[rec * 384 + o];
  const float bhz = bhh[rec * 384 + 128 + o];
  const float bhn = bhh[rec * 384 + 256 + o];

  float h[4] = {0.f, 0.f, 0.f, 0.f};
  float hsum[4] = {0.f, 0.f, 0.f, 0.f};
  for (int i = t; i < 16 * AST; i += 512) Abuf[0][i] = __float2bfloat16(0.f);

  const __hip_bfloat16* gxb = GX + ((size_t)rec * BB + bg * 16) * SS * 384;

  // gx prefetch registers (12 bf16: 4 batches x {r,z,n})
  __hip_bfloat16 cur[12], nxt[12];
  {
    const int tt0 = dir ? (SS - 1) : 0;
#pragma unroll
    for (int i = 0; i < 4; ++i) {
      const __hip_bfloat16* gp = gxb + ((size_t)(q4 + i) * SS + tt0) * 384;
      cur[i * 3 + 0] = gp[o];
      cur[i * 3 + 1] = gp[128 + o];
      cur[i * 3 + 2] = gp[256 + o];
    }
  }
  __syncthreads();

#pragma unroll 2
  for (int s = 0; s < SS; ++s) {
    const int p = s & 1;
    // prefetch gx for step s+1 (clamped)
    int tn = dir ? (SS - 2 - s) : (s + 1);
    tn = tn < 0 ? 0 : (tn > SS - 1 ? SS - 1 : tn);
#pragma unroll
    for (int i = 0; i < 4; ++i) {
      const __hip_bfloat16* gp = gxb + ((size_t)(q4 + i) * SS + tn) * 384;
      nxt[i * 3 + 0] = gp[o];
      nxt[i * 3 + 1] = gp[128 + o];
      nxt[i * 3 + 2] = gp[256 + o];
    }
    // GH = bf16(H) @ Whh^T + bhh
    f32x4 ar = {bhr, bhr, bhr, bhr};
    f32x4 az = {bhz, bhz, bhz, bhz};
    f32x4 an = {bhn, bhn, bhn, bhn};
#pragma unroll
    for (int c = 0; c < 4; ++c) {
      short8 a = *reinterpret_cast<const short8*>(&Abuf[p][lm * AST + c * 32 + q * 8]);
      ar = __builtin_amdgcn_mfma_f32_16x16x32_bf16(a, Bf[0][c], ar, 0, 0, 0);
      az = __builtin_amdgcn_mfma_f32_16x16x32_bf16(a, Bf[1][c], az, 0, 0, 0);
      an = __builtin_amdgcn_mfma_f32_16x16x32_bf16(a, Bf[2][c], an, 0, 0, 0);
    }
    // gates, fully in-register; write h_new bf16 to the other A buffer
#pragma unroll
    for (int i = 0; i < 4; ++i) {
      float xr = __bfloat162float(cur[i * 3 + 0]);
      float xz = __bfloat162float(cur[i * 3 + 1]);
      float xn = __bfloat162float(cur[i * 3 + 2]);
      float r = sigmoidf_(xr + ar[i]);
      float z = sigmoidf_(xz + az[i]);
      float nn = tanhf_(xn + r * an[i]);
      h[i] = (1.f - z) * nn + z * h[i];
      hsum[i] += h[i];
      Abuf[p ^ 1][(q4 + i) * AST + o] = __float2bfloat16(h[i]);
    }
#pragma unroll
    for (int i = 0; i < 12; ++i) cur[i] = nxt[i];
    __syncthreads();
  }
#pragma unroll
  for (int i = 0; i < 4; ++i)
    HS[((size_t)rec * BB + bg * 16 + q4 + i) * 128 + o] = hsum[i];
}

// ---------------------------------------------------------------------------
// Head with pooling folded in: pooled[b][j] = (HS[seg] + HS[seg+3]) * 0.5/512,
// seg = j>>7.  Then Linear -> BN(eval) -> ReLU6 -> Linear.  grid=64, block=256.
// ---------------------------------------------------------------------------
__global__ __launch_bounds__(256) void head_kernel(
    const float* __restrict__ HS, const float* __restrict__ fW1,
    const float* __restrict__ fb1, const float* __restrict__ bng,
    const float* __restrict__ bnb, const float* __restrict__ fW2,
    const float* __restrict__ fb2, float* __restrict__ out) {
  __shared__ float pl[384];
  __shared__ float h1[256];
  int b = blockIdx.x, n = threadIdx.x;
  {
    int j = n;
    int seg = j >> 7, oo = j & 127;
    pl[j] = (HS[((size_t)seg * BB + b) * 128 + oo] +
             HS[((size_t)(seg + 3) * BB + b) * 128 + oo]) * (0.5f / 512.f);
  }
  if (n < 128) {
    int j = 256 + n;
    int seg = j >> 7, oo = j & 127;
    pl[j] = (HS[((size_t)seg * BB + b) * 128 + oo] +
             HS[((size_t)(seg + 3) * BB + b) * 128 + oo]) * (0.5f / 512.f);
  }
  __syncthreads();
  float acc = fb1[n];
  for (int k = 0; k < 384; ++k) acc += pl[k] * fW1[k * 256 + n];
  float hv = acc * rsqrtf(1.f + 1e-5f) * bng[n] + bnb[n];
  hv = fminf(fmaxf(hv, 0.f), 6.f);
  h1[n] = hv;
  __syncthreads();
  if (n < 8) {
    float a2 = fb2[n];
    for (int k = 0; k < 256; ++k) a2 += h1[k] * fW2[k * 8 + n];
    out[b * 8 + n] = a2;
  }
}

// ---------------------------------------------------------------------------
extern "C" void kernel_launch(void* const* d_in, const int* in_sizes, int n_in,
                              void* d_out, int out_size, void* d_ws,
                              size_t ws_size, hipStream_t stream) {
  (void)in_sizes; (void)n_in; (void)out_size; (void)ws_size;
  const float* text = (const float*)d_in[0];
  const float* vis  = (const float*)d_in[1];
  const float* aud  = (const float*)d_in[2];
  const float* fc1W = (const float*)d_in[3];
  const float* fc1b = (const float*)d_in[4];
  const float* fc2W = (const float*)d_in[5];
  const float* fc2b = (const float*)d_in[6];
  const float* fc3W = (const float*)d_in[7];
  const float* fc3b = (const float*)d_in[8];
  const float* Wq = (const float*)d_in[9];
  const float* bq = (const float*)d_in[10];
  const float* Wk = (const float*)d_in[11];
  const float* bk = (const float*)d_in[12];
  const float* Wv = (const float*)d_in[13];
  const float* bv = (const float*)d_in[14];
  const float* Wd = (const float*)d_in[15];
  const float* bd = (const float*)d_in[16];
  const float* lng = (const float*)d_in[17];
  const float* lnb = (const float*)d_in[18];
  const float* gWih = (const float*)d_in[19];
  const float* gWhh = (const float*)d_in[20];
  const float* gbih = (const float*)d_in[21];
  const float* gbhh = (const float*)d_in[22];
  const float* fW1 = (const float*)d_in[23];
  const float* fb1 = (const float*)d_in[24];
  const float* bng = (const float*)d_in[25];
  const float* bnb = (const float*)d_in[26];
  const float* fW2 = (const float*)d_in[27];
  const float* fb2 = (const float*)d_in[28];
  float* out = (float*)d_out;

  // Workspace layout:
  //   [0, 160 MB)  : phase A/B fp32 buffers (8*SZ + vsum); later GX bf16 overlay
  //   [160, +48MB) : GRUIN fp32 [3][32768][128]
  //   then         : HS fp32 [6][64][128] (196 KB)
  float* ws = (float*)d_ws;
  float* T    = ws;
  float* Vv   = ws + SZ;
  float* Aa   = ws + 2 * SZ;
  float* Qb   = ws + 3 * SZ;
  float* Kb_  = ws + 4 * SZ;
  float* Vb_  = ws + 5 * SZ;
  float* CTX  = ws + 6 * SZ;
  float* DOUT = ws + 7 * SZ;
  float* VSUM = ws + 8 * SZ;
  __hip_bfloat16* GX = (__hip_bfloat16*)d_ws;  // phase C overlay
  char* base2 = (char*)d_ws + (size_t)160 * 1024 * 1024;
  float* GRUIN = (float*)base2;  // 3*SZ floats
  float* HS = (float*)(base2 + 3 * SZ * sizeof(float));

  hipMemsetAsync(GRUIN, 0, 3 * SZ * sizeof(float), stream);

  dim3 blk(256);
  gemm64<<<dim3(NROW / 64, 2), blk, 0, stream>>>(text, fc1W, fc1b, T, nullptr, 300, 128, 0);
  gemm64<<<dim3(NROW / 64, 2), blk, 0, stream>>>(vis,  fc2W, fc2b, Vv, nullptr, 35, 128, 0);
  gemm64<<<dim3(NROW / 64, 2), blk, 0, stream>>>(aud,  fc3W, fc3b, Aa, nullptr, 74, 128, 0);

  const float* qin[6]  = {T, Aa, T, Vv, Vv, Aa};
  const float* kvin[6] = {Aa, T, Vv, T, Aa, Vv};
  const int tgt[6] = {2, 0, 1, 0, 2, 1};

  for (int u = 0; u < 6; ++u) {
    const size_t wo = (size_t)u * 128 * 128;
    const size_t bo = (size_t)u * 128;
    gemm64<<<dim3(NROW / 64, 2), blk, 0, stream>>>(qin[u],  Wq + wo, bq + bo, Qb,  nullptr, 128, 128, 0);
    gemm64<<<dim3(NROW / 64, 2), blk, 0, stream>>>(kvin[u], Wk + wo, bk + bo, Kb_, nullptr, 128, 128, 0);
    gemm64<<<dim3(NROW / 64, 2), blk, 0, stream>>>(kvin[u], Wv + wo, bv + bo, Vb_, nullptr, 128, 128, 0);
    vsum_kernel<<<dim3(BB), dim3(128), 0, stream>>>(Vb_, VSUM);
    attn64<<<dim3(8, 128), blk, 0, stream>>>(Qb, Kb_, Vb_, VSUM, CTX);
    gemm64<<<dim3(NROW / 64, 2), blk, 0, stream>>>(CTX, Wd + wo, bd + bo, DOUT, nullptr, 128, 128, 0);
    ln_add64<<<dim3(NROW), dim3(64), 0, stream>>>(DOUT, lng + bo, lnb + bo, GRUIN + (size_t)tgt[u] * SZ);
  }

  for (int r = 0; r < 6; ++r) {
    int g = r >> 1;
    gemm64<<<dim3(NROW / 64, 6), blk, 0, stream>>>(
        GRUIN + (size_t)g * SZ, gWih + (size_t)r * 384 * 128, gbih + (size_t)r * 384,
        nullptr, GX + (size_t)r * NROW * 384, 128, 384, 1);
  }

  gru_mfma<<<dim3(4, 6), dim3(512), 0, stream>>>(GX, gWhh, gbhh, HS);
  head_kernel<<<dim3(BB), dim3(256), 0, stream>>>(HS, fW1, fb1, bng, bnb, fW2, fb2, out);
}

// Round 3
// 2328.732 us; speedup vs baseline: 1.8275x; 1.4988x over previous
//
#include <hip/hip_runtime.h>
#include <hip/hip_bf16.h>

// Problem constants
#define BB 64
#define SS 512
#define DD 128
#define NROW (BB * SS)          // 32768
#define SZ ((size_t)NROW * DD)  // 4,194,304 elems per [B,S,128] slice

typedef __attribute__((ext_vector_type(8))) short short8;
typedef __attribute__((ext_vector_type(4))) float f32x4;

// WB (converted-weight buffer) element offsets, all bf16:
#define WB_P1 0          // fc1W^T [128][320] (K=300 pad 320)
#define WB_P2 40960      // fc2W^T [128][64]  (K=35 pad 64)
#define WB_P3 49152      // fc3W^T [128][96]  (K=74 pad 96)
#define WB_QKVD 61440    // [4 op][6 u][128 n][128 k]
#define WB_WIH 454656    // [6 rec][384 n][128 k]
#define WB_WHH 749568    // [6 rec][384 n][128 k]
#define WB_TOTAL 1044480

__device__ __forceinline__ float sigmoidf_(float x) { return 1.f / (1.f + __expf(-x)); }
__device__ __forceinline__ float tanhf_(float x) {
  x = fminf(fmaxf(x, -15.f), 15.f);
  float e = __expf(2.f * x);
  return (e - 1.f) / (e + 1.f);
}
__device__ __forceinline__ float b2f(unsigned short u) {
  union { unsigned int i; float f; } x; x.i = ((unsigned int)u) << 16; return x.f;
}
__device__ __forceinline__ unsigned short f2b(float f) {
  __hip_bfloat16 b = __float2bfloat16(f);
  return *reinterpret_cast<unsigned short*>(&b);
}

// ---------------------------------------------------------------------------
// Weight prep: transpose/convert all weights into WB (bf16, [N][Kpad], zero-
// padded for k >= K).  Grid-stride over WB_TOTAL.
// ---------------------------------------------------------------------------
__global__ __launch_bounds__(256) void prep_kernel(
    const float* __restrict__ fc1W, const float* __restrict__ fc2W,
    const float* __restrict__ fc3W, const float* __restrict__ Wq,
    const float* __restrict__ Wk, const float* __restrict__ Wv,
    const float* __restrict__ Wd, const float* __restrict__ gWih,
    const float* __restrict__ gWhh, unsigned short* __restrict__ WB) {
  for (int idx = blockIdx.x * 256 + threadIdx.x; idx < WB_TOTAL;
       idx += gridDim.x * 256) {
    float v;
    if (idx < WB_P2) {
      int n = idx / 320, k = idx % 320;
      v = (k < 300) ? fc1W[k * 128 + n] : 0.f;
    } else if (idx < WB_P3) {
      int r = idx - WB_P2; int n = r >> 6, k = r & 63;
      v = (k < 35) ? fc2W[k * 128 + n] : 0.f;
    } else if (idx < WB_QKVD) {
      int r = idx - WB_P3; int n = r / 96, k = r % 96;
      v = (k < 74) ? fc3W[k * 128 + n] : 0.f;
    } else if (idx < WB_WIH) {
      int r = idx - WB_QKVD;
      int op = r / 98304; int r2 = r % 98304;
      int u = r2 >> 14; int r3 = r2 & 16383;
      int n = r3 >> 7, k = r3 & 127;
      const float* src = (op == 0) ? Wq : (op == 1) ? Wk : (op == 2) ? Wv : Wd;
      v = src[u * 16384 + k * 128 + n];
    } else if (idx < WB_WHH) {
      v = gWih[idx - WB_WIH];
    } else {
      v = gWhh[idx - WB_WHH];
    }
    WB[idx] = f2b(v);
  }
}

// ---------------------------------------------------------------------------
// Batched MFMA GEMM: C[32768,128] = A[32768,Ka] @ W^T + bias, per blockIdx.z.
// W in WB layout [128][Kp] bf16 (pre-transposed, zero-padded).  A fp32 (abf=0)
// or bf16 (abf=1).  C bf16 (cbf=1) or fp32.  Tile 128x128, BK=32, 4 waves.
// grid = (256, 1, Z), block = 256.
// ---------------------------------------------------------------------------
struct GArg {
  const void* A; const unsigned short* W; const float* bias; void* C;
  int Ka, Kp, abf, cbf;
};
struct GArgs { GArg g[18]; };

__global__ __launch_bounds__(256) void gemm_b(GArgs args) {
  const GArg ga = args.g[blockIdx.z];
  __shared__ unsigned short As[128 * 40];
  __shared__ unsigned short Ws[128 * 40];
  const int t = threadIdx.x;
  const int w = t >> 6, lane = t & 63, q = lane >> 4, lm = lane & 15;
  const int wm = w >> 1, wn = w & 1;
  const int m0 = blockIdx.x * 128;
  const int row = t >> 1, cb = (t & 1) * 16;
  f32x4 acc[4][4];
#pragma unroll
  for (int i = 0; i < 4; ++i)
#pragma unroll
    for (int j = 0; j < 4; ++j) acc[i][j] = (f32x4){0.f, 0.f, 0.f, 0.f};

  for (int kt = 0; kt < ga.Kp; kt += 32) {
    // stage A -> bf16 LDS [row][40]
    if (ga.abf) {
      const unsigned short* Ag =
          (const unsigned short*)ga.A + (size_t)(m0 + row) * ga.Ka + kt + cb;
      short8 v0 = *reinterpret_cast<const short8*>(Ag);
      short8 v1 = *reinterpret_cast<const short8*>(Ag + 8);
      *reinterpret_cast<short8*>(&As[row * 40 + cb]) = v0;
      *reinterpret_cast<short8*>(&As[row * 40 + cb + 8]) = v1;
    } else {
      const float* Ag = (const float*)ga.A + (size_t)(m0 + row) * ga.Ka + kt + cb;
      unsigned short tmp[16];
#pragma unroll
      for (int j = 0; j < 16; ++j) {
        int k = kt + cb + j;
        tmp[j] = (k < ga.Ka) ? f2b(Ag[j]) : 0;
      }
      *reinterpret_cast<short8*>(&As[row * 40 + cb]) =
          *reinterpret_cast<short8*>(&tmp[0]);
      *reinterpret_cast<short8*>(&As[row * 40 + cb + 8]) =
          *reinterpret_cast<short8*>(&tmp[8]);
    }
    // stage W (already bf16 [n][Kp])
    {
      const unsigned short* Wg = ga.W + (size_t)row * ga.Kp + kt + cb;
      short8 v0 = *reinterpret_cast<const short8*>(Wg);
      short8 v1 = *reinterpret_cast<const short8*>(Wg + 8);
      *reinterpret_cast<short8*>(&Ws[row * 40 + cb]) = v0;
      *reinterpret_cast<short8*>(&Ws[row * 40 + cb + 8]) = v1;
    }
    __syncthreads();
    short8 af[4], bfv[4];
#pragma unroll
    for (int mi = 0; mi < 4; ++mi)
      af[mi] = *reinterpret_cast<const short8*>(
          &As[(wm * 64 + mi * 16 + lm) * 40 + q * 8]);
#pragma unroll
    for (int ni = 0; ni < 4; ++ni)
      bfv[ni] = *reinterpret_cast<const short8*>(
          &Ws[(wn * 64 + ni * 16 + lm) * 40 + q * 8]);
#pragma unroll
    for (int mi = 0; mi < 4; ++mi)
#pragma unroll
      for (int ni = 0; ni < 4; ++ni)
        acc[mi][ni] = __builtin_amdgcn_mfma_f32_16x16x32_bf16(
            af[mi], bfv[ni], acc[mi][ni], 0, 0, 0);
    __syncthreads();
  }
  // epilogue: C row = m0 + wm*64 + mi*16 + q*4 + r, col = wn*64 + ni*16 + lm
#pragma unroll
  for (int ni = 0; ni < 4; ++ni) {
    const int col = wn * 64 + ni * 16 + lm;
    const float bv = ga.bias[col];
#pragma unroll
    for (int mi = 0; mi < 4; ++mi) {
      const int rg = m0 + wm * 64 + mi * 16 + q * 4;
#pragma unroll
      for (int r = 0; r < 4; ++r) {
        float v = acc[mi][ni][r] + bv;
        if (ga.cbf)
          ((unsigned short*)ga.C)[(size_t)(rg + r) * 128 + col] = f2b(v);
        else
          ((float*)ga.C)[(size_t)(rg + r) * 128 + col] = v;
      }
    }
  }
}

// ---------------------------------------------------------------------------
// V column sums: VS[z][b][128] = sum_s V_z[b][s][:]   (V bf16)
// grid = (64, 3), block = 128.
// ---------------------------------------------------------------------------
__global__ __launch_bounds__(128) void vsum_kernel(
    const unsigned short* __restrict__ QKV, float* __restrict__ VS) {
  int b = blockIdx.x, z = blockIdx.y, d = threadIdx.x;
  const unsigned short* p = QKV + (size_t)(z * 3 + 2) * SZ + (size_t)b * SS * DD + d;
  float s = 0.f;
  for (int k = 0; k < SS; ++k) s += b2f(p[(size_t)k * DD]);
  VS[(z * BB + b) * DD + d] = s;
}

// ---------------------------------------------------------------------------
// Attention (probs = 1 - softmax): ctx = Vsum - softmax(QK^T/8) @ V.  bf16 IO.
// grid = (8 qtiles, 128 = b*2+h, 3 units), block = 256.
// ---------------------------------------------------------------------------
__global__ __launch_bounds__(256) void attn64(
    const unsigned short* __restrict__ QKV, const float* __restrict__ VS,
    unsigned short* __restrict__ CTX) {
  __shared__ float Kt[64][68];
  __shared__ float Vt[64][68];
  __shared__ float St[64][65];
  const int t = threadIdx.x;
  const int z = blockIdx.z;
  const int bh = blockIdx.y, b = bh >> 1, h = bh & 1;
  const int q0 = blockIdx.x * 64;
  const int qr = t >> 2, g4 = t & 3, d0 = g4 * 16;
  const unsigned short* Qg = QKV + (size_t)(z * 3 + 0) * SZ;
  const unsigned short* Kg = QKV + (size_t)(z * 3 + 1) * SZ + (size_t)b * SS * DD + h * 64;
  const unsigned short* Vg = QKV + (size_t)(z * 3 + 2) * SZ + (size_t)b * SS * DD + h * 64;
  const unsigned short* qp = Qg + ((size_t)(b * SS + q0 + qr)) * DD + h * 64;
  float qreg[64];
#pragma unroll
  for (int i = 0; i < 8; ++i) {
    short8 f = *reinterpret_cast<const short8*>(qp + i * 8);
#pragma unroll
    for (int j = 0; j < 8; ++j) qreg[i * 8 + j] = b2f((unsigned short)f[j]);
  }
  float o[16];
#pragma unroll
  for (int i = 0; i < 16; ++i) o[i] = 0.f;
  float l = 0.f;
  for (int kt = 0; kt < 8; ++kt) {
    const int k0 = kt * 64;
    __syncthreads();
#pragma unroll
    for (int i = 0; i < 2; ++i) {
      int idx = t + i * 256;
      int r = idx >> 3, c8 = (idx & 7) * 8;
      short8 kv = *reinterpret_cast<const short8*>(Kg + (size_t)(k0 + r) * DD + c8);
      short8 vv = *reinterpret_cast<const short8*>(Vg + (size_t)(k0 + r) * DD + c8);
#pragma unroll
      for (int j = 0; j < 8; ++j) {
        Kt[r][c8 + j] = b2f((unsigned short)kv[j]);
        Vt[r][c8 + j] = b2f((unsigned short)vv[j]);
      }
    }
    __syncthreads();
    float sv[16];
#pragma unroll
    for (int j = 0; j < 16; ++j) sv[j] = 0.f;
#pragma unroll
    for (int ch = 0; ch < 16; ++ch) {
      const float qa = qreg[ch * 4], qb = qreg[ch * 4 + 1];
      const float qc = qreg[ch * 4 + 2], qd = qreg[ch * 4 + 3];
#pragma unroll
      for (int j = 0; j < 16; ++j) {
        float4 kv = *reinterpret_cast<const float4*>(&Kt[j * 4 + g4][ch * 4]);
        sv[j] += qa * kv.x + qb * kv.y + qc * kv.z + qd * kv.w;
      }
    }
#pragma unroll
    for (int j = 0; j < 16; ++j) St[qr][j * 4 + g4] = sv[j] * 0.125f;
    __syncthreads();
#pragma unroll 4
    for (int k = 0; k < 64; ++k) {
      float p = __expf(St[qr][k]);
      l += p;
      float4 v0 = *reinterpret_cast<const float4*>(&Vt[k][d0]);
      float4 v1 = *reinterpret_cast<const float4*>(&Vt[k][d0 + 4]);
      float4 v2 = *reinterpret_cast<const float4*>(&Vt[k][d0 + 8]);
      float4 v3 = *reinterpret_cast<const float4*>(&Vt[k][d0 + 12]);
      o[0] += p * v0.x;  o[1] += p * v0.y;  o[2] += p * v0.z;  o[3] += p * v0.w;
      o[4] += p * v1.x;  o[5] += p * v1.y;  o[6] += p * v1.z;  o[7] += p * v1.w;
      o[8] += p * v2.x;  o[9] += p * v2.y;  o[10] += p * v2.z; o[11] += p * v2.w;
      o[12] += p * v3.x; o[13] += p * v3.y; o[14] += p * v3.z; o[15] += p * v3.w;
    }
  }
  float invl = 1.f / l;
  unsigned short* cp = CTX + (size_t)z * SZ + ((size_t)(b * SS + q0 + qr)) * DD + h * 64 + d0;
  const float* vsp = VS + (z * BB + b) * DD + h * 64 + d0;
  unsigned short res[16];
#pragma unroll
  for (int i = 0; i < 16; ++i) res[i] = f2b(vsp[i] - o[i] * invl);
  *reinterpret_cast<short8*>(cp) = *reinterpret_cast<short8*>(&res[0]);
  *reinterpret_cast<short8*>(cp + 8) = *reinterpret_cast<short8*>(&res[8]);
}

// ---------------------------------------------------------------------------
// Fused LN pair: GRUIN[g][row] = 0.5*(LN_u1(DOUT[u1][row]) + LN_u2(DOUT[u2][row]))
// grid = (NROW, 3), block = 64.  DOUT bf16 in, GRUIN bf16 out.
// ---------------------------------------------------------------------------
__global__ __launch_bounds__(64) void ln_pair(
    const unsigned short* __restrict__ DOUT, const float* __restrict__ lng,
    const float* __restrict__ lnb, unsigned short* __restrict__ GRUIN) {
  const int row = blockIdx.x, g = blockIdx.y, t = threadIdx.x;
  const int u1t[3] = {1, 2, 0};
  const int u2t[3] = {3, 5, 4};
  float outA = 0.f, outB = 0.f;
#pragma unroll
  for (int half = 0; half < 2; ++half) {
    const int u = half == 0 ? u1t[g] : u2t[g];
    const unsigned short* x = DOUT + (size_t)u * SZ + (size_t)row * DD;
    float a = b2f(x[t]), c = b2f(x[t + 64]);
    float s = a + c, sq = a * a + c * c;
#pragma unroll
    for (int off = 32; off > 0; off >>= 1) {
      s += __shfl_down(s, off);
      sq += __shfl_down(sq, off);
    }
    s = __shfl(s, 0); sq = __shfl(sq, 0);
    float mean = s * (1.f / 128.f);
    float var = sq * (1.f / 128.f) - mean * mean;
    float rs = rsqrtf(var + 1e-5f);
    const float* gg = lng + u * 128;
    const float* bb = lnb + u * 128;
    outA += (a - mean) * rs * gg[t] + bb[t];
    outB += (c - mean) * rs * gg[t + 64] + bb[t + 64];
  }
  unsigned short* op = GRUIN + (size_t)g * SZ + (size_t)row * DD;
  op[t] = f2b(0.5f * outA);
  op[t + 64] = f2b(0.5f * outB);
}

// ---------------------------------------------------------------------------
// GRU v3: recurrence with fused x-projection, all-MFMA.
// grid = (4 batch-groups of 16, 6 recs), block = 512 (8 waves).
// Per step:  pre = X_t[16,128] @ Wih^T + H[16,128] @ Whh^T + biases  (24 MFMAs
// per wave over its 3 gate-columns), gates in-register (C-frag layout).
// X A-frags loaded straight from global (dwordx4, layout == A-frag), PD=2
// prefetch.  H bf16 ping-pong in LDS, 1 barrier/step.
// HS[rec][64][128] = sum_t h.
// ---------------------------------------------------------------------------
#define AST 136

__global__ __launch_bounds__(512, 2) void gru2(
    const unsigned short* __restrict__ GRUIN, const unsigned short* __restrict__ WB,
    const float* __restrict__ gbih, const float* __restrict__ gbhh,
    float* __restrict__ HS) {
  __shared__ unsigned short Abuf[2][16 * AST];
  const int rec = blockIdx.y, bg = blockIdx.x;
  const int g = rec >> 1, dir = rec & 1;
  const int t = threadIdx.x;
  const int w = t >> 6, lane = t & 63, q = lane >> 4, lm = lane & 15;
  const int q4 = q * 4;
  const int o = w * 16 + lm;  // hidden unit 0..127

  // B fragments (bf16, pre-converted): row (gate*128+o), k = c*32+q*8+j
  short8 Bh[3][4], Bx[3][4];
  const unsigned short* whh = WB + WB_WHH + (size_t)rec * 49152;
  const unsigned short* wih = WB + WB_WIH + (size_t)rec * 49152;
#pragma unroll
  for (int gate = 0; gate < 3; ++gate)
#pragma unroll
    for (int c = 0; c < 4; ++c) {
      Bh[gate][c] = *reinterpret_cast<const short8*>(
          whh + (size_t)(gate * 128 + o) * 128 + c * 32 + q * 8);
      Bx[gate][c] = *reinterpret_cast<const short8*>(
          wih + (size_t)(gate * 128 + o) * 128 + c * 32 + q * 8);
    }
  const float br = gbih[rec * 384 + o] + gbhh[rec * 384 + o];
  const float bz = gbih[rec * 384 + 128 + o] + gbhh[rec * 384 + 128 + o];
  const float bxn = gbih[rec * 384 + 256 + o];
  const float bhn = gbhh[rec * 384 + 256 + o];

  float h[4] = {0.f, 0.f, 0.f, 0.f};
  float hsum[4] = {0.f, 0.f, 0.f, 0.f};
  for (int i = t; i < 16 * AST; i += 512) Abuf[0][i] = 0;

  // X base: GRUIN[g][b = bg*16+lm][t][128]
  const unsigned short* xb = GRUIN + (size_t)g * SZ + ((size_t)(bg * 16 + lm)) * SS * DD;

  short8 xf[2][4];
#pragma unroll
  for (int pp = 0; pp < 2; ++pp) {
    const int tt = dir ? (SS - 1 - pp) : pp;
#pragma unroll
    for (int c = 0; c < 4; ++c)
      xf[pp][c] = *reinterpret_cast<const short8*>(xb + (size_t)tt * DD + c * 32 + q * 8);
  }
  __syncthreads();

#pragma unroll 2
  for (int s = 0; s < SS; ++s) {
    const int p = s & 1;
    short8 ah[4];
#pragma unroll
    for (int c = 0; c < 4; ++c)
      ah[c] = *reinterpret_cast<const short8*>(&Abuf[p][lm * AST + c * 32 + q * 8]);
    f32x4 ar = {br, br, br, br};
    f32x4 az = {bz, bz, bz, bz};
    f32x4 axn = {bxn, bxn, bxn, bxn};
    f32x4 ahn = {bhn, bhn, bhn, bhn};
#pragma unroll
    for (int c = 0; c < 4; ++c) {
      ar = __builtin_amdgcn_mfma_f32_16x16x32_bf16(ah[c], Bh[0][c], ar, 0, 0, 0);
      az = __builtin_amdgcn_mfma_f32_16x16x32_bf16(ah[c], Bh[1][c], az, 0, 0, 0);
      ahn = __builtin_amdgcn_mfma_f32_16x16x32_bf16(ah[c], Bh[2][c], ahn, 0, 0, 0);
      ar = __builtin_amdgcn_mfma_f32_16x16x32_bf16(xf[p][c], Bx[0][c], ar, 0, 0, 0);
      az = __builtin_amdgcn_mfma_f32_16x16x32_bf16(xf[p][c], Bx[1][c], az, 0, 0, 0);
      axn = __builtin_amdgcn_mfma_f32_16x16x32_bf16(xf[p][c], Bx[2][c], axn, 0, 0, 0);
    }
    // prefetch X for step s+2 into the slot just consumed
    {
      int sn = s + 2; if (sn > SS - 1) sn = SS - 1;
      const int tn = dir ? (SS - 1 - sn) : sn;
#pragma unroll
      for (int c = 0; c < 4; ++c)
        xf[p][c] = *reinterpret_cast<const short8*>(xb + (size_t)tn * DD + c * 32 + q * 8);
    }
#pragma unroll
    for (int i = 0; i < 4; ++i) {
      float r = sigmoidf_(ar[i]);
      float z = sigmoidf_(az[i]);
      float nn = tanhf_(axn[i] + r * ahn[i]);
      h[i] = (1.f - z) * nn + z * h[i];
      hsum[i] += h[i];
      Abuf[p ^ 1][(q4 + i) * AST + o] = f2b(h[i]);
    }
    __syncthreads();
  }
#pragma unroll
  for (int i = 0; i < 4; ++i)
    HS[((size_t)rec * BB + bg * 16 + q4 + i) * 128 + o] = hsum[i];
}

// ---------------------------------------------------------------------------
// Head: pooled -> Linear -> BN(eval) -> ReLU6 -> Linear.  grid=64, block=256.
// ---------------------------------------------------------------------------
__global__ __launch_bounds__(256) void head_kernel(
    const float* __restrict__ HS, const float* __restrict__ fW1,
    const float* __restrict__ fb1, const float* __restrict__ bng,
    const float* __restrict__ bnb, const float* __restrict__ fW2,
    const float* __restrict__ fb2, float* __restrict__ out) {
  __shared__ float pl[384];
  __shared__ float h1[256];
  int b = blockIdx.x, n = threadIdx.x;
  {
    int j = n;
    int seg = j >> 7, oo = j & 127;
    pl[j] = (HS[((size_t)seg * BB + b) * 128 + oo] +
             HS[((size_t)(seg + 3) * BB + b) * 128 + oo]) * (0.5f / 512.f);
  }
  if (n < 128) {
    int j = 256 + n;
    int seg = j >> 7, oo = j & 127;
    pl[j] = (HS[((size_t)seg * BB + b) * 128 + oo] +
             HS[((size_t)(seg + 3) * BB + b) * 128 + oo]) * (0.5f / 512.f);
  }
  __syncthreads();
  float acc = fb1[n];
  for (int k = 0; k < 384; ++k) acc += pl[k] * fW1[k * 256 + n];
  float hv = acc * rsqrtf(1.f + 1e-5f) * bng[n] + bnb[n];
  hv = fminf(fmaxf(hv, 0.f), 6.f);
  h1[n] = hv;
  __syncthreads();
  if (n < 8) {
    float a2 = fb2[n];
    for (int k = 0; k < 256; ++k) a2 += h1[k] * fW2[k * 8 + n];
    out[b * 8 + n] = a2;
  }
}

// ---------------------------------------------------------------------------
extern "C" void kernel_launch(void* const* d_in, const int* in_sizes, int n_in,
                              void* d_out, int out_size, void* d_ws,
                              size_t ws_size, hipStream_t stream) {
  (void)in_sizes; (void)n_in; (void)out_size; (void)ws_size;
  const float* text = (const float*)d_in[0];
  const float* vis  = (const float*)d_in[1];
  const float* aud  = (const float*)d_in[2];
  const float* fc1W = (const float*)d_in[3];
  const float* fc1b = (const float*)d_in[4];
  const float* fc2W = (const float*)d_in[5];
  const float* fc2b = (const float*)d_in[6];
  const float* fc3W = (const float*)d_in[7];
  const float* fc3b = (const float*)d_in[8];
  const float* Wq = (const float*)d_in[9];
  const float* bq = (const float*)d_in[10];
  const float* Wk = (const float*)d_in[11];
  const float* bk = (const float*)d_in[12];
  const float* Wv = (const float*)d_in[13];
  const float* bv = (const float*)d_in[14];
  const float* Wd = (const float*)d_in[15];
  const float* bd = (const float*)d_in[16];
  const float* lng = (const float*)d_in[17];
  const float* lnb = (const float*)d_in[18];
  const float* gWih = (const float*)d_in[19];
  const float* gWhh = (const float*)d_in[20];
  const float* gbih = (const float*)d_in[21];
  const float* gbhh = (const float*)d_in[22];
  const float* fW1 = (const float*)d_in[23];
  const float* fb1 = (const float*)d_in[24];
  const float* bng = (const float*)d_in[25];
  const float* bnb = (const float*)d_in[26];
  const float* fW2 = (const float*)d_in[27];
  const float* fb2 = (const float*)d_in[28];
  float* out = (float*)d_out;

  // Workspace (bf16 slices of SZ elems = 8.39 MB each):
  //  slice 0..2 : T, Vv, Aa (proj)          -> later DOUT u=0..5 (slices 0..5)
  //  slice 3..11: QKV phase (9 per phase, reused)       -> later GRUIN g=0..2
  //               (GRUIN at slices 6..8 after QKV dead)
  //  slice 12..17: CTX u=0..5
  //  after slice 18: WB (1,044,480 bf16), then VS (fp32 6*64*128), HS (same)
  unsigned short* WSB = (unsigned short*)d_ws;
  unsigned short* T   = WSB;
  unsigned short* Vv  = WSB + SZ;
  unsigned short* Aa  = WSB + 2 * SZ;
  unsigned short* QKV = WSB + 3 * SZ;
  unsigned short* CTX = WSB + 12 * SZ;
  unsigned short* DOUT = WSB;            // slices 0..5 (T/Vv/Aa + QKV0..2 dead)
  unsigned short* GRUIN = WSB + 6 * SZ;  // slices 6..8 (QKV dead)
  unsigned short* WB  = WSB + 18 * SZ;
  float* VS = (float*)(WSB + 18 * SZ + 1048576);  // 6*64*128 floats
  float* HS = VS + 6 * 64 * 128;

  // 1. weight prep
  prep_kernel<<<dim3(1024), dim3(256), 0, stream>>>(
      fc1W, fc2W, fc3W, Wq, Wk, Wv, Wd, gWih, gWhh, WB);

  // 2. input projections (z=3)
  {
    GArgs ga{};
    ga.g[0] = {text, WB + WB_P1, fc1b, T, 300, 320, 0, 1};
    ga.g[1] = {vis,  WB + WB_P2, fc2b, Vv, 35, 64, 0, 1};
    ga.g[2] = {aud,  WB + WB_P3, fc3b, Aa, 74, 96, 0, 1};
    gemm_b<<<dim3(256, 1, 3), dim3(256), 0, stream>>>(ga);
  }

  const int qsel[6] = {0, 2, 0, 1, 1, 2};   // qin:  T,Aa,T,Vv,Vv,Aa
  const int ksel[6] = {2, 0, 1, 0, 2, 1};   // kvin: Aa,T,Vv,T,Aa,Vv
  unsigned short* proj[3] = {T, Vv, Aa};
  const float* qkvbias[3] = {bq, bk, bv};

  for (int phase = 0; phase < 2; ++phase) {
    // 3. QKV gemms for 3 units (z=9)
    GArgs ga{};
    for (int ul = 0; ul < 3; ++ul) {
      int u = phase * 3 + ul;
      for (int op = 0; op < 3; ++op) {
        int z = ul * 3 + op;
        ga.g[z] = {proj[op == 0 ? qsel[u] : ksel[u]],
                   WB + WB_QKVD + op * 98304 + u * 16384,
                   qkvbias[op] + u * 128,
                   QKV + (size_t)z * SZ, 128, 128, 1, 1};
      }
    }
    gemm_b<<<dim3(256, 1, 9), dim3(256), 0, stream>>>(ga);
    // 4. V column sums
    vsum_kernel<<<dim3(BB, 3), dim3(128), 0, stream>>>(QKV, VS + phase * 3 * BB * DD);
    // 5. attention -> CTX
    attn64<<<dim3(8, 128, 3), dim3(256), 0, stream>>>(
        QKV, VS + phase * 3 * BB * DD, CTX + (size_t)phase * 3 * SZ);
  }

  // 6. dense-out gemms (z=6): DOUT[u] = CTX[u] @ Wd[u] + bd[u]
  {
    GArgs ga{};
    for (int u = 0; u < 6; ++u)
      ga.g[u] = {CTX + (size_t)u * SZ, WB + WB_QKVD + 3 * 98304 + u * 16384,
                 bd + u * 128, DOUT + (size_t)u * SZ, 128, 128, 1, 1};
    gemm_b<<<dim3(256, 1, 6), dim3(256), 0, stream>>>(ga);
  }

  // 7. fused LN pair -> GRUIN (bf16)
  ln_pair<<<dim3(NROW, 3), dim3(64), 0, stream>>>(DOUT, lng, lnb, GRUIN);

  // 8. GRU (fused x-projection, MFMA)
  gru2<<<dim3(4, 6), dim3(512), 0, stream>>>(GRUIN, WB, gbih, gbhh, HS);

  // 9. head
  head_kernel<<<dim3(BB), dim3(256), 0, stream>>>(HS, fW1, fb1, bng, bnb, fW2, fb2, out);
}

// Round 4
// 1312.417 us; speedup vs baseline: 3.2427x; 1.7744x over previous
//
#include <hip/hip_runtime.h>
#include <hip/hip_bf16.h>

// Problem constants
#define BB 64
#define SS 512
#define DD 128
#define NROW (BB * SS)          // 32768
#define SZ ((size_t)NROW * DD)  // 4,194,304 elems per [B,S,128] slice

typedef __attribute__((ext_vector_type(8))) short short8;
typedef __attribute__((ext_vector_type(4))) float f32x4;

// WB (converted-weight buffer) element offsets, all bf16:
#define WB_P1 0          // fc1W^T [128][320] (K=300 pad 320)
#define WB_P2 40960      // fc2W^T [128][64]  (K=35 pad 64)
#define WB_P3 49152      // fc3W^T [128][96]  (K=74 pad 96)
#define WB_QKVD 61440    // [4 op][6 u][128 n][128 k]
#define WB_WIH 454656    // [6 rec][384 n][128 k]
#define WB_WHH 749568    // [6 rec][384 n][128 k]
#define WB_TOTAL 1044480

__device__ __forceinline__ float sigmoidf_(float x) { return 1.f / (1.f + __expf(-x)); }
__device__ __forceinline__ float tanhf_(float x) {
  x = fminf(fmaxf(x, -15.f), 15.f);
  float e = __expf(2.f * x);
  return (e - 1.f) / (e + 1.f);
}
__device__ __forceinline__ float b2f(unsigned short u) {
  union { unsigned int i; float f; } x; x.i = ((unsigned int)u) << 16; return x.f;
}
__device__ __forceinline__ unsigned short f2b(float f) {
  __hip_bfloat16 b = __float2bfloat16(f);
  return *reinterpret_cast<unsigned short*>(&b);
}

// ---------------------------------------------------------------------------
// Weight prep: transpose/convert all weights into WB (bf16, [N][Kpad]).
// ---------------------------------------------------------------------------
__global__ __launch_bounds__(256) void prep_kernel(
    const float* __restrict__ fc1W, const float* __restrict__ fc2W,
    const float* __restrict__ fc3W, const float* __restrict__ Wq,
    const float* __restrict__ Wk, const float* __restrict__ Wv,
    const float* __restrict__ Wd, const float* __restrict__ gWih,
    const float* __restrict__ gWhh, unsigned short* __restrict__ WB) {
  for (int idx = blockIdx.x * 256 + threadIdx.x; idx < WB_TOTAL;
       idx += gridDim.x * 256) {
    float v;
    if (idx < WB_P2) {
      int n = idx / 320, k = idx % 320;
      v = (k < 300) ? fc1W[k * 128 + n] : 0.f;
    } else if (idx < WB_P3) {
      int r = idx - WB_P2; int n = r >> 6, k = r & 63;
      v = (k < 35) ? fc2W[k * 128 + n] : 0.f;
    } else if (idx < WB_QKVD) {
      int r = idx - WB_P3; int n = r / 96, k = r % 96;
      v = (k < 74) ? fc3W[k * 128 + n] : 0.f;
    } else if (idx < WB_WIH) {
      int r = idx - WB_QKVD;
      int op = r / 98304; int r2 = r % 98304;
      int u = r2 >> 14; int r3 = r2 & 16383;
      int n = r3 >> 7, k = r3 & 127;
      const float* src = (op == 0) ? Wq : (op == 1) ? Wk : (op == 2) ? Wv : Wd;
      v = src[u * 16384 + k * 128 + n];
    } else if (idx < WB_WHH) {
      v = gWih[idx - WB_WIH];
    } else {
      v = gWhh[idx - WB_WHH];
    }
    WB[idx] = f2b(v);
  }
}

// ---------------------------------------------------------------------------
// Batched MFMA GEMM: C[32768,128] = A[32768,Ka] @ W^T + bias, per blockIdx.z.
// ---------------------------------------------------------------------------
struct GArg {
  const void* A; const unsigned short* W; const float* bias; void* C;
  int Ka, Kp, abf, cbf;
};
struct GArgs { GArg g[18]; };

__global__ __launch_bounds__(256) void gemm_b(GArgs args) {
  const GArg ga = args.g[blockIdx.z];
  __shared__ unsigned short As[128 * 40];
  __shared__ unsigned short Ws[128 * 40];
  const int t = threadIdx.x;
  const int w = t >> 6, lane = t & 63, q = lane >> 4, lm = lane & 15;
  const int wm = w >> 1, wn = w & 1;
  const int m0 = blockIdx.x * 128;
  const int row = t >> 1, cb = (t & 1) * 16;
  f32x4 acc[4][4];
#pragma unroll
  for (int i = 0; i < 4; ++i)
#pragma unroll
    for (int j = 0; j < 4; ++j) acc[i][j] = (f32x4){0.f, 0.f, 0.f, 0.f};

  for (int kt = 0; kt < ga.Kp; kt += 32) {
    if (ga.abf) {
      const unsigned short* Ag =
          (const unsigned short*)ga.A + (size_t)(m0 + row) * ga.Ka + kt + cb;
      short8 v0 = *reinterpret_cast<const short8*>(Ag);
      short8 v1 = *reinterpret_cast<const short8*>(Ag + 8);
      *reinterpret_cast<short8*>(&As[row * 40 + cb]) = v0;
      *reinterpret_cast<short8*>(&As[row * 40 + cb + 8]) = v1;
    } else {
      const float* Ag = (const float*)ga.A + (size_t)(m0 + row) * ga.Ka + kt + cb;
      unsigned short tmp[16];
#pragma unroll
      for (int j = 0; j < 16; ++j) {
        int k = kt + cb + j;
        tmp[j] = (k < ga.Ka) ? f2b(Ag[j]) : 0;
      }
      *reinterpret_cast<short8*>(&As[row * 40 + cb]) =
          *reinterpret_cast<short8*>(&tmp[0]);
      *reinterpret_cast<short8*>(&As[row * 40 + cb + 8]) =
          *reinterpret_cast<short8*>(&tmp[8]);
    }
    {
      const unsigned short* Wg = ga.W + (size_t)row * ga.Kp + kt + cb;
      short8 v0 = *reinterpret_cast<const short8*>(Wg);
      short8 v1 = *reinterpret_cast<const short8*>(Wg + 8);
      *reinterpret_cast<short8*>(&Ws[row * 40 + cb]) = v0;
      *reinterpret_cast<short8*>(&Ws[row * 40 + cb + 8]) = v1;
    }
    __syncthreads();
    short8 af[4], bfv[4];
#pragma unroll
    for (int mi = 0; mi < 4; ++mi)
      af[mi] = *reinterpret_cast<const short8*>(
          &As[(wm * 64 + mi * 16 + lm) * 40 + q * 8]);
#pragma unroll
    for (int ni = 0; ni < 4; ++ni)
      bfv[ni] = *reinterpret_cast<const short8*>(
          &Ws[(wn * 64 + ni * 16 + lm) * 40 + q * 8]);
#pragma unroll
    for (int mi = 0; mi < 4; ++mi)
#pragma unroll
      for (int ni = 0; ni < 4; ++ni)
        acc[mi][ni] = __builtin_amdgcn_mfma_f32_16x16x32_bf16(
            af[mi], bfv[ni], acc[mi][ni], 0, 0, 0);
    __syncthreads();
  }
#pragma unroll
  for (int ni = 0; ni < 4; ++ni) {
    const int col = wn * 64 + ni * 16 + lm;
    const float bv = ga.bias[col];
#pragma unroll
    for (int mi = 0; mi < 4; ++mi) {
      const int rg = m0 + wm * 64 + mi * 16 + q * 4;
#pragma unroll
      for (int r = 0; r < 4; ++r) {
        float v = acc[mi][ni][r] + bv;
        if (ga.cbf)
          ((unsigned short*)ga.C)[(size_t)(rg + r) * 128 + col] = f2b(v);
        else
          ((float*)ga.C)[(size_t)(rg + r) * 128 + col] = v;
      }
    }
  }
}

// ---------------------------------------------------------------------------
// V column sums: VS[z][b][128] = sum_s V_z[b][s][:]   (V bf16)
// ---------------------------------------------------------------------------
__global__ __launch_bounds__(128) void vsum_kernel(
    const unsigned short* __restrict__ QKV, float* __restrict__ VS) {
  int b = blockIdx.x, z = blockIdx.y, d = threadIdx.x;
  const unsigned short* p = QKV + (size_t)(z * 3 + 2) * SZ + (size_t)b * SS * DD + d;
  float s = 0.f;
  for (int k = 0; k < SS; ++k) s += b2f(p[(size_t)k * DD]);
  VS[(z * BB + b) * DD + d] = s;
}

// ---------------------------------------------------------------------------
// MFMA attention (probs = 1 - softmax): ctx = Vsum - softmax(QK^T/8) @ V.
// grid = (8 qtiles, 128 = b*2+h, 3 units), block = 256 (4 waves).
// Wave w: q-rows [q0+w*16, +16).  QK^T: A,B frags loaded directly from global
// (contract dim d is contiguous for both Q and K rows).  P = exp(S/8) crosses
// C-layout -> A-layout via wave-private LDS (no barrier).  V staged transposed
// in LDS with XOR swizzle col = k ^ (d&56) (conflict-free b16 scatter, aligned
// b128 reads).  Row-sum l via 16-lane xor shuffles; normalize once at end.
// LDS: Vt 9216 + Pt 9216 = 18.4 KB -> 8 blocks/CU.
// ---------------------------------------------------------------------------
__global__ __launch_bounds__(256) void attn_mfma(
    const unsigned short* __restrict__ QKV, const float* __restrict__ VS,
    unsigned short* __restrict__ CTX) {
  __shared__ unsigned short Vt[64 * 72];       // [d][k ^ (d&56)]
  __shared__ unsigned short Pt[4][16 * 72];    // per-wave [q][k]
  const int t = threadIdx.x;
  const int w = t >> 6, lane = t & 63, quad = lane >> 4, lm = lane & 15;
  const int z = blockIdx.z;
  const int bh = blockIdx.y, b = bh >> 1, h = bh & 1;
  const int q0 = blockIdx.x * 64;

  const unsigned short* Qg = QKV + (size_t)(z * 3 + 0) * SZ;
  const unsigned short* Kg = QKV + (size_t)(z * 3 + 1) * SZ;
  const unsigned short* Vg = QKV + (size_t)(z * 3 + 2) * SZ;

  // Q A-frags resident: row q0+w*16+lm, d-chunks c*32+quad*8 (+h*64)
  short8 aq[2];
#pragma unroll
  for (int c = 0; c < 2; ++c)
    aq[c] = *reinterpret_cast<const short8*>(
        Qg + ((size_t)(b * SS + q0 + w * 16 + lm)) * DD + h * 64 + c * 32 + quad * 8);

  f32x4 o[4];
#pragma unroll
  for (int i = 0; i < 4; ++i) o[i] = (f32x4){0.f, 0.f, 0.f, 0.f};
  float suml[4] = {0.f, 0.f, 0.f, 0.f};

  // V staging indices: idx = t + i*256; k = idx>>3, d0 = (idx&7)*8
  const int vk = t >> 3, vd0 = (t & 7) * 8;

  for (int kt = 0; kt < 8; ++kt) {
    const int k0 = kt * 64;
    __syncthreads();  // prior Vt fully consumed
#pragma unroll
    for (int i = 0; i < 2; ++i) {
      const int k = vk + i * 32;
      short8 vv = *reinterpret_cast<const short8*>(
          Vg + ((size_t)(b * SS + k0 + k)) * DD + h * 64 + vd0);
#pragma unroll
      for (int j = 0; j < 8; ++j) {
        const int d = vd0 + j;
        Vt[d * 72 + (k ^ (d & 56))] = (unsigned short)vv[j];
      }
    }
    __syncthreads();

    // S-tile: 4 n-tiles of 16 keys, contract over 64 dims (2 chunks)
    f32x4 sacc[4];
#pragma unroll
    for (int nt = 0; nt < 4; ++nt) sacc[nt] = (f32x4){0.f, 0.f, 0.f, 0.f};
#pragma unroll
    for (int c = 0; c < 2; ++c) {
#pragma unroll
      for (int nt = 0; nt < 4; ++nt) {
        short8 bk = *reinterpret_cast<const short8*>(
            Kg + ((size_t)(b * SS + k0 + nt * 16 + lm)) * DD + h * 64 + c * 32 + quad * 8);
        sacc[nt] = __builtin_amdgcn_mfma_f32_16x16x32_bf16(aq[c], bk, sacc[nt], 0, 0, 0);
      }
    }
    // exp, row-sum partials, P -> wave-private LDS (bf16)
#pragma unroll
    for (int nt = 0; nt < 4; ++nt) {
#pragma unroll
      for (int r = 0; r < 4; ++r) {
        float p = __expf(sacc[nt][r] * 0.125f);
        suml[r] += p;
        Pt[w][(quad * 4 + r) * 72 + nt * 16 + lm] = f2b(p);
      }
    }
    // PV: O[q][d] += P @ V   (A from Pt, B from swizzled Vt)
#pragma unroll
    for (int c = 0; c < 2; ++c) {
      short8 ap = *reinterpret_cast<const short8*>(&Pt[w][lm * 72 + c * 32 + quad * 8]);
#pragma unroll
      for (int dt = 0; dt < 4; ++dt) {
        const int d = dt * 16 + lm;
        short8 bv = *reinterpret_cast<const short8*>(
            &Vt[d * 72 + ((c * 32 + quad * 8) ^ (d & 56))]);
        o[dt] = __builtin_amdgcn_mfma_f32_16x16x32_bf16(ap, bv, o[dt], 0, 0, 0);
      }
    }
  }
  // reduce row sums across the 16 lanes of each quad
#pragma unroll
  for (int r = 0; r < 4; ++r) {
#pragma unroll
    for (int m = 1; m < 16; m <<= 1) suml[r] += __shfl_xor(suml[r], m);
  }
  // epilogue: ctx = Vsum - O/l
  const float* vsp = VS + (size_t)(z * BB + b) * DD + h * 64;
#pragma unroll
  for (int dt = 0; dt < 4; ++dt) {
    const int col = dt * 16 + lm;
    const float vs = vsp[col];
#pragma unroll
    for (int r = 0; r < 4; ++r) {
      const int row = q0 + w * 16 + quad * 4 + r;
      CTX[(size_t)z * SZ + ((size_t)(b * SS + row)) * DD + h * 64 + col] =
          f2b(vs - o[dt][r] / suml[r]);
    }
  }
}

// ---------------------------------------------------------------------------
// Fused LN pair: GRUIN[g][row] = 0.5*(LN_u1(DOUT[u1][row]) + LN_u2(DOUT[u2][row]))
// ---------------------------------------------------------------------------
__global__ __launch_bounds__(64) void ln_pair(
    const unsigned short* __restrict__ DOUT, const float* __restrict__ lng,
    const float* __restrict__ lnb, unsigned short* __restrict__ GRUIN) {
  const int row = blockIdx.x, g = blockIdx.y, t = threadIdx.x;
  const int u1t[3] = {1, 2, 0};
  const int u2t[3] = {3, 5, 4};
  float outA = 0.f, outB = 0.f;
#pragma unroll
  for (int half = 0; half < 2; ++half) {
    const int u = half == 0 ? u1t[g] : u2t[g];
    const unsigned short* x = DOUT + (size_t)u * SZ + (size_t)row * DD;
    float a = b2f(x[t]), c = b2f(x[t + 64]);
    float s = a + c, sq = a * a + c * c;
#pragma unroll
    for (int off = 32; off > 0; off >>= 1) {
      s += __shfl_down(s, off);
      sq += __shfl_down(sq, off);
    }
    s = __shfl(s, 0); sq = __shfl(sq, 0);
    float mean = s * (1.f / 128.f);
    float var = sq * (1.f / 128.f) - mean * mean;
    float rs = rsqrtf(var + 1e-5f);
    const float* gg = lng + u * 128;
    const float* bb = lnb + u * 128;
    outA += (a - mean) * rs * gg[t] + bb[t];
    outB += (c - mean) * rs * gg[t + 64] + bb[t + 64];
  }
  unsigned short* op = GRUIN + (size_t)g * SZ + (size_t)row * DD;
  op[t] = f2b(0.5f * outA);
  op[t + 64] = f2b(0.5f * outB);
}

// ---------------------------------------------------------------------------
// GRU v3: recurrence with fused x-projection, all-MFMA.
// ---------------------------------------------------------------------------
#define AST 136

__global__ __launch_bounds__(512, 2) void gru2(
    const unsigned short* __restrict__ GRUIN, const unsigned short* __restrict__ WB,
    const float* __restrict__ gbih, const float* __restrict__ gbhh,
    float* __restrict__ HS) {
  __shared__ unsigned short Abuf[2][16 * AST];
  const int rec = blockIdx.y, bg = blockIdx.x;
  const int g = rec >> 1, dir = rec & 1;
  const int t = threadIdx.x;
  const int w = t >> 6, lane = t & 63, q = lane >> 4, lm = lane & 15;
  const int q4 = q * 4;
  const int o = w * 16 + lm;

  short8 Bh[3][4], Bx[3][4];
  const unsigned short* whh = WB + WB_WHH + (size_t)rec * 49152;
  const unsigned short* wih = WB + WB_WIH + (size_t)rec * 49152;
#pragma unroll
  for (int gate = 0; gate < 3; ++gate)
#pragma unroll
    for (int c = 0; c < 4; ++c) {
      Bh[gate][c] = *reinterpret_cast<const short8*>(
          whh + (size_t)(gate * 128 + o) * 128 + c * 32 + q * 8);
      Bx[gate][c] = *reinterpret_cast<const short8*>(
          wih + (size_t)(gate * 128 + o) * 128 + c * 32 + q * 8);
    }
  const float br = gbih[rec * 384 + o] + gbhh[rec * 384 + o];
  const float bz = gbih[rec * 384 + 128 + o] + gbhh[rec * 384 + 128 + o];
  const float bxn = gbih[rec * 384 + 256 + o];
  const float bhn = gbhh[rec * 384 + 256 + o];

  float h[4] = {0.f, 0.f, 0.f, 0.f};
  float hsum[4] = {0.f, 0.f, 0.f, 0.f};
  for (int i = t; i < 16 * AST; i += 512) Abuf[0][i] = 0;

  const unsigned short* xb = GRUIN + (size_t)g * SZ + ((size_t)(bg * 16 + lm)) * SS * DD;

  short8 xf[2][4];
#pragma unroll
  for (int pp = 0; pp < 2; ++pp) {
    const int tt = dir ? (SS - 1 - pp) : pp;
#pragma unroll
    for (int c = 0; c < 4; ++c)
      xf[pp][c] = *reinterpret_cast<const short8*>(xb + (size_t)tt * DD + c * 32 + q * 8);
  }
  __syncthreads();

#pragma unroll 2
  for (int s = 0; s < SS; ++s) {
    const int p = s & 1;
    short8 ah[4];
#pragma unroll
    for (int c = 0; c < 4; ++c)
      ah[c] = *reinterpret_cast<const short8*>(&Abuf[p][lm * AST + c * 32 + q * 8]);
    f32x4 ar = {br, br, br, br};
    f32x4 az = {bz, bz, bz, bz};
    f32x4 axn = {bxn, bxn, bxn, bxn};
    f32x4 ahn = {bhn, bhn, bhn, bhn};
#pragma unroll
    for (int c = 0; c < 4; ++c) {
      ar = __builtin_amdgcn_mfma_f32_16x16x32_bf16(ah[c], Bh[0][c], ar, 0, 0, 0);
      az = __builtin_amdgcn_mfma_f32_16x16x32_bf16(ah[c], Bh[1][c], az, 0, 0, 0);
      ahn = __builtin_amdgcn_mfma_f32_16x16x32_bf16(ah[c], Bh[2][c], ahn, 0, 0, 0);
      ar = __builtin_amdgcn_mfma_f32_16x16x32_bf16(xf[p][c], Bx[0][c], ar, 0, 0, 0);
      az = __builtin_amdgcn_mfma_f32_16x16x32_bf16(xf[p][c], Bx[1][c], az, 0, 0, 0);
      axn = __builtin_amdgcn_mfma_f32_16x16x32_bf16(xf[p][c], Bx[2][c], axn, 0, 0, 0);
    }
    {
      int sn = s + 2; if (sn > SS - 1) sn = SS - 1;
      const int tn = dir ? (SS - 1 - sn) : sn;
#pragma unroll
      for (int c = 0; c < 4; ++c)
        xf[p][c] = *reinterpret_cast<const short8*>(xb + (size_t)tn * DD + c * 32 + q * 8);
    }
#pragma unroll
    for (int i = 0; i < 4; ++i) {
      float r = sigmoidf_(ar[i]);
      float z = sigmoidf_(az[i]);
      float nn = tanhf_(axn[i] + r * ahn[i]);
      h[i] = (1.f - z) * nn + z * h[i];
      hsum[i] += h[i];
      Abuf[p ^ 1][(q4 + i) * AST + o] = f2b(h[i]);
    }
    __syncthreads();
  }
#pragma unroll
  for (int i = 0; i < 4; ++i)
    HS[((size_t)rec * BB + bg * 16 + q4 + i) * 128 + o] = hsum[i];
}

// ---------------------------------------------------------------------------
// Head: pooled -> Linear -> BN(eval) -> ReLU6 -> Linear.  grid=64, block=256.
// ---------------------------------------------------------------------------
__global__ __launch_bounds__(256) void head_kernel(
    const float* __restrict__ HS, const float* __restrict__ fW1,
    const float* __restrict__ fb1, const float* __restrict__ bng,
    const float* __restrict__ bnb, const float* __restrict__ fW2,
    const float* __restrict__ fb2, float* __restrict__ out) {
  __shared__ float pl[384];
  __shared__ float h1[256];
  int b = blockIdx.x, n = threadIdx.x;
  {
    int j = n;
    int seg = j >> 7, oo = j & 127;
    pl[j] = (HS[((size_t)seg * BB + b) * 128 + oo] +
             HS[((size_t)(seg + 3) * BB + b) * 128 + oo]) * (0.5f / 512.f);
  }
  if (n < 128) {
    int j = 256 + n;
    int seg = j >> 7, oo = j & 127;
    pl[j] = (HS[((size_t)seg * BB + b) * 128 + oo] +
             HS[((size_t)(seg + 3) * BB + b) * 128 + oo]) * (0.5f / 512.f);
  }
  __syncthreads();
  float acc = fb1[n];
  for (int k = 0; k < 384; ++k) acc += pl[k] * fW1[k * 256 + n];
  float hv = acc * rsqrtf(1.f + 1e-5f) * bng[n] + bnb[n];
  hv = fminf(fmaxf(hv, 0.f), 6.f);
  h1[n] = hv;
  __syncthreads();
  if (n < 8) {
    float a2 = fb2[n];
    for (int k = 0; k < 256; ++k) a2 += h1[k] * fW2[k * 8 + n];
    out[b * 8 + n] = a2;
  }
}

// ---------------------------------------------------------------------------
extern "C" void kernel_launch(void* const* d_in, const int* in_sizes, int n_in,
                              void* d_out, int out_size, void* d_ws,
                              size_t ws_size, hipStream_t stream) {
  (void)in_sizes; (void)n_in; (void)out_size; (void)ws_size;
  const float* text = (const float*)d_in[0];
  const float* vis  = (const float*)d_in[1];
  const float* aud  = (const float*)d_in[2];
  const float* fc1W = (const float*)d_in[3];
  const float* fc1b = (const float*)d_in[4];
  const float* fc2W = (const float*)d_in[5];
  const float* fc2b = (const float*)d_in[6];
  const float* fc3W = (const float*)d_in[7];
  const float* fc3b = (const float*)d_in[8];
  const float* Wq = (const float*)d_in[9];
  const float* bq = (const float*)d_in[10];
  const float* Wk = (const float*)d_in[11];
  const float* bk = (const float*)d_in[12];
  const float* Wv = (const float*)d_in[13];
  const float* bv = (const float*)d_in[14];
  const float* Wd = (const float*)d_in[15];
  const float* bd = (const float*)d_in[16];
  const float* lng = (const float*)d_in[17];
  const float* lnb = (const float*)d_in[18];
  const float* gWih = (const float*)d_in[19];
  const float* gWhh = (const float*)d_in[20];
  const float* gbih = (const float*)d_in[21];
  const float* gbhh = (const float*)d_in[22];
  const float* fW1 = (const float*)d_in[23];
  const float* fb1 = (const float*)d_in[24];
  const float* bng = (const float*)d_in[25];
  const float* bnb = (const float*)d_in[26];
  const float* fW2 = (const float*)d_in[27];
  const float* fb2 = (const float*)d_in[28];
  float* out = (float*)d_out;

  unsigned short* WSB = (unsigned short*)d_ws;
  unsigned short* T   = WSB;
  unsigned short* Vv  = WSB + SZ;
  unsigned short* Aa  = WSB + 2 * SZ;
  unsigned short* QKV = WSB + 3 * SZ;
  unsigned short* CTX = WSB + 12 * SZ;
  unsigned short* DOUT = WSB;
  unsigned short* GRUIN = WSB + 6 * SZ;
  unsigned short* WB  = WSB + 18 * SZ;
  float* VS = (float*)(WSB + 18 * SZ + 1048576);
  float* HS = VS + 6 * 64 * 128;

  prep_kernel<<<dim3(1024), dim3(256), 0, stream>>>(
      fc1W, fc2W, fc3W, Wq, Wk, Wv, Wd, gWih, gWhh, WB);

  {
    GArgs ga{};
    ga.g[0] = {text, WB + WB_P1, fc1b, T, 300, 320, 0, 1};
    ga.g[1] = {vis,  WB + WB_P2, fc2b, Vv, 35, 64, 0, 1};
    ga.g[2] = {aud,  WB + WB_P3, fc3b, Aa, 74, 96, 0, 1};
    gemm_b<<<dim3(256, 1, 3), dim3(256), 0, stream>>>(ga);
  }

  const int qsel[6] = {0, 2, 0, 1, 1, 2};
  const int ksel[6] = {2, 0, 1, 0, 2, 1};
  unsigned short* proj[3] = {T, Vv, Aa};
  const float* qkvbias[3] = {bq, bk, bv};

  for (int phase = 0; phase < 2; ++phase) {
    GArgs ga{};
    for (int ul = 0; ul < 3; ++ul) {
      int u = phase * 3 + ul;
      for (int op = 0; op < 3; ++op) {
        int z = ul * 3 + op;
        ga.g[z] = {proj[op == 0 ? qsel[u] : ksel[u]],
                   WB + WB_QKVD + op * 98304 + u * 16384,
                   qkvbias[op] + u * 128,
                   QKV + (size_t)z * SZ, 128, 128, 1, 1};
      }
    }
    gemm_b<<<dim3(256, 1, 9), dim3(256), 0, stream>>>(ga);
    vsum_kernel<<<dim3(BB, 3), dim3(128), 0, stream>>>(QKV, VS + phase * 3 * BB * DD);
    attn_mfma<<<dim3(8, 128, 3), dim3(256), 0, stream>>>(
        QKV, VS + phase * 3 * BB * DD, CTX + (size_t)phase * 3 * SZ);
  }

  {
    GArgs ga{};
    for (int u = 0; u < 6; ++u)
      ga.g[u] = {CTX + (size_t)u * SZ, WB + WB_QKVD + 3 * 98304 + u * 16384,
                 bd + u * 128, DOUT + (size_t)u * SZ, 128, 128, 1, 1};
    gemm_b<<<dim3(256, 1, 6), dim3(256), 0, stream>>>(ga);
  }

  ln_pair<<<dim3(NROW, 3), dim3(64), 0, stream>>>(DOUT, lng, lnb, GRUIN);
  gru2<<<dim3(4, 6), dim3(512), 0, stream>>>(GRUIN, WB, gbih, gbhh, HS);
  head_kernel<<<dim3(BB), dim3(256), 0, stream>>>(HS, fW1, fb1, bng, bnb, fW2, fb2, out);
}

// Round 5
// 1301.179 us; speedup vs baseline: 3.2707x; 1.0086x over previous
//
#include <hip/hip_runtime.h>
#include <hip/hip_bf16.h>

// Problem constants
#define BB 64
#define SS 512
#define DD 128
#define NROW (BB * SS)          // 32768
#define SZ ((size_t)NROW * DD)  // 4,194,304 elems per [B,S,128] slice

typedef __attribute__((ext_vector_type(8))) short short8;
typedef __attribute__((ext_vector_type(4))) float f32x4;

// WB (converted-weight buffer) element offsets, all bf16:
#define WB_P1 0          // fc1W^T [128][320] (K=300 pad 320)
#define WB_P2 40960      // fc2W^T [128][64]  (K=35 pad 64)
#define WB_P3 49152      // fc3W^T [128][96]  (K=74 pad 96)
#define WB_QKVD 61440    // [4 op][6 u][128 n][128 k]
#define WB_WIH 454656    // [6 rec][384 n][128 k]
#define WB_WHH 749568    // [6 rec][384 n][128 k]
#define WB_TOTAL 1044480

__device__ __forceinline__ float sigmoidf_(float x) { return 1.f / (1.f + __expf(-x)); }
__device__ __forceinline__ float tanhf_(float x) {
  x = fminf(fmaxf(x, -15.f), 15.f);
  float e = __expf(2.f * x);
  return (e - 1.f) / (e + 1.f);
}
__device__ __forceinline__ float b2f(unsigned short u) {
  union { unsigned int i; float f; } x; x.i = ((unsigned int)u) << 16; return x.f;
}
__device__ __forceinline__ unsigned short f2b(float f) {
  __hip_bfloat16 b = __float2bfloat16(f);
  return *reinterpret_cast<unsigned short*>(&b);
}

// ---------------------------------------------------------------------------
// Weight prep: transpose/convert all weights into WB (bf16, [N][Kpad]).
// ---------------------------------------------------------------------------
__global__ __launch_bounds__(256) void prep_kernel(
    const float* __restrict__ fc1W, const float* __restrict__ fc2W,
    const float* __restrict__ fc3W, const float* __restrict__ Wq,
    const float* __restrict__ Wk, const float* __restrict__ Wv,
    const float* __restrict__ Wd, const float* __restrict__ gWih,
    const float* __restrict__ gWhh, unsigned short* __restrict__ WB) {
  for (int idx = blockIdx.x * 256 + threadIdx.x; idx < WB_TOTAL;
       idx += gridDim.x * 256) {
    float v;
    if (idx < WB_P2) {
      int n = idx / 320, k = idx % 320;
      v = (k < 300) ? fc1W[k * 128 + n] : 0.f;
    } else if (idx < WB_P3) {
      int r = idx - WB_P2; int n = r >> 6, k = r & 63;
      v = (k < 35) ? fc2W[k * 128 + n] : 0.f;
    } else if (idx < WB_QKVD) {
      int r = idx - WB_P3; int n = r / 96, k = r % 96;
      v = (k < 74) ? fc3W[k * 128 + n] : 0.f;
    } else if (idx < WB_WIH) {
      int r = idx - WB_QKVD;
      int op = r / 98304; int r2 = r % 98304;
      int u = r2 >> 14; int r3 = r2 & 16383;
      int n = r3 >> 7, k = r3 & 127;
      const float* src = (op == 0) ? Wq : (op == 1) ? Wk : (op == 2) ? Wv : Wd;
      v = src[u * 16384 + k * 128 + n];
    } else if (idx < WB_WHH) {
      v = gWih[idx - WB_WIH];
    } else {
      v = gWhh[idx - WB_WHH];
    }
    WB[idx] = f2b(v);
  }
}

// ---------------------------------------------------------------------------
// Batched MFMA GEMM: C[32768, N] = A[32768,Ka] @ W^T + bias, per blockIdx.z.
// N-tile via blockIdx.y (128 cols each).  mode 0: C[m*128+col] (cbf sel dtype).
// mode 1: GX2 permuted store [bg][s][b16][384] with step reversal by dirf
// (for the GRU: s = dirf ? 511-ss : ss, row m = b*512+ss, col = gate*128+unit).
// ---------------------------------------------------------------------------
struct GArg {
  const void* A; const unsigned short* W; const float* bias; void* C;
  int Ka, Kp, abf, cbf, mode, dirf;
};
struct GArgs { GArg g[18]; };

__global__ __launch_bounds__(256) void gemm_b(GArgs args) {
  const GArg ga = args.g[blockIdx.z];
  const int ny = blockIdx.y;
  __shared__ unsigned short As[128 * 40];
  __shared__ unsigned short Ws[128 * 40];
  const int t = threadIdx.x;
  const int w = t >> 6, lane = t & 63, q = lane >> 4, lm = lane & 15;
  const int wm = w >> 1, wn = w & 1;
  const int m0 = blockIdx.x * 128;
  const int row = t >> 1, cb = (t & 1) * 16;
  f32x4 acc[4][4];
#pragma unroll
  for (int i = 0; i < 4; ++i)
#pragma unroll
    for (int j = 0; j < 4; ++j) acc[i][j] = (f32x4){0.f, 0.f, 0.f, 0.f};

  for (int kt = 0; kt < ga.Kp; kt += 32) {
    if (ga.abf) {
      const unsigned short* Ag =
          (const unsigned short*)ga.A + (size_t)(m0 + row) * ga.Ka + kt + cb;
      short8 v0 = *reinterpret_cast<const short8*>(Ag);
      short8 v1 = *reinterpret_cast<const short8*>(Ag + 8);
      *reinterpret_cast<short8*>(&As[row * 40 + cb]) = v0;
      *reinterpret_cast<short8*>(&As[row * 40 + cb + 8]) = v1;
    } else {
      const float* Ag = (const float*)ga.A + (size_t)(m0 + row) * ga.Ka + kt + cb;
      unsigned short tmp[16];
#pragma unroll
      for (int j = 0; j < 16; ++j) {
        int k = kt + cb + j;
        tmp[j] = (k < ga.Ka) ? f2b(Ag[j]) : 0;
      }
      *reinterpret_cast<short8*>(&As[row * 40 + cb]) =
          *reinterpret_cast<short8*>(&tmp[0]);
      *reinterpret_cast<short8*>(&As[row * 40 + cb + 8]) =
          *reinterpret_cast<short8*>(&tmp[8]);
    }
    {
      const unsigned short* Wg =
          ga.W + (size_t)(ny * 128 + row) * ga.Kp + kt + cb;
      short8 v0 = *reinterpret_cast<const short8*>(Wg);
      short8 v1 = *reinterpret_cast<const short8*>(Wg + 8);
      *reinterpret_cast<short8*>(&Ws[row * 40 + cb]) = v0;
      *reinterpret_cast<short8*>(&Ws[row * 40 + cb + 8]) = v1;
    }
    __syncthreads();
    short8 af[4], bfv[4];
#pragma unroll
    for (int mi = 0; mi < 4; ++mi)
      af[mi] = *reinterpret_cast<const short8*>(
          &As[(wm * 64 + mi * 16 + lm) * 40 + q * 8]);
#pragma unroll
    for (int ni = 0; ni < 4; ++ni)
      bfv[ni] = *reinterpret_cast<const short8*>(
          &Ws[(wn * 64 + ni * 16 + lm) * 40 + q * 8]);
#pragma unroll
    for (int mi = 0; mi < 4; ++mi)
#pragma unroll
      for (int ni = 0; ni < 4; ++ni)
        acc[mi][ni] = __builtin_amdgcn_mfma_f32_16x16x32_bf16(
            af[mi], bfv[ni], acc[mi][ni], 0, 0, 0);
    __syncthreads();
  }
#pragma unroll
  for (int ni = 0; ni < 4; ++ni) {
    const int colg = ny * 128 + wn * 64 + ni * 16 + lm;
    const float bv = ga.bias[colg];
#pragma unroll
    for (int mi = 0; mi < 4; ++mi) {
      const int rg = m0 + wm * 64 + mi * 16 + q * 4;
#pragma unroll
      for (int r = 0; r < 4; ++r) {
        float v = acc[mi][ni][r] + bv;
        if (ga.mode == 1) {
          int m = rg + r, b = m >> 9, ss = m & 511;
          int s = ga.dirf ? (511 - ss) : ss;
          ((unsigned short*)ga.C)[((((size_t)(b >> 4)) * 512 + s) * 16 +
                                   (b & 15)) * 384 + colg] = f2b(v);
        } else if (ga.cbf) {
          ((unsigned short*)ga.C)[(size_t)(rg + r) * 128 + colg] = f2b(v);
        } else {
          ((float*)ga.C)[(size_t)(rg + r) * 128 + colg] = v;
        }
      }
    }
  }
}

// ---------------------------------------------------------------------------
// V column sums: VS[z][b][128] = sum_s V_z[b][s][:]   (V bf16)
// ---------------------------------------------------------------------------
__global__ __launch_bounds__(128) void vsum_kernel(
    const unsigned short* __restrict__ QKV, float* __restrict__ VS) {
  int b = blockIdx.x, z = blockIdx.y, d = threadIdx.x;
  const unsigned short* p = QKV + (size_t)(z * 3 + 2) * SZ + (size_t)b * SS * DD + d;
  float s = 0.f;
  for (int k = 0; k < SS; ++k) s += b2f(p[(size_t)k * DD]);
  VS[(z * BB + b) * DD + d] = s;
}

// ---------------------------------------------------------------------------
// MFMA attention (probs = 1 - softmax): ctx = Vsum - softmax(QK^T/8) @ V.
// ---------------------------------------------------------------------------
__global__ __launch_bounds__(256) void attn_mfma(
    const unsigned short* __restrict__ QKV, const float* __restrict__ VS,
    unsigned short* __restrict__ CTX) {
  __shared__ unsigned short Vt[64 * 72];       // [d][k ^ (d&56)]
  __shared__ unsigned short Pt[4][16 * 72];    // per-wave [q][k]
  const int t = threadIdx.x;
  const int w = t >> 6, lane = t & 63, quad = lane >> 4, lm = lane & 15;
  const int z = blockIdx.z;
  const int bh = blockIdx.y, b = bh >> 1, h = bh & 1;
  const int q0 = blockIdx.x * 64;

  const unsigned short* Qg = QKV + (size_t)(z * 3 + 0) * SZ;
  const unsigned short* Kg = QKV + (size_t)(z * 3 + 1) * SZ;
  const unsigned short* Vg = QKV + (size_t)(z * 3 + 2) * SZ;

  short8 aq[2];
#pragma unroll
  for (int c = 0; c < 2; ++c)
    aq[c] = *reinterpret_cast<const short8*>(
        Qg + ((size_t)(b * SS + q0 + w * 16 + lm)) * DD + h * 64 + c * 32 + quad * 8);

  f32x4 o[4];
#pragma unroll
  for (int i = 0; i < 4; ++i) o[i] = (f32x4){0.f, 0.f, 0.f, 0.f};
  float suml[4] = {0.f, 0.f, 0.f, 0.f};

  const int vk = t >> 3, vd0 = (t & 7) * 8;

  for (int kt = 0; kt < 8; ++kt) {
    const int k0 = kt * 64;
    __syncthreads();
#pragma unroll
    for (int i = 0; i < 2; ++i) {
      const int k = vk + i * 32;
      short8 vv = *reinterpret_cast<const short8*>(
          Vg + ((size_t)(b * SS + k0 + k)) * DD + h * 64 + vd0);
#pragma unroll
      for (int j = 0; j < 8; ++j) {
        const int d = vd0 + j;
        Vt[d * 72 + (k ^ (d & 56))] = (unsigned short)vv[j];
      }
    }
    __syncthreads();

    f32x4 sacc[4];
#pragma unroll
    for (int nt = 0; nt < 4; ++nt) sacc[nt] = (f32x4){0.f, 0.f, 0.f, 0.f};
#pragma unroll
    for (int c = 0; c < 2; ++c) {
#pragma unroll
      for (int nt = 0; nt < 4; ++nt) {
        short8 bk = *reinterpret_cast<const short8*>(
            Kg + ((size_t)(b * SS + k0 + nt * 16 + lm)) * DD + h * 64 + c * 32 + quad * 8);
        sacc[nt] = __builtin_amdgcn_mfma_f32_16x16x32_bf16(aq[c], bk, sacc[nt], 0, 0, 0);
      }
    }
#pragma unroll
    for (int nt = 0; nt < 4; ++nt) {
#pragma unroll
      for (int r = 0; r < 4; ++r) {
        float p = __expf(sacc[nt][r] * 0.125f);
        suml[r] += p;
        Pt[w][(quad * 4 + r) * 72 + nt * 16 + lm] = f2b(p);
      }
    }
#pragma unroll
    for (int c = 0; c < 2; ++c) {
      short8 ap = *reinterpret_cast<const short8*>(&Pt[w][lm * 72 + c * 32 + quad * 8]);
#pragma unroll
      for (int dt = 0; dt < 4; ++dt) {
        const int d = dt * 16 + lm;
        short8 bv = *reinterpret_cast<const short8*>(
            &Vt[d * 72 + ((c * 32 + quad * 8) ^ (d & 56))]);
        o[dt] = __builtin_amdgcn_mfma_f32_16x16x32_bf16(ap, bv, o[dt], 0, 0, 0);
      }
    }
  }
#pragma unroll
  for (int r = 0; r < 4; ++r) {
#pragma unroll
    for (int m = 1; m < 16; m <<= 1) suml[r] += __shfl_xor(suml[r], m);
  }
  const float* vsp = VS + (size_t)(z * BB + b) * DD + h * 64;
#pragma unroll
  for (int dt = 0; dt < 4; ++dt) {
    const int col = dt * 16 + lm;
    const float vs = vsp[col];
#pragma unroll
    for (int r = 0; r < 4; ++r) {
      const int row = q0 + w * 16 + quad * 4 + r;
      CTX[(size_t)z * SZ + ((size_t)(b * SS + row)) * DD + h * 64 + col] =
          f2b(vs - o[dt][r] / suml[r]);
    }
  }
}

// ---------------------------------------------------------------------------
// Fused LN pair: GRUIN[g][row] = 0.5*(LN_u1(DOUT[u1][row]) + LN_u2(DOUT[u2][row]))
// ---------------------------------------------------------------------------
__global__ __launch_bounds__(64) void ln_pair(
    const unsigned short* __restrict__ DOUT, const float* __restrict__ lng,
    const float* __restrict__ lnb, unsigned short* __restrict__ GRUIN) {
  const int row = blockIdx.x, g = blockIdx.y, t = threadIdx.x;
  const int u1t[3] = {1, 2, 0};
  const int u2t[3] = {3, 5, 4};
  float outA = 0.f, outB = 0.f;
#pragma unroll
  for (int half = 0; half < 2; ++half) {
    const int u = half == 0 ? u1t[g] : u2t[g];
    const unsigned short* x = DOUT + (size_t)u * SZ + (size_t)row * DD;
    float a = b2f(x[t]), c = b2f(x[t + 64]);
    float s = a + c, sq = a * a + c * c;
#pragma unroll
    for (int off = 32; off > 0; off >>= 1) {
      s += __shfl_down(s, off);
      sq += __shfl_down(sq, off);
    }
    s = __shfl(s, 0); sq = __shfl(sq, 0);
    float mean = s * (1.f / 128.f);
    float var = sq * (1.f / 128.f) - mean * mean;
    float rs = rsqrtf(var + 1e-5f);
    const float* gg = lng + u * 128;
    const float* bb = lnb + u * 128;
    outA += (a - mean) * rs * gg[t] + bb[t];
    outB += (c - mean) * rs * gg[t + 64] + bb[t + 64];
  }
  unsigned short* op = GRUIN + (size_t)g * SZ + (size_t)row * DD;
  op[t] = f2b(0.5f * outA);
  op[t + 64] = f2b(0.5f * outB);
}

// ---------------------------------------------------------------------------
// GRU v4: recurrence-only MFMA loop; gx precomputed step-major in thread order.
// grid = (4 batch-groups of 16, 6 recs), block = 512 (8 waves).
// GX2[rec][bg][s][b16][384], step index pre-reversed for bwd recs, so the
// loop always walks forward.  Thread reads its own 12 gx ushorts per step
// (register ring, prefetch 4 steps ahead, one address + 12 imm offsets).
// In-loop MFMAs: 12 (H @ Whh^T only, chains 4 deep).  1 barrier/step.
// ---------------------------------------------------------------------------
#define AST 136

__global__ __launch_bounds__(512, 1) void gru3(
    const unsigned short* __restrict__ GX2, const unsigned short* __restrict__ WB,
    const float* __restrict__ gbhh, float* __restrict__ HS) {
  __shared__ unsigned short Abuf[2][16 * AST];
  const int rec = blockIdx.y, bg = blockIdx.x;
  const int t = threadIdx.x;
  const int w = t >> 6, lane = t & 63, q = lane >> 4, lm = lane & 15;
  const int q4 = q * 4;
  const int o = w * 16 + lm;

  short8 Bh[3][4];
  const unsigned short* whh = WB + WB_WHH + (size_t)rec * 49152;
#pragma unroll
  for (int gate = 0; gate < 3; ++gate)
#pragma unroll
    for (int c = 0; c < 4; ++c)
      Bh[gate][c] = *reinterpret_cast<const short8*>(
          whh + (size_t)(gate * 128 + o) * 128 + c * 32 + q * 8);
  const float br = gbhh[rec * 384 + o];
  const float bz = gbhh[rec * 384 + 128 + o];
  const float bhn = gbhh[rec * 384 + 256 + o];

  float h[4] = {0.f, 0.f, 0.f, 0.f};
  float hsum[4] = {0.f, 0.f, 0.f, 0.f};
  for (int i = t; i < 16 * AST; i += 512) Abuf[0][i] = 0;

  // per-thread gx base: step-block is [b16][384]; this thread's cells are
  // (q4+i)*384 + gate*128 + o, i<4, gate<3.
  const unsigned short* gxt =
      GX2 + ((size_t)(rec * 4 + bg) * 512) * 6144 + q4 * 384 + o;

  unsigned short ring[4][12];
#pragma unroll
  for (int pp = 0; pp < 4; ++pp)
#pragma unroll
    for (int i = 0; i < 4; ++i)
#pragma unroll
      for (int j = 0; j < 3; ++j)
        ring[pp][i * 3 + j] = gxt[(size_t)pp * 6144 + i * 384 + j * 128];
  __syncthreads();

#pragma unroll 4
  for (int s = 0; s < SS; ++s) {
    const int p = s & 1, slot = s & 3;
    float gx[12];
#pragma unroll
    for (int k = 0; k < 12; ++k) gx[k] = b2f(ring[slot][k]);
    // prefetch step s+4 into the slot just consumed
    int sp = s + 4; if (sp > SS - 1) sp = SS - 1;
    const unsigned short* gp = gxt + (size_t)sp * 6144;
#pragma unroll
    for (int i = 0; i < 4; ++i)
#pragma unroll
      for (int j = 0; j < 3; ++j) ring[slot][i * 3 + j] = gp[i * 384 + j * 128];

    short8 ah[4];
#pragma unroll
    for (int c = 0; c < 4; ++c)
      ah[c] = *reinterpret_cast<const short8*>(&Abuf[p][lm * AST + c * 32 + q * 8]);
    f32x4 ar = {br, br, br, br};
    f32x4 az = {bz, bz, bz, bz};
    f32x4 ahn = {bhn, bhn, bhn, bhn};
#pragma unroll
    for (int c = 0; c < 4; ++c) {
      ar = __builtin_amdgcn_mfma_f32_16x16x32_bf16(ah[c], Bh[0][c], ar, 0, 0, 0);
      az = __builtin_amdgcn_mfma_f32_16x16x32_bf16(ah[c], Bh[1][c], az, 0, 0, 0);
      ahn = __builtin_amdgcn_mfma_f32_16x16x32_bf16(ah[c], Bh[2][c], ahn, 0, 0, 0);
    }
#pragma unroll
    for (int i = 0; i < 4; ++i) {
      float r = sigmoidf_(gx[i * 3 + 0] + ar[i]);
      float z = sigmoidf_(gx[i * 3 + 1] + az[i]);
      float nn = tanhf_(gx[i * 3 + 2] + r * ahn[i]);
      h[i] = (1.f - z) * nn + z * h[i];
      hsum[i] += h[i];
      Abuf[p ^ 1][(q4 + i) * AST + o] = f2b(h[i]);
    }
    __syncthreads();
  }
#pragma unroll
  for (int i = 0; i < 4; ++i)
    HS[((size_t)rec * BB + bg * 16 + q4 + i) * 128 + o] = hsum[i];
}

// ---------------------------------------------------------------------------
// Head: pooled -> Linear -> BN(eval) -> ReLU6 -> Linear.  grid=64, block=256.
// ---------------------------------------------------------------------------
__global__ __launch_bounds__(256) void head_kernel(
    const float* __restrict__ HS, const float* __restrict__ fW1,
    const float* __restrict__ fb1, const float* __restrict__ bng,
    const float* __restrict__ bnb, const float* __restrict__ fW2,
    const float* __restrict__ fb2, float* __restrict__ out) {
  __shared__ float pl[384];
  __shared__ float h1[256];
  int b = blockIdx.x, n = threadIdx.x;
  {
    int j = n;
    int seg = j >> 7, oo = j & 127;
    pl[j] = (HS[((size_t)seg * BB + b) * 128 + oo] +
             HS[((size_t)(seg + 3) * BB + b) * 128 + oo]) * (0.5f / 512.f);
  }
  if (n < 128) {
    int j = 256 + n;
    int seg = j >> 7, oo = j & 127;
    pl[j] = (HS[((size_t)seg * BB + b) * 128 + oo] +
             HS[((size_t)(seg + 3) * BB + b) * 128 + oo]) * (0.5f / 512.f);
  }
  __syncthreads();
  float acc = fb1[n];
  for (int k = 0; k < 384; ++k) acc += pl[k] * fW1[k * 256 + n];
  float hv = acc * rsqrtf(1.f + 1e-5f) * bng[n] + bnb[n];
  hv = fminf(fmaxf(hv, 0.f), 6.f);
  h1[n] = hv;
  __syncthreads();
  if (n < 8) {
    float a2 = fb2[n];
    for (int k = 0; k < 256; ++k) a2 += h1[k] * fW2[k * 8 + n];
    out[b * 8 + n] = a2;
  }
}

// ---------------------------------------------------------------------------
extern "C" void kernel_launch(void* const* d_in, const int* in_sizes, int n_in,
                              void* d_out, int out_size, void* d_ws,
                              size_t ws_size, hipStream_t stream) {
  (void)in_sizes; (void)n_in; (void)out_size; (void)ws_size;
  const float* text = (const float*)d_in[0];
  const float* vis  = (const float*)d_in[1];
  const float* aud  = (const float*)d_in[2];
  const float* fc1W = (const float*)d_in[3];
  const float* fc1b = (const float*)d_in[4];
  const float* fc2W = (const float*)d_in[5];
  const float* fc2b = (const float*)d_in[6];
  const float* fc3W = (const float*)d_in[7];
  const float* fc3b = (const float*)d_in[8];
  const float* Wq = (const float*)d_in[9];
  const float* bq = (const float*)d_in[10];
  const float* Wk = (const float*)d_in[11];
  const float* bk = (const float*)d_in[12];
  const float* Wv = (const float*)d_in[13];
  const float* bv = (const float*)d_in[14];
  const float* Wd = (const float*)d_in[15];
  const float* bd = (const float*)d_in[16];
  const float* lng = (const float*)d_in[17];
  const float* lnb = (const float*)d_in[18];
  const float* gWih = (const float*)d_in[19];
  const float* gWhh = (const float*)d_in[20];
  const float* gbih = (const float*)d_in[21];
  const float* gbhh = (const float*)d_in[22];
  const float* fW1 = (const float*)d_in[23];
  const float* fb1 = (const float*)d_in[24];
  const float* bng = (const float*)d_in[25];
  const float* bnb = (const float*)d_in[26];
  const float* fW2 = (const float*)d_in[27];
  const float* fb2 = (const float*)d_in[28];
  float* out = (float*)d_out;

  // Workspace (bf16 slices of SZ elems = 8.39 MB each), ~179 MB total:
  //  slices 0..2 : T, Vv, Aa          -> later DOUT u=0..5 (slices 0..5)
  //  slices 3..11: QKV (per phase)    -> dead after attn
  //  slices 12..17: CTX u=0..5
  //  slices 0..17: GX2 overlay [6 rec][4 bg][512 s][16 b16][384]  (phase D)
  //  slices 18..20: GRUIN g=0..2 (alive through GX gemm)
  //  then WB (bf16), VS (fp32), HS (fp32)
  unsigned short* WSB = (unsigned short*)d_ws;
  unsigned short* T   = WSB;
  unsigned short* Vv  = WSB + SZ;
  unsigned short* Aa  = WSB + 2 * SZ;
  unsigned short* QKV = WSB + 3 * SZ;
  unsigned short* CTX = WSB + 12 * SZ;
  unsigned short* DOUT = WSB;
  unsigned short* GX2 = WSB;              // slices 0..17 (75.5M elems)
  unsigned short* GRUIN = WSB + 18 * SZ;  // slices 18..20
  unsigned short* WB  = WSB + 21 * SZ;
  float* VS = (float*)(WSB + 21 * SZ + 1048576);
  float* HS = VS + 6 * 64 * 128;

  prep_kernel<<<dim3(1024), dim3(256), 0, stream>>>(
      fc1W, fc2W, fc3W, Wq, Wk, Wv, Wd, gWih, gWhh, WB);

  {
    GArgs ga{};
    ga.g[0] = {text, WB + WB_P1, fc1b, T, 300, 320, 0, 1, 0, 0};
    ga.g[1] = {vis,  WB + WB_P2, fc2b, Vv, 35, 64, 0, 1, 0, 0};
    ga.g[2] = {aud,  WB + WB_P3, fc3b, Aa, 74, 96, 0, 1, 0, 0};
    gemm_b<<<dim3(256, 1, 3), dim3(256), 0, stream>>>(ga);
  }

  const int qsel[6] = {0, 2, 0, 1, 1, 2};
  const int ksel[6] = {2, 0, 1, 0, 2, 1};
  unsigned short* proj[3] = {T, Vv, Aa};
  const float* qkvbias[3] = {bq, bk, bv};

  for (int phase = 0; phase < 2; ++phase) {
    GArgs ga{};
    for (int ul = 0; ul < 3; ++ul) {
      int u = phase * 3 + ul;
      for (int op = 0; op < 3; ++op) {
        int z = ul * 3 + op;
        ga.g[z] = {proj[op == 0 ? qsel[u] : ksel[u]],
                   WB + WB_QKVD + op * 98304 + u * 16384,
                   qkvbias[op] + u * 128,
                   QKV + (size_t)z * SZ, 128, 128, 1, 1, 0, 0};
      }
    }
    gemm_b<<<dim3(256, 1, 9), dim3(256), 0, stream>>>(ga);
    vsum_kernel<<<dim3(BB, 3), dim3(128), 0, stream>>>(QKV, VS + phase * 3 * BB * DD);
    attn_mfma<<<dim3(8, 128, 3), dim3(256), 0, stream>>>(
        QKV, VS + phase * 3 * BB * DD, CTX + (size_t)phase * 3 * SZ);
  }

  {
    GArgs ga{};
    for (int u = 0; u < 6; ++u)
      ga.g[u] = {CTX + (size_t)u * SZ, WB + WB_QKVD + 3 * 98304 + u * 16384,
                 bd + u * 128, DOUT + (size_t)u * SZ, 128, 128, 1, 1, 0, 0};
    gemm_b<<<dim3(256, 1, 6), dim3(256), 0, stream>>>(ga);
  }

  ln_pair<<<dim3(NROW, 3), dim3(64), 0, stream>>>(DOUT, lng, lnb, GRUIN);

  // gx = GRUIN[g] @ Wih[rec]^T + gbih[rec], stored permuted into GX2
  {
    GArgs ga{};
    for (int r6 = 0; r6 < 6; ++r6) {
      int g = r6 >> 1;
      ga.g[r6] = {GRUIN + (size_t)g * SZ, WB + WB_WIH + r6 * 49152,
                  gbih + r6 * 384, GX2 + (size_t)r6 * 12582912,
                  128, 128, 1, 1, 1, r6 & 1};
    }
    gemm_b<<<dim3(256, 3, 6), dim3(256), 0, stream>>>(ga);
  }

  gru3<<<dim3(4, 6), dim3(512), 0, stream>>>(GX2, WB, gbhh, HS);
  head_kernel<<<dim3(BB), dim3(256), 0, stream>>>(HS, fW1, fb1, bng, bnb, fW2, fb2, out);
}

// Round 6
// 1259.232 us; speedup vs baseline: 3.3797x; 1.0333x over previous
//
#include <hip/hip_runtime.h>
#include <hip/hip_bf16.h>

// Problem constants
#define BB 64
#define SS 512
#define DD 128
#define NROW (BB * SS)          // 32768
#define SZ ((size_t)NROW * DD)  // 4,194,304 elems per [B,S,128] slice

typedef __attribute__((ext_vector_type(8))) short short8;
typedef __attribute__((ext_vector_type(4))) float f32x4;

// WB (converted-weight buffer) element offsets, all bf16:
#define WB_P1 0          // fc1W^T [128][320] (K=300 pad 320)
#define WB_P2 40960      // fc2W^T [128][64]  (K=35 pad 64)
#define WB_P3 49152      // fc3W^T [128][96]  (K=74 pad 96)
#define WB_QKVD 61440    // [4 op][6 u][128 n][128 k]
#define WB_WIH 454656    // [6 rec][384 n][128 k]
#define WB_WHH 749568    // [6 rec][384 n][128 k]
#define WB_TOTAL 1044480

__device__ __forceinline__ float frcp_(float x) { return __builtin_amdgcn_rcpf(x); }
// sigmoid = rcp(1+exp(-x)); saturates correctly: exp->inf => rcp->0.
__device__ __forceinline__ float sigmoidf_(float x) {
  return frcp_(1.f + __expf(-x));
}
// tanh = 1 - 2*rcp(exp(2x)+1); exp->inf => 1, exp->0 => -1.  No clamps.
__device__ __forceinline__ float tanhf_(float x) {
  return 1.f - 2.f * frcp_(__expf(2.f * x) + 1.f);
}
__device__ __forceinline__ float b2f(unsigned short u) {
  union { unsigned int i; float f; } x; x.i = ((unsigned int)u) << 16; return x.f;
}
__device__ __forceinline__ float b2f_lo(unsigned int u) {
  union { unsigned int i; float f; } x; x.i = u << 16; return x.f;
}
__device__ __forceinline__ float b2f_hi(unsigned int u) {
  union { unsigned int i; float f; } x; x.i = u & 0xffff0000u; return x.f;
}
__device__ __forceinline__ unsigned short f2b(float f) {
  __hip_bfloat16 b = __float2bfloat16(f);
  return *reinterpret_cast<unsigned short*>(&b);
}

// ---------------------------------------------------------------------------
// Weight prep: transpose/convert all weights into WB (bf16, [N][Kpad]).
// ---------------------------------------------------------------------------
__global__ __launch_bounds__(256) void prep_kernel(
    const float* __restrict__ fc1W, const float* __restrict__ fc2W,
    const float* __restrict__ fc3W, const float* __restrict__ Wq,
    const float* __restrict__ Wk, const float* __restrict__ Wv,
    const float* __restrict__ Wd, const float* __restrict__ gWih,
    const float* __restrict__ gWhh, unsigned short* __restrict__ WB) {
  for (int idx = blockIdx.x * 256 + threadIdx.x; idx < WB_TOTAL;
       idx += gridDim.x * 256) {
    float v;
    if (idx < WB_P2) {
      int n = idx / 320, k = idx % 320;
      v = (k < 300) ? fc1W[k * 128 + n] : 0.f;
    } else if (idx < WB_P3) {
      int r = idx - WB_P2; int n = r >> 6, k = r & 63;
      v = (k < 35) ? fc2W[k * 128 + n] : 0.f;
    } else if (idx < WB_QKVD) {
      int r = idx - WB_P3; int n = r / 96, k = r % 96;
      v = (k < 74) ? fc3W[k * 128 + n] : 0.f;
    } else if (idx < WB_WIH) {
      int r = idx - WB_QKVD;
      int op = r / 98304; int r2 = r % 98304;
      int u = r2 >> 14; int r3 = r2 & 16383;
      int n = r3 >> 7, k = r3 & 127;
      const float* src = (op == 0) ? Wq : (op == 1) ? Wk : (op == 2) ? Wv : Wd;
      v = src[u * 16384 + k * 128 + n];
    } else if (idx < WB_WHH) {
      v = gWih[idx - WB_WIH];
    } else {
      v = gWhh[idx - WB_WHH];
    }
    WB[idx] = f2b(v);
  }
}

// ---------------------------------------------------------------------------
// Batched MFMA GEMM: C[32768, N] = A[32768,Ka] @ W^T + bias, per blockIdx.z.
// mode 0: row-major C.  mode 1: GX2 thread-major store for gru3:
//   [bg][s][tid][12], step pre-reversed by dirf; tid/idx derived from (b,unit).
// ---------------------------------------------------------------------------
struct GArg {
  const void* A; const unsigned short* W; const float* bias; void* C;
  int Ka, Kp, abf, cbf, mode, dirf;
};
struct GArgs { GArg g[18]; };

__global__ __launch_bounds__(256) void gemm_b(GArgs args) {
  const GArg ga = args.g[blockIdx.z];
  const int ny = blockIdx.y;
  __shared__ unsigned short As[128 * 40];
  __shared__ unsigned short Ws[128 * 40];
  const int t = threadIdx.x;
  const int w = t >> 6, lane = t & 63, q = lane >> 4, lm = lane & 15;
  const int wm = w >> 1, wn = w & 1;
  const int m0 = blockIdx.x * 128;
  const int row = t >> 1, cb = (t & 1) * 16;
  f32x4 acc[4][4];
#pragma unroll
  for (int i = 0; i < 4; ++i)
#pragma unroll
    for (int j = 0; j < 4; ++j) acc[i][j] = (f32x4){0.f, 0.f, 0.f, 0.f};

  for (int kt = 0; kt < ga.Kp; kt += 32) {
    if (ga.abf) {
      const unsigned short* Ag =
          (const unsigned short*)ga.A + (size_t)(m0 + row) * ga.Ka + kt + cb;
      short8 v0 = *reinterpret_cast<const short8*>(Ag);
      short8 v1 = *reinterpret_cast<const short8*>(Ag + 8);
      *reinterpret_cast<short8*>(&As[row * 40 + cb]) = v0;
      *reinterpret_cast<short8*>(&As[row * 40 + cb + 8]) = v1;
    } else {
      const float* Ag = (const float*)ga.A + (size_t)(m0 + row) * ga.Ka + kt + cb;
      unsigned short tmp[16];
#pragma unroll
      for (int j = 0; j < 16; ++j) {
        int k = kt + cb + j;
        tmp[j] = (k < ga.Ka) ? f2b(Ag[j]) : 0;
      }
      *reinterpret_cast<short8*>(&As[row * 40 + cb]) =
          *reinterpret_cast<short8*>(&tmp[0]);
      *reinterpret_cast<short8*>(&As[row * 40 + cb + 8]) =
          *reinterpret_cast<short8*>(&tmp[8]);
    }
    {
      const unsigned short* Wg =
          ga.W + (size_t)(ny * 128 + row) * ga.Kp + kt + cb;
      short8 v0 = *reinterpret_cast<const short8*>(Wg);
      short8 v1 = *reinterpret_cast<const short8*>(Wg + 8);
      *reinterpret_cast<short8*>(&Ws[row * 40 + cb]) = v0;
      *reinterpret_cast<short8*>(&Ws[row * 40 + cb + 8]) = v1;
    }
    __syncthreads();
    short8 af[4], bfv[4];
#pragma unroll
    for (int mi = 0; mi < 4; ++mi)
      af[mi] = *reinterpret_cast<const short8*>(
          &As[(wm * 64 + mi * 16 + lm) * 40 + q * 8]);
#pragma unroll
    for (int ni = 0; ni < 4; ++ni)
      bfv[ni] = *reinterpret_cast<const short8*>(
          &Ws[(wn * 64 + ni * 16 + lm) * 40 + q * 8]);
#pragma unroll
    for (int mi = 0; mi < 4; ++mi)
#pragma unroll
      for (int ni = 0; ni < 4; ++ni)
        acc[mi][ni] = __builtin_amdgcn_mfma_f32_16x16x32_bf16(
            af[mi], bfv[ni], acc[mi][ni], 0, 0, 0);
    __syncthreads();
  }
#pragma unroll
  for (int ni = 0; ni < 4; ++ni) {
    const int colg = ny * 128 + wn * 64 + ni * 16 + lm;
    const float bv = ga.bias[colg];
#pragma unroll
    for (int mi = 0; mi < 4; ++mi) {
      const int rg = m0 + wm * 64 + mi * 16 + q * 4;
#pragma unroll
      for (int r = 0; r < 4; ++r) {
        float v = acc[mi][ni][r] + bv;
        if (ga.mode == 1) {
          int m = rg + r, b = m >> 9, ss = m & 511;
          int s = ga.dirf ? (511 - ss) : ss;
          int unit = colg & 127, gate = colg >> 7;
          int b16 = b & 15;
          int tid = ((unit >> 4) << 6) + ((b16 >> 2) << 4) + (unit & 15);
          int idx = (b16 & 3) * 3 + gate;
          ((unsigned short*)ga.C)[((((size_t)(b >> 4)) * 512 + s) * 512 + tid) * 12 + idx] = f2b(v);
        } else if (ga.cbf) {
          ((unsigned short*)ga.C)[(size_t)(rg + r) * 128 + colg] = f2b(v);
        } else {
          ((float*)ga.C)[(size_t)(rg + r) * 128 + colg] = v;
        }
      }
    }
  }
}

// ---------------------------------------------------------------------------
// V column sums: VS[z][b][128] = sum_s V_z[b][s][:]   (V bf16)
// ---------------------------------------------------------------------------
__global__ __launch_bounds__(128) void vsum_kernel(
    const unsigned short* __restrict__ QKV, float* __restrict__ VS) {
  int b = blockIdx.x, z = blockIdx.y, d = threadIdx.x;
  const unsigned short* p = QKV + (size_t)(z * 3 + 2) * SZ + (size_t)b * SS * DD + d;
  float s = 0.f;
  for (int k = 0; k < SS; ++k) s += b2f(p[(size_t)k * DD]);
  VS[(z * BB + b) * DD + d] = s;
}

// ---------------------------------------------------------------------------
// MFMA attention (probs = 1 - softmax): ctx = Vsum - softmax(QK^T/8) @ V.
// ---------------------------------------------------------------------------
__global__ __launch_bounds__(256) void attn_mfma(
    const unsigned short* __restrict__ QKV, const float* __restrict__ VS,
    unsigned short* __restrict__ CTX) {
  __shared__ unsigned short Vt[64 * 72];       // [d][k ^ (d&56)]
  __shared__ unsigned short Pt[4][16 * 72];    // per-wave [q][k]
  const int t = threadIdx.x;
  const int w = t >> 6, lane = t & 63, quad = lane >> 4, lm = lane & 15;
  const int z = blockIdx.z;
  const int bh = blockIdx.y, b = bh >> 1, h = bh & 1;
  const int q0 = blockIdx.x * 64;

  const unsigned short* Qg = QKV + (size_t)(z * 3 + 0) * SZ;
  const unsigned short* Kg = QKV + (size_t)(z * 3 + 1) * SZ;
  const unsigned short* Vg = QKV + (size_t)(z * 3 + 2) * SZ;

  short8 aq[2];
#pragma unroll
  for (int c = 0; c < 2; ++c)
    aq[c] = *reinterpret_cast<const short8*>(
        Qg + ((size_t)(b * SS + q0 + w * 16 + lm)) * DD + h * 64 + c * 32 + quad * 8);

  f32x4 o[4];
#pragma unroll
  for (int i = 0; i < 4; ++i) o[i] = (f32x4){0.f, 0.f, 0.f, 0.f};
  float suml[4] = {0.f, 0.f, 0.f, 0.f};

  const int vk = t >> 3, vd0 = (t & 7) * 8;

  for (int kt = 0; kt < 8; ++kt) {
    const int k0 = kt * 64;
    __syncthreads();
#pragma unroll
    for (int i = 0; i < 2; ++i) {
      const int k = vk + i * 32;
      short8 vv = *reinterpret_cast<const short8*>(
          Vg + ((size_t)(b * SS + k0 + k)) * DD + h * 64 + vd0);
#pragma unroll
      for (int j = 0; j < 8; ++j) {
        const int d = vd0 + j;
        Vt[d * 72 + (k ^ (d & 56))] = (unsigned short)vv[j];
      }
    }
    __syncthreads();

    f32x4 sacc[4];
#pragma unroll
    for (int nt = 0; nt < 4; ++nt) sacc[nt] = (f32x4){0.f, 0.f, 0.f, 0.f};
#pragma unroll
    for (int c = 0; c < 2; ++c) {
#pragma unroll
      for (int nt = 0; nt < 4; ++nt) {
        short8 bk = *reinterpret_cast<const short8*>(
            Kg + ((size_t)(b * SS + k0 + nt * 16 + lm)) * DD + h * 64 + c * 32 + quad * 8);
        sacc[nt] = __builtin_amdgcn_mfma_f32_16x16x32_bf16(aq[c], bk, sacc[nt], 0, 0, 0);
      }
    }
#pragma unroll
    for (int nt = 0; nt < 4; ++nt) {
#pragma unroll
      for (int r = 0; r < 4; ++r) {
        float p = __expf(sacc[nt][r] * 0.125f);
        suml[r] += p;
        Pt[w][(quad * 4 + r) * 72 + nt * 16 + lm] = f2b(p);
      }
    }
#pragma unroll
    for (int c = 0; c < 2; ++c) {
      short8 ap = *reinterpret_cast<const short8*>(&Pt[w][lm * 72 + c * 32 + quad * 8]);
#pragma unroll
      for (int dt = 0; dt < 4; ++dt) {
        const int d = dt * 16 + lm;
        short8 bv = *reinterpret_cast<const short8*>(
            &Vt[d * 72 + ((c * 32 + quad * 8) ^ (d & 56))]);
        o[dt] = __builtin_amdgcn_mfma_f32_16x16x32_bf16(ap, bv, o[dt], 0, 0, 0);
      }
    }
  }
#pragma unroll
  for (int r = 0; r < 4; ++r) {
#pragma unroll
    for (int m = 1; m < 16; m <<= 1) suml[r] += __shfl_xor(suml[r], m);
  }
  const float* vsp = VS + (size_t)(z * BB + b) * DD + h * 64;
#pragma unroll
  for (int dt = 0; dt < 4; ++dt) {
    const int col = dt * 16 + lm;
    const float vs = vsp[col];
#pragma unroll
    for (int r = 0; r < 4; ++r) {
      const int row = q0 + w * 16 + quad * 4 + r;
      CTX[(size_t)z * SZ + ((size_t)(b * SS + row)) * DD + h * 64 + col] =
          f2b(vs - o[dt][r] * frcp_(suml[r]));
    }
  }
}

// ---------------------------------------------------------------------------
// Fused LN pair, 4 rows/block (1 wave per row).
// grid = (NROW/4, 3), block = 256.
// ---------------------------------------------------------------------------
__global__ __launch_bounds__(256) void ln_pair(
    const unsigned short* __restrict__ DOUT, const float* __restrict__ lng,
    const float* __restrict__ lnb, unsigned short* __restrict__ GRUIN) {
  const int g = blockIdx.y;
  const int row = blockIdx.x * 4 + (threadIdx.x >> 6);
  const int t = threadIdx.x & 63;
  const int u1t[3] = {1, 2, 0};
  const int u2t[3] = {3, 5, 4};
  float outA = 0.f, outB = 0.f;
#pragma unroll
  for (int half = 0; half < 2; ++half) {
    const int u = half == 0 ? u1t[g] : u2t[g];
    const unsigned short* x = DOUT + (size_t)u * SZ + (size_t)row * DD;
    float a = b2f(x[t]), c = b2f(x[t + 64]);
    float s = a + c, sq = a * a + c * c;
#pragma unroll
    for (int off = 32; off > 0; off >>= 1) {
      s += __shfl_down(s, off);
      sq += __shfl_down(sq, off);
    }
    s = __shfl(s, 0); sq = __shfl(sq, 0);
    float mean = s * (1.f / 128.f);
    float var = sq * (1.f / 128.f) - mean * mean;
    float rs = rsqrtf(var + 1e-5f);
    const float* gg = lng + u * 128;
    const float* bb = lnb + u * 128;
    outA += (a - mean) * rs * gg[t] + bb[t];
    outB += (c - mean) * rs * gg[t + 64] + bb[t + 64];
  }
  unsigned short* op = GRUIN + (size_t)g * SZ + (size_t)row * DD;
  op[t] = f2b(0.5f * outA);
  op[t + 64] = f2b(0.5f * outB);
}

// ---------------------------------------------------------------------------
// GRU v5: recurrence-only MFMA loop; gx thread-major (3 uint2 loads/step),
// fast-rcp gates.  grid = (4 bg, 6 rec), block = 512 (8 waves).
// ---------------------------------------------------------------------------
#define AST 136

__global__ __launch_bounds__(512, 1) void gru3(
    const unsigned short* __restrict__ GX2, const unsigned short* __restrict__ WB,
    const float* __restrict__ gbhh, float* __restrict__ HS) {
  __shared__ unsigned short Abuf[2][16 * AST];
  const int rec = blockIdx.y, bg = blockIdx.x;
  const int t = threadIdx.x;
  const int w = t >> 6, lane = t & 63, q = lane >> 4, lm = lane & 15;
  const int q4 = q * 4;
  const int o = w * 16 + lm;

  short8 Bh[3][4];
  const unsigned short* whh = WB + WB_WHH + (size_t)rec * 49152;
#pragma unroll
  for (int gate = 0; gate < 3; ++gate)
#pragma unroll
    for (int c = 0; c < 4; ++c)
      Bh[gate][c] = *reinterpret_cast<const short8*>(
          whh + (size_t)(gate * 128 + o) * 128 + c * 32 + q * 8);
  const float br = gbhh[rec * 384 + o];
  const float bz = gbhh[rec * 384 + 128 + o];
  const float bhn = gbhh[rec * 384 + 256 + o];

  float h[4] = {0.f, 0.f, 0.f, 0.f};
  float hsum[4] = {0.f, 0.f, 0.f, 0.f};
  for (int i = t; i < 16 * AST; i += 512) Abuf[0][i] = 0;

  // thread-major gx: base + s*1536 uint2, 3 uint2 per thread per step
  const uint2* gxp = reinterpret_cast<const uint2*>(
      GX2 + ((size_t)(rec * 4 + bg) * 512) * 6144 + (size_t)t * 12);

  uint2 ring[4][3];
#pragma unroll
  for (int pp = 0; pp < 4; ++pp) {
#pragma unroll
    for (int j = 0; j < 3; ++j) ring[pp][j] = gxp[(size_t)pp * 1536 + j];
  }
  __syncthreads();

#pragma unroll 4
  for (int s = 0; s < SS; ++s) {
    const int p = s & 1, slot = s & 3;
    float gx[12];
#pragma unroll
    for (int j = 0; j < 3; ++j) {
      gx[j * 4 + 0] = b2f_lo(ring[slot][j].x);
      gx[j * 4 + 1] = b2f_hi(ring[slot][j].x);
      gx[j * 4 + 2] = b2f_lo(ring[slot][j].y);
      gx[j * 4 + 3] = b2f_hi(ring[slot][j].y);
    }
    // prefetch step s+4 into the slot just consumed
    int sp = s + 4; if (sp > SS - 1) sp = SS - 1;
#pragma unroll
    for (int j = 0; j < 3; ++j) ring[slot][j] = gxp[(size_t)sp * 1536 + j];

    short8 ah[4];
#pragma unroll
    for (int c = 0; c < 4; ++c)
      ah[c] = *reinterpret_cast<const short8*>(&Abuf[p][lm * AST + c * 32 + q * 8]);
    f32x4 ar = {br, br, br, br};
    f32x4 az = {bz, bz, bz, bz};
    f32x4 ahn = {bhn, bhn, bhn, bhn};
#pragma unroll
    for (int c = 0; c < 4; ++c) {
      ar = __builtin_amdgcn_mfma_f32_16x16x32_bf16(ah[c], Bh[0][c], ar, 0, 0, 0);
      az = __builtin_amdgcn_mfma_f32_16x16x32_bf16(ah[c], Bh[1][c], az, 0, 0, 0);
      ahn = __builtin_amdgcn_mfma_f32_16x16x32_bf16(ah[c], Bh[2][c], ahn, 0, 0, 0);
    }
#pragma unroll
    for (int i = 0; i < 4; ++i) {
      float r = sigmoidf_(gx[i * 3 + 0] + ar[i]);
      float z = sigmoidf_(gx[i * 3 + 1] + az[i]);
      float nn = tanhf_(gx[i * 3 + 2] + r * ahn[i]);
      h[i] = (1.f - z) * nn + z * h[i];
      hsum[i] += h[i];
      Abuf[p ^ 1][(q4 + i) * AST + o] = f2b(h[i]);
    }
    __syncthreads();
  }
#pragma unroll
  for (int i = 0; i < 4; ++i)
    HS[((size_t)rec * BB + bg * 16 + q4 + i) * 128 + o] = hsum[i];
}

// ---------------------------------------------------------------------------
// Head: pooled -> Linear -> BN(eval) -> ReLU6 -> Linear.  grid=64, block=256.
// ---------------------------------------------------------------------------
__global__ __launch_bounds__(256) void head_kernel(
    const float* __restrict__ HS, const float* __restrict__ fW1,
    const float* __restrict__ fb1, const float* __restrict__ bng,
    const float* __restrict__ bnb, const float* __restrict__ fW2,
    const float* __restrict__ fb2, float* __restrict__ out) {
  __shared__ float pl[384];
  __shared__ float h1[256];
  int b = blockIdx.x, n = threadIdx.x;
  {
    int j = n;
    int seg = j >> 7, oo = j & 127;
    pl[j] = (HS[((size_t)seg * BB + b) * 128 + oo] +
             HS[((size_t)(seg + 3) * BB + b) * 128 + oo]) * (0.5f / 512.f);
  }
  if (n < 128) {
    int j = 256 + n;
    int seg = j >> 7, oo = j & 127;
    pl[j] = (HS[((size_t)seg * BB + b) * 128 + oo] +
             HS[((size_t)(seg + 3) * BB + b) * 128 + oo]) * (0.5f / 512.f);
  }
  __syncthreads();
  float acc = fb1[n];
  for (int k = 0; k < 384; ++k) acc += pl[k] * fW1[k * 256 + n];
  float hv = acc * rsqrtf(1.f + 1e-5f) * bng[n] + bnb[n];
  hv = fminf(fmaxf(hv, 0.f), 6.f);
  h1[n] = hv;
  __syncthreads();
  if (n < 8) {
    float a2 = fb2[n];
    for (int k = 0; k < 256; ++k) a2 += h1[k] * fW2[k * 8 + n];
    out[b * 8 + n] = a2;
  }
}

// ---------------------------------------------------------------------------
extern "C" void kernel_launch(void* const* d_in, const int* in_sizes, int n_in,
                              void* d_out, int out_size, void* d_ws,
                              size_t ws_size, hipStream_t stream) {
  (void)in_sizes; (void)n_in; (void)out_size; (void)ws_size;
  const float* text = (const float*)d_in[0];
  const float* vis  = (const float*)d_in[1];
  const float* aud  = (const float*)d_in[2];
  const float* fc1W = (const float*)d_in[3];
  const float* fc1b = (const float*)d_in[4];
  const float* fc2W = (const float*)d_in[5];
  const float* fc2b = (const float*)d_in[6];
  const float* fc3W = (const float*)d_in[7];
  const float* fc3b = (const float*)d_in[8];
  const float* Wq = (const float*)d_in[9];
  const float* bq = (const float*)d_in[10];
  const float* Wk = (const float*)d_in[11];
  const float* bk = (const float*)d_in[12];
  const float* Wv = (const float*)d_in[13];
  const float* bv = (const float*)d_in[14];
  const float* Wd = (const float*)d_in[15];
  const float* bd = (const float*)d_in[16];
  const float* lng = (const float*)d_in[17];
  const float* lnb = (const float*)d_in[18];
  const float* gWih = (const float*)d_in[19];
  const float* gWhh = (const float*)d_in[20];
  const float* gbih = (const float*)d_in[21];
  const float* gbhh = (const float*)d_in[22];
  const float* fW1 = (const float*)d_in[23];
  const float* fb1 = (const float*)d_in[24];
  const float* bng = (const float*)d_in[25];
  const float* bnb = (const float*)d_in[26];
  const float* fW2 = (const float*)d_in[27];
  const float* fb2 = (const float*)d_in[28];
  float* out = (float*)d_out;

  unsigned short* WSB = (unsigned short*)d_ws;
  unsigned short* T   = WSB;
  unsigned short* Vv  = WSB + SZ;
  unsigned short* Aa  = WSB + 2 * SZ;
  unsigned short* QKV = WSB + 3 * SZ;
  unsigned short* CTX = WSB + 12 * SZ;
  unsigned short* DOUT = WSB;
  unsigned short* GX2 = WSB;              // slices 0..17 (75.5M elems)
  unsigned short* GRUIN = WSB + 18 * SZ;  // slices 18..20
  unsigned short* WB  = WSB + 21 * SZ;
  float* VS = (float*)(WSB + 21 * SZ + 1048576);
  float* HS = VS + 6 * 64 * 128;

  prep_kernel<<<dim3(1024), dim3(256), 0, stream>>>(
      fc1W, fc2W, fc3W, Wq, Wk, Wv, Wd, gWih, gWhh, WB);

  {
    GArgs ga{};
    ga.g[0] = {text, WB + WB_P1, fc1b, T, 300, 320, 0, 1, 0, 0};
    ga.g[1] = {vis,  WB + WB_P2, fc2b, Vv, 35, 64, 0, 1, 0, 0};
    ga.g[2] = {aud,  WB + WB_P3, fc3b, Aa, 74, 96, 0, 1, 0, 0};
    gemm_b<<<dim3(256, 1, 3), dim3(256), 0, stream>>>(ga);
  }

  const int qsel[6] = {0, 2, 0, 1, 1, 2};
  const int ksel[6] = {2, 0, 1, 0, 2, 1};
  unsigned short* proj[3] = {T, Vv, Aa};
  const float* qkvbias[3] = {bq, bk, bv};

  for (int phase = 0; phase < 2; ++phase) {
    GArgs ga{};
    for (int ul = 0; ul < 3; ++ul) {
      int u = phase * 3 + ul;
      for (int op = 0; op < 3; ++op) {
        int z = ul * 3 + op;
        ga.g[z] = {proj[op == 0 ? qsel[u] : ksel[u]],
                   WB + WB_QKVD + op * 98304 + u * 16384,
                   qkvbias[op] + u * 128,
                   QKV + (size_t)z * SZ, 128, 128, 1, 1, 0, 0};
      }
    }
    gemm_b<<<dim3(256, 1, 9), dim3(256), 0, stream>>>(ga);
    vsum_kernel<<<dim3(BB, 3), dim3(128), 0, stream>>>(QKV, VS + phase * 3 * BB * DD);
    attn_mfma<<<dim3(8, 128, 3), dim3(256), 0, stream>>>(
        QKV, VS + phase * 3 * BB * DD, CTX + (size_t)phase * 3 * SZ);
  }

  {
    GArgs ga{};
    for (int u = 0; u < 6; ++u)
      ga.g[u] = {CTX + (size_t)u * SZ, WB + WB_QKVD + 3 * 98304 + u * 16384,
                 bd + u * 128, DOUT + (size_t)u * SZ, 128, 128, 1, 1, 0, 0};
    gemm_b<<<dim3(256, 1, 6), dim3(256), 0, stream>>>(ga);
  }

  ln_pair<<<dim3(NROW / 4, 3), dim3(256), 0, stream>>>(DOUT, lng, lnb, GRUIN);

  // gx = GRUIN[g] @ Wih[rec]^T + gbih[rec], stored thread-major into GX2
  {
    GArgs ga{};
    for (int r6 = 0; r6 < 6; ++r6) {
      int g = r6 >> 1;
      ga.g[r6] = {GRUIN + (size_t)g * SZ, WB + WB_WIH + r6 * 49152,
                  gbih + r6 * 384, GX2 + (size_t)r6 * 12582912,
                  128, 128, 1, 1, 1, r6 & 1};
    }
    gemm_b<<<dim3(256, 3, 6), dim3(256), 0, stream>>>(ga);
  }

  gru3<<<dim3(4, 6), dim3(512), 0, stream>>>(GX2, WB, gbhh, HS);
  head_kernel<<<dim3(BB), dim3(256), 0, stream>>>(HS, fW1, fb1, bng, bnb, fW2, fb2, out);
}

// Round 7
// 1042.041 us; speedup vs baseline: 4.0841x; 1.2084x over previous
//
#include <hip/hip_runtime.h>
#include <hip/hip_bf16.h>

// Problem constants
#define BB 64
#define SS 512
#define DD 128
#define NROW (BB * SS)          // 32768
#define SZ ((size_t)NROW * DD)  // 4,194,304 elems per [B,S,128] slice

#define LOG2E 1.4426950408889634f

typedef __attribute__((ext_vector_type(8))) short short8;
typedef __attribute__((ext_vector_type(4))) float f32x4;

// WB (converted-weight buffer) element offsets, all bf16:
#define WB_P1 0          // fc1W^T [128][320] (K=300 pad 320)
#define WB_P2 40960      // fc2W^T [128][64]  (K=35 pad 64)
#define WB_P3 49152      // fc3W^T [128][96]  (K=74 pad 96)
#define WB_QKVD 61440    // [4 op][6 u][128 n][128 k]
#define WB_WIH 454656    // [6 rec][384 n][128 k]  (prescaled by log2e/2log2e)
#define WB_WHH 749568    // [6 rec][384 n][128 k]  (prescaled by log2e/2log2e)
#define WB_TOTAL 1044480

__device__ __forceinline__ float frcp_(float x) { return __builtin_amdgcn_rcpf(x); }
__device__ __forceinline__ float fexp2_(float x) { return __builtin_amdgcn_exp2f(x); }
__device__ __forceinline__ float b2f(unsigned short u) {
  union { unsigned int i; float f; } x; x.i = ((unsigned int)u) << 16; return x.f;
}
__device__ __forceinline__ unsigned short f2b(float f) {
  __hip_bfloat16 b = __float2bfloat16(f);
  return *reinterpret_cast<unsigned short*>(&b);
}
__device__ __forceinline__ unsigned short f2b_trunc(float f) {
  union { float f; unsigned int i; } x; x.f = f; return (unsigned short)(x.i >> 16);
}

// ---------------------------------------------------------------------------
// Weight prep: transpose/convert all weights into WB (bf16, [N][Kpad]).
// GRU weights (WIH/WHH) are prescaled: gates r,z by log2e, gate n by 2*log2e,
// so the recurrence uses raw exp2.  Also writes a scaled gbih copy (fp32).
// ---------------------------------------------------------------------------
__global__ __launch_bounds__(256) void prep_kernel(
    const float* __restrict__ fc1W, const float* __restrict__ fc2W,
    const float* __restrict__ fc3W, const float* __restrict__ Wq,
    const float* __restrict__ Wk, const float* __restrict__ Wv,
    const float* __restrict__ Wd, const float* __restrict__ gWih,
    const float* __restrict__ gWhh, const float* __restrict__ gbih,
    unsigned short* __restrict__ WB, float* __restrict__ gbihs) {
  for (int idx = blockIdx.x * 256 + threadIdx.x; idx < WB_TOTAL;
       idx += gridDim.x * 256) {
    float v;
    if (idx < WB_P2) {
      int n = idx / 320, k = idx % 320;
      v = (k < 300) ? fc1W[k * 128 + n] : 0.f;
    } else if (idx < WB_P3) {
      int r = idx - WB_P2; int n = r >> 6, k = r & 63;
      v = (k < 35) ? fc2W[k * 128 + n] : 0.f;
    } else if (idx < WB_QKVD) {
      int r = idx - WB_P3; int n = r / 96, k = r % 96;
      v = (k < 74) ? fc3W[k * 128 + n] : 0.f;
    } else if (idx < WB_WIH) {
      int r = idx - WB_QKVD;
      int op = r / 98304; int r2 = r % 98304;
      int u = r2 >> 14; int r3 = r2 & 16383;
      int n = r3 >> 7, k = r3 & 127;
      const float* src = (op == 0) ? Wq : (op == 1) ? Wk : (op == 2) ? Wv : Wd;
      v = src[u * 16384 + k * 128 + n];
    } else if (idx < WB_WHH) {
      int r = idx - WB_WIH;
      int r3 = r % 49152;  // within rec: [384 n][128 k]
      int gate = (r3 >> 7) >> 7;
      v = gWih[r] * (gate < 2 ? LOG2E : 2.f * LOG2E);
    } else {
      int r = idx - WB_WHH;
      int r3 = r % 49152;
      int gate = (r3 >> 7) >> 7;
      v = gWhh[r] * (gate < 2 ? LOG2E : 2.f * LOG2E);
    }
    WB[idx] = f2b(v);
  }
  for (int idx = blockIdx.x * 256 + threadIdx.x; idx < 6 * 384;
       idx += gridDim.x * 256) {
    int gate = (idx % 384) >> 7;
    gbihs[idx] = gbih[idx] * (gate < 2 ? LOG2E : 2.f * LOG2E);
  }
}

// ---------------------------------------------------------------------------
// Batched MFMA GEMM: C[32768, N] = A[32768,Ka] @ W^T + bias, per blockIdx.z.
// mode 0: row-major C.  mode 1: GX2 store for gru4:
//   [bg16][s][tid512][3], step pre-reversed by dirf.
//   tid = (unit>>4)<<6 | (b&3)<<4 | (unit&15);  b = global batch, bg = b>>2.
// ---------------------------------------------------------------------------
struct GArg {
  const void* A; const unsigned short* W; const float* bias; void* C;
  int Ka, Kp, abf, cbf, mode, dirf;
};
struct GArgs { GArg g[18]; };

__global__ __launch_bounds__(256) void gemm_b(GArgs args) {
  const GArg ga = args.g[blockIdx.z];
  const int ny = blockIdx.y;
  __shared__ unsigned short As[128 * 40];
  __shared__ unsigned short Ws[128 * 40];
  const int t = threadIdx.x;
  const int w = t >> 6, lane = t & 63, q = lane >> 4, lm = lane & 15;
  const int wm = w >> 1, wn = w & 1;
  const int m0 = blockIdx.x * 128;
  const int row = t >> 1, cb = (t & 1) * 16;
  f32x4 acc[4][4];
#pragma unroll
  for (int i = 0; i < 4; ++i)
#pragma unroll
    for (int j = 0; j < 4; ++j) acc[i][j] = (f32x4){0.f, 0.f, 0.f, 0.f};

  for (int kt = 0; kt < ga.Kp; kt += 32) {
    if (ga.abf) {
      const unsigned short* Ag =
          (const unsigned short*)ga.A + (size_t)(m0 + row) * ga.Ka + kt + cb;
      short8 v0 = *reinterpret_cast<const short8*>(Ag);
      short8 v1 = *reinterpret_cast<const short8*>(Ag + 8);
      *reinterpret_cast<short8*>(&As[row * 40 + cb]) = v0;
      *reinterpret_cast<short8*>(&As[row * 40 + cb + 8]) = v1;
    } else {
      const float* Ag = (const float*)ga.A + (size_t)(m0 + row) * ga.Ka + kt + cb;
      unsigned short tmp[16];
#pragma unroll
      for (int j = 0; j < 16; ++j) {
        int k = kt + cb + j;
        tmp[j] = (k < ga.Ka) ? f2b(Ag[j]) : 0;
      }
      *reinterpret_cast<short8*>(&As[row * 40 + cb]) =
          *reinterpret_cast<short8*>(&tmp[0]);
      *reinterpret_cast<short8*>(&As[row * 40 + cb + 8]) =
          *reinterpret_cast<short8*>(&tmp[8]);
    }
    {
      const unsigned short* Wg =
          ga.W + (size_t)(ny * 128 + row) * ga.Kp + kt + cb;
      short8 v0 = *reinterpret_cast<const short8*>(Wg);
      short8 v1 = *reinterpret_cast<const short8*>(Wg + 8);
      *reinterpret_cast<short8*>(&Ws[row * 40 + cb]) = v0;
      *reinterpret_cast<short8*>(&Ws[row * 40 + cb + 8]) = v1;
    }
    __syncthreads();
    short8 af[4], bfv[4];
#pragma unroll
    for (int mi = 0; mi < 4; ++mi)
      af[mi] = *reinterpret_cast<const short8*>(
          &As[(wm * 64 + mi * 16 + lm) * 40 + q * 8]);
#pragma unroll
    for (int ni = 0; ni < 4; ++ni)
      bfv[ni] = *reinterpret_cast<const short8*>(
          &Ws[(wn * 64 + ni * 16 + lm) * 40 + q * 8]);
#pragma unroll
    for (int mi = 0; mi < 4; ++mi)
#pragma unroll
      for (int ni = 0; ni < 4; ++ni)
        acc[mi][ni] = __builtin_amdgcn_mfma_f32_16x16x32_bf16(
            af[mi], bfv[ni], acc[mi][ni], 0, 0, 0);
    __syncthreads();
  }
#pragma unroll
  for (int ni = 0; ni < 4; ++ni) {
    const int colg = ny * 128 + wn * 64 + ni * 16 + lm;
    const float bv = ga.bias[colg];
#pragma unroll
    for (int mi = 0; mi < 4; ++mi) {
      const int rg = m0 + wm * 64 + mi * 16 + q * 4;
#pragma unroll
      for (int r = 0; r < 4; ++r) {
        float v = acc[mi][ni][r] + bv;
        if (ga.mode == 1) {
          int m = rg + r, b = m >> 9, ss = m & 511;
          int s = ga.dirf ? (511 - ss) : ss;
          int unit = colg & 127, gate = colg >> 7;
          int tid = ((unit >> 4) << 6) | ((b & 3) << 4) | (unit & 15);
          ((unsigned short*)ga.C)[((((size_t)(b >> 2)) * 512 + s) * 512 + tid) * 3 + gate] = f2b(v);
        } else if (ga.cbf) {
          ((unsigned short*)ga.C)[(size_t)(rg + r) * 128 + colg] = f2b(v);
        } else {
          ((float*)ga.C)[(size_t)(rg + r) * 128 + colg] = v;
        }
      }
    }
  }
}

// ---------------------------------------------------------------------------
// V column sums: VS[z][b][128] = sum_s V_z[b][s][:]   (V bf16)
// ---------------------------------------------------------------------------
__global__ __launch_bounds__(128) void vsum_kernel(
    const unsigned short* __restrict__ QKV, float* __restrict__ VS) {
  int b = blockIdx.x, z = blockIdx.y, d = threadIdx.x;
  const unsigned short* p = QKV + (size_t)(z * 3 + 2) * SZ + (size_t)b * SS * DD + d;
  float s = 0.f;
  for (int k = 0; k < SS; ++k) s += b2f(p[(size_t)k * DD]);
  VS[(z * BB + b) * DD + d] = s;
}

// ---------------------------------------------------------------------------
// MFMA attention (probs = 1 - softmax): ctx = Vsum - softmax(QK^T/8) @ V.
// ---------------------------------------------------------------------------
__global__ __launch_bounds__(256) void attn_mfma(
    const unsigned short* __restrict__ QKV, const float* __restrict__ VS,
    unsigned short* __restrict__ CTX) {
  __shared__ unsigned short Vt[64 * 72];       // [d][k ^ (d&56)]
  __shared__ unsigned short Pt[4][16 * 72];    // per-wave [q][k]
  const int t = threadIdx.x;
  const int w = t >> 6, lane = t & 63, quad = lane >> 4, lm = lane & 15;
  const int z = blockIdx.z;
  const int bh = blockIdx.y, b = bh >> 1, h = bh & 1;
  const int q0 = blockIdx.x * 64;

  const unsigned short* Qg = QKV + (size_t)(z * 3 + 0) * SZ;
  const unsigned short* Kg = QKV + (size_t)(z * 3 + 1) * SZ;
  const unsigned short* Vg = QKV + (size_t)(z * 3 + 2) * SZ;

  short8 aq[2];
#pragma unroll
  for (int c = 0; c < 2; ++c)
    aq[c] = *reinterpret_cast<const short8*>(
        Qg + ((size_t)(b * SS + q0 + w * 16 + lm)) * DD + h * 64 + c * 32 + quad * 8);

  f32x4 o[4];
#pragma unroll
  for (int i = 0; i < 4; ++i) o[i] = (f32x4){0.f, 0.f, 0.f, 0.f};
  float suml[4] = {0.f, 0.f, 0.f, 0.f};

  const int vk = t >> 3, vd0 = (t & 7) * 8;

  for (int kt = 0; kt < 8; ++kt) {
    const int k0 = kt * 64;
    __syncthreads();
#pragma unroll
    for (int i = 0; i < 2; ++i) {
      const int k = vk + i * 32;
      short8 vv = *reinterpret_cast<const short8*>(
          Vg + ((size_t)(b * SS + k0 + k)) * DD + h * 64 + vd0);
#pragma unroll
      for (int j = 0; j < 8; ++j) {
        const int d = vd0 + j;
        Vt[d * 72 + (k ^ (d & 56))] = (unsigned short)vv[j];
      }
    }
    __syncthreads();

    f32x4 sacc[4];
#pragma unroll
    for (int nt = 0; nt < 4; ++nt) sacc[nt] = (f32x4){0.f, 0.f, 0.f, 0.f};
#pragma unroll
    for (int c = 0; c < 2; ++c) {
#pragma unroll
      for (int nt = 0; nt < 4; ++nt) {
        short8 bk = *reinterpret_cast<const short8*>(
            Kg + ((size_t)(b * SS + k0 + nt * 16 + lm)) * DD + h * 64 + c * 32 + quad * 8);
        sacc[nt] = __builtin_amdgcn_mfma_f32_16x16x32_bf16(aq[c], bk, sacc[nt], 0, 0, 0);
      }
    }
#pragma unroll
    for (int nt = 0; nt < 4; ++nt) {
#pragma unroll
      for (int r = 0; r < 4; ++r) {
        float p = __expf(sacc[nt][r] * 0.125f);
        suml[r] += p;
        Pt[w][(quad * 4 + r) * 72 + nt * 16 + lm] = f2b(p);
      }
    }
#pragma unroll
    for (int c = 0; c < 2; ++c) {
      short8 ap = *reinterpret_cast<const short8*>(&Pt[w][lm * 72 + c * 32 + quad * 8]);
#pragma unroll
      for (int dt = 0; dt < 4; ++dt) {
        const int d = dt * 16 + lm;
        short8 bv = *reinterpret_cast<const short8*>(
            &Vt[d * 72 + ((c * 32 + quad * 8) ^ (d & 56))]);
        o[dt] = __builtin_amdgcn_mfma_f32_16x16x32_bf16(ap, bv, o[dt], 0, 0, 0);
      }
    }
  }
#pragma unroll
  for (int r = 0; r < 4; ++r) {
#pragma unroll
    for (int m = 1; m < 16; m <<= 1) suml[r] += __shfl_xor(suml[r], m);
  }
  const float* vsp = VS + (size_t)(z * BB + b) * DD + h * 64;
#pragma unroll
  for (int dt = 0; dt < 4; ++dt) {
    const int col = dt * 16 + lm;
    const float vs = vsp[col];
#pragma unroll
    for (int r = 0; r < 4; ++r) {
      const int row = q0 + w * 16 + quad * 4 + r;
      CTX[(size_t)z * SZ + ((size_t)(b * SS + row)) * DD + h * 64 + col] =
          f2b(vs - o[dt][r] * frcp_(suml[r]));
    }
  }
}

// ---------------------------------------------------------------------------
// Fused LN pair, 4 rows/block (1 wave per row).
// ---------------------------------------------------------------------------
__global__ __launch_bounds__(256) void ln_pair(
    const unsigned short* __restrict__ DOUT, const float* __restrict__ lng,
    const float* __restrict__ lnb, unsigned short* __restrict__ GRUIN) {
  const int g = blockIdx.y;
  const int row = blockIdx.x * 4 + (threadIdx.x >> 6);
  const int t = threadIdx.x & 63;
  const int u1t[3] = {1, 2, 0};
  const int u2t[3] = {3, 5, 4};
  float outA = 0.f, outB = 0.f;
#pragma unroll
  for (int half = 0; half < 2; ++half) {
    const int u = half == 0 ? u1t[g] : u2t[g];
    const unsigned short* x = DOUT + (size_t)u * SZ + (size_t)row * DD;
    float a = b2f(x[t]), c = b2f(x[t + 64]);
    float s = a + c, sq = a * a + c * c;
#pragma unroll
    for (int off = 32; off > 0; off >>= 1) {
      s += __shfl_down(s, off);
      sq += __shfl_down(sq, off);
    }
    s = __shfl(s, 0); sq = __shfl(sq, 0);
    float mean = s * (1.f / 128.f);
    float var = sq * (1.f / 128.f) - mean * mean;
    float rs = rsqrtf(var + 1e-5f);
    const float* gg = lng + u * 128;
    const float* bb = lnb + u * 128;
    outA += (a - mean) * rs * gg[t] + bb[t];
    outB += (c - mean) * rs * gg[t + 64] + bb[t + 64];
  }
  unsigned short* op = GRUIN + (size_t)g * SZ + (size_t)row * DD;
  op[t] = f2b(0.5f * outA);
  op[t + 64] = f2b(0.5f * outB);
}

// ---------------------------------------------------------------------------
// GRU v6: 4 batches per block (batch <-> quad; A-row 4q; rows r!=0 stay 0).
// grid = (16 bg, 6 rec), block = 512 (8 waves).  Each lane: 3 gate activations
// from acc[0] only (uniform).  Weights prescaled by log2e (r,z) / 2log2e (n)
// so gates use raw exp2.  gx: 3 ushort loads/step from GX2[bg][s][tid][3],
// ring-prefetched 4 steps ahead.  1 barrier/step.
// HS[rec][64][128] = sum_t h.
// ---------------------------------------------------------------------------
#define AST 136

__global__ __launch_bounds__(512, 1) void gru4(
    const unsigned short* __restrict__ GX2, const unsigned short* __restrict__ WB,
    const float* __restrict__ gbhh, float* __restrict__ HS) {
  __shared__ unsigned short Abuf[2][16 * AST];
  const int rec = blockIdx.y, bg = blockIdx.x;
  const int t = threadIdx.x;
  const int w = t >> 6, lane = t & 63, q = lane >> 4, lm = lane & 15;
  const int o = w * 16 + lm;

  short8 Bh[3][4];
  const unsigned short* whh = WB + WB_WHH + (size_t)rec * 49152;
#pragma unroll
  for (int gate = 0; gate < 3; ++gate)
#pragma unroll
    for (int c = 0; c < 4; ++c)
      Bh[gate][c] = *reinterpret_cast<const short8*>(
          whh + (size_t)(gate * 128 + o) * 128 + c * 32 + q * 8);
  const float br = gbhh[rec * 384 + o] * LOG2E;
  const float bz = gbhh[rec * 384 + 128 + o] * LOG2E;
  const float bhn = gbhh[rec * 384 + 256 + o] * (2.f * LOG2E);

  float h = 0.f, hsum = 0.f;
  for (int i = t; i < 2 * 16 * AST; i += 512)
    (&Abuf[0][0])[i] = 0;

  // gx: 3 ushorts per thread per step, tid == threadIdx
  const unsigned short* gxt =
      GX2 + ((size_t)(rec * 16 + bg) * 512) * 1536 + (size_t)t * 3;

  unsigned short ring[4][3];
#pragma unroll
  for (int pp = 0; pp < 4; ++pp)
#pragma unroll
    for (int j = 0; j < 3; ++j) ring[pp][j] = gxt[(size_t)pp * 1536 + j];
  __syncthreads();

#pragma unroll 4
  for (int s = 0; s < SS; ++s) {
    const int p = s & 1, slot = s & 3;
    const float gxr = b2f(ring[slot][0]);
    const float gxz = b2f(ring[slot][1]);
    const float gxn = b2f(ring[slot][2]);
    // prefetch step s+4
    int sp = s + 4; if (sp > SS - 1) sp = SS - 1;
    const unsigned short* gp = gxt + (size_t)sp * 1536;
#pragma unroll
    for (int j = 0; j < 3; ++j) ring[slot][j] = gp[j];

    short8 ah[4];
#pragma unroll
    for (int c = 0; c < 4; ++c)
      ah[c] = *reinterpret_cast<const short8*>(&Abuf[p][lm * AST + c * 32 + q * 8]);
    f32x4 ar = {br, br, br, br};
    f32x4 az = {bz, bz, bz, bz};
    f32x4 ahn = {bhn, bhn, bhn, bhn};
#pragma unroll
    for (int c = 0; c < 4; ++c) {
      ar = __builtin_amdgcn_mfma_f32_16x16x32_bf16(ah[c], Bh[0][c], ar, 0, 0, 0);
      az = __builtin_amdgcn_mfma_f32_16x16x32_bf16(ah[c], Bh[1][c], az, 0, 0, 0);
      ahn = __builtin_amdgcn_mfma_f32_16x16x32_bf16(ah[c], Bh[2][c], ahn, 0, 0, 0);
    }
    // gates (all quantities prescaled by log2e / 2log2e)
    {
      float r = frcp_(1.f + fexp2_(-(gxr + ar[0])));
      float z = frcp_(1.f + fexp2_(-(gxz + az[0])));
      float nn = 1.f - 2.f * frcp_(fexp2_(gxn + r * ahn[0]) + 1.f);
      h = nn + z * (h - nn);
      hsum += h;
      Abuf[p ^ 1][(q * 4) * AST + o] = f2b_trunc(h);
    }
    __syncthreads();
  }
  HS[((size_t)rec * BB + bg * 4 + q) * 128 + o] = hsum;
}

// ---------------------------------------------------------------------------
// Head: pooled -> Linear -> BN(eval) -> ReLU6 -> Linear.  grid=64, block=256.
// ---------------------------------------------------------------------------
__global__ __launch_bounds__(256) void head_kernel(
    const float* __restrict__ HS, const float* __restrict__ fW1,
    const float* __restrict__ fb1, const float* __restrict__ bng,
    const float* __restrict__ bnb, const float* __restrict__ fW2,
    const float* __restrict__ fb2, float* __restrict__ out) {
  __shared__ float pl[384];
  __shared__ float h1[256];
  int b = blockIdx.x, n = threadIdx.x;
  {
    int j = n;
    int seg = j >> 7, oo = j & 127;
    pl[j] = (HS[((size_t)seg * BB + b) * 128 + oo] +
             HS[((size_t)(seg + 3) * BB + b) * 128 + oo]) * (0.5f / 512.f);
  }
  if (n < 128) {
    int j = 256 + n;
    int seg = j >> 7, oo = j & 127;
    pl[j] = (HS[((size_t)seg * BB + b) * 128 + oo] +
             HS[((size_t)(seg + 3) * BB + b) * 128 + oo]) * (0.5f / 512.f);
  }
  __syncthreads();
  float acc = fb1[n];
  for (int k = 0; k < 384; ++k) acc += pl[k] * fW1[k * 256 + n];
  float hv = acc * rsqrtf(1.f + 1e-5f) * bng[n] + bnb[n];
  hv = fminf(fmaxf(hv, 0.f), 6.f);
  h1[n] = hv;
  __syncthreads();
  if (n < 8) {
    float a2 = fb2[n];
    for (int k = 0; k < 256; ++k) a2 += h1[k] * fW2[k * 8 + n];
    out[b * 8 + n] = a2;
  }
}

// ---------------------------------------------------------------------------
extern "C" void kernel_launch(void* const* d_in, const int* in_sizes, int n_in,
                              void* d_out, int out_size, void* d_ws,
                              size_t ws_size, hipStream_t stream) {
  (void)in_sizes; (void)n_in; (void)out_size; (void)ws_size;
  const float* text = (const float*)d_in[0];
  const float* vis  = (const float*)d_in[1];
  const float* aud  = (const float*)d_in[2];
  const float* fc1W = (const float*)d_in[3];
  const float* fc1b = (const float*)d_in[4];
  const float* fc2W = (const float*)d_in[5];
  const float* fc2b = (const float*)d_in[6];
  const float* fc3W = (const float*)d_in[7];
  const float* fc3b = (const float*)d_in[8];
  const float* Wq = (const float*)d_in[9];
  const float* bq = (const float*)d_in[10];
  const float* Wk = (const float*)d_in[11];
  const float* bk = (const float*)d_in[12];
  const float* Wv = (const float*)d_in[13];
  const float* bv = (const float*)d_in[14];
  const float* Wd = (const float*)d_in[15];
  const float* bd = (const float*)d_in[16];
  const float* lng = (const float*)d_in[17];
  const float* lnb = (const float*)d_in[18];
  const float* gWih = (const float*)d_in[19];
  const float* gWhh = (const float*)d_in[20];
  const float* gbih = (const float*)d_in[21];
  const float* gbhh = (const float*)d_in[22];
  const float* fW1 = (const float*)d_in[23];
  const float* fb1 = (const float*)d_in[24];
  const float* bng = (const float*)d_in[25];
  const float* bnb = (const float*)d_in[26];
  const float* fW2 = (const float*)d_in[27];
  const float* fb2 = (const float*)d_in[28];
  float* out = (float*)d_out;

  unsigned short* WSB = (unsigned short*)d_ws;
  unsigned short* T   = WSB;
  unsigned short* Vv  = WSB + SZ;
  unsigned short* Aa  = WSB + 2 * SZ;
  unsigned short* QKV = WSB + 3 * SZ;
  unsigned short* CTX = WSB + 12 * SZ;
  unsigned short* DOUT = WSB;
  unsigned short* GX2 = WSB;              // slices 0..17 (75.5M elems)
  unsigned short* GRUIN = WSB + 18 * SZ;  // slices 18..20
  unsigned short* WB  = WSB + 21 * SZ;
  float* VS = (float*)(WSB + 21 * SZ + 1048576);
  float* HS = VS + 6 * 64 * 128;
  float* gbihs = HS + 6 * 64 * 128;       // 2304 floats

  prep_kernel<<<dim3(1024), dim3(256), 0, stream>>>(
      fc1W, fc2W, fc3W, Wq, Wk, Wv, Wd, gWih, gWhh, gbih, WB, gbihs);

  {
    GArgs ga{};
    ga.g[0] = {text, WB + WB_P1, fc1b, T, 300, 320, 0, 1, 0, 0};
    ga.g[1] = {vis,  WB + WB_P2, fc2b, Vv, 35, 64, 0, 1, 0, 0};
    ga.g[2] = {aud,  WB + WB_P3, fc3b, Aa, 74, 96, 0, 1, 0, 0};
    gemm_b<<<dim3(256, 1, 3), dim3(256), 0, stream>>>(ga);
  }

  const int qsel[6] = {0, 2, 0, 1, 1, 2};
  const int ksel[6] = {2, 0, 1, 0, 2, 1};
  unsigned short* proj[3] = {T, Vv, Aa};
  const float* qkvbias[3] = {bq, bk, bv};

  for (int phase = 0; phase < 2; ++phase) {
    GArgs ga{};
    for (int ul = 0; ul < 3; ++ul) {
      int u = phase * 3 + ul;
      for (int op = 0; op < 3; ++op) {
        int z = ul * 3 + op;
        ga.g[z] = {proj[op == 0 ? qsel[u] : ksel[u]],
                   WB + WB_QKVD + op * 98304 + u * 16384,
                   qkvbias[op] + u * 128,
                   QKV + (size_t)z * SZ, 128, 128, 1, 1, 0, 0};
      }
    }
    gemm_b<<<dim3(256, 1, 9), dim3(256), 0, stream>>>(ga);
    vsum_kernel<<<dim3(BB, 3), dim3(128), 0, stream>>>(QKV, VS + phase * 3 * BB * DD);
    attn_mfma<<<dim3(8, 128, 3), dim3(256), 0, stream>>>(
        QKV, VS + phase * 3 * BB * DD, CTX + (size_t)phase * 3 * SZ);
  }

  {
    GArgs ga{};
    for (int u = 0; u < 6; ++u)
      ga.g[u] = {CTX + (size_t)u * SZ, WB + WB_QKVD + 3 * 98304 + u * 16384,
                 bd + u * 128, DOUT + (size_t)u * SZ, 128, 128, 1, 1, 0, 0};
    gemm_b<<<dim3(256, 1, 6), dim3(256), 0, stream>>>(ga);
  }

  ln_pair<<<dim3(NROW / 4, 3), dim3(256), 0, stream>>>(DOUT, lng, lnb, GRUIN);

  // gx = GRUIN[g] @ Wih[rec]^T + gbih_scaled[rec], stored gru4-layout into GX2
  {
    GArgs ga{};
    for (int r6 = 0; r6 < 6; ++r6) {
      int g = r6 >> 1;
      ga.g[r6] = {GRUIN + (size_t)g * SZ, WB + WB_WIH + r6 * 49152,
                  gbihs + r6 * 384, GX2 + (size_t)r6 * 12582912,
                  128, 128, 1, 1, 1, r6 & 1};
    }
    gemm_b<<<dim3(256, 3, 6), dim3(256), 0, stream>>>(ga);
  }

  gru4<<<dim3(16, 6), dim3(512), 0, stream>>>(GX2, WB, gbhh, HS);
  head_kernel<<<dim3(BB), dim3(256), 0, stream>>>(HS, fW1, fb1, bng, bnb, fW2, fb2, out);
}

// Round 8
// 967.507 us; speedup vs baseline: 4.3988x; 1.0770x over previous
//
#include <hip/hip_runtime.h>
#include <hip/hip_bf16.h>

// Problem constants
#define BB 64
#define SS 512
#define DD 128
#define NROW (BB * SS)          // 32768
#define SZ ((size_t)NROW * DD)  // 4,194,304 elems per [B,S,128] slice

#define LOG2E 1.4426950408889634f
#define QSCALE (0.125f * LOG2E)

typedef __attribute__((ext_vector_type(8))) short short8;
typedef __attribute__((ext_vector_type(4))) float f32x4;
typedef __attribute__((ext_vector_type(4))) unsigned int u32x4;

// WB (converted-weight buffer) element offsets, all bf16:
#define WB_P1 0          // fc1W^T [128][320] (K=300 pad 320)
#define WB_P2 40960      // fc2W^T [128][64]  (K=35 pad 64)
#define WB_P3 49152      // fc3W^T [128][96]  (K=74 pad 96)
#define WB_QKVD 61440    // [4 op][6 u][128 n][128 k]  (op0=Wq prescaled by QSCALE)
#define WB_WIH 454656    // [6 rec][384 n][128 k]  (prescaled by log2e/2log2e)
#define WB_WHH 749568    // [6 rec][384 n][128 k]  (prescaled by log2e/2log2e)
#define WB_TOTAL 1044480

__device__ __forceinline__ float frcp_(float x) { return __builtin_amdgcn_rcpf(x); }
__device__ __forceinline__ float fexp2_(float x) { return __builtin_amdgcn_exp2f(x); }
__device__ __forceinline__ float b2f(unsigned short u) {
  union { unsigned int i; float f; } x; x.i = ((unsigned int)u) << 16; return x.f;
}
__device__ __forceinline__ float b2f_lo(unsigned int u) {
  union { unsigned int i; float f; } x; x.i = u << 16; return x.f;
}
__device__ __forceinline__ float b2f_hi(unsigned int u) {
  union { unsigned int i; float f; } x; x.i = u & 0xffff0000u; return x.f;
}
__device__ __forceinline__ unsigned short f2b(float f) {
  __hip_bfloat16 b = __float2bfloat16(f);
  return *reinterpret_cast<unsigned short*>(&b);
}
__device__ __forceinline__ unsigned short f2b_trunc(float f) {
  union { float f; unsigned int i; } x; x.f = f; return (unsigned short)(x.i >> 16);
}

// ---------------------------------------------------------------------------
// Weight prep: transpose/convert all weights into WB (bf16, [N][Kpad]).
// Wq prescaled by QSCALE (attention exp2 path).  GRU weights prescaled by
// log2e (r,z) / 2log2e (n).  Scaled fp32 copies of gbih and bq also emitted.
// ---------------------------------------------------------------------------
__global__ __launch_bounds__(256) void prep_kernel(
    const float* __restrict__ fc1W, const float* __restrict__ fc2W,
    const float* __restrict__ fc3W, const float* __restrict__ Wq,
    const float* __restrict__ Wk, const float* __restrict__ Wv,
    const float* __restrict__ Wd, const float* __restrict__ gWih,
    const float* __restrict__ gWhh, const float* __restrict__ gbih,
    const float* __restrict__ bq, unsigned short* __restrict__ WB,
    float* __restrict__ gbihs, float* __restrict__ bqs) {
  for (int idx = blockIdx.x * 256 + threadIdx.x; idx < WB_TOTAL;
       idx += gridDim.x * 256) {
    float v;
    if (idx < WB_P2) {
      int n = idx / 320, k = idx % 320;
      v = (k < 300) ? fc1W[k * 128 + n] : 0.f;
    } else if (idx < WB_P3) {
      int r = idx - WB_P2; int n = r >> 6, k = r & 63;
      v = (k < 35) ? fc2W[k * 128 + n] : 0.f;
    } else if (idx < WB_QKVD) {
      int r = idx - WB_P3; int n = r / 96, k = r % 96;
      v = (k < 74) ? fc3W[k * 128 + n] : 0.f;
    } else if (idx < WB_WIH) {
      int r = idx - WB_QKVD;
      int op = r / 98304; int r2 = r % 98304;
      int u = r2 >> 14; int r3 = r2 & 16383;
      int n = r3 >> 7, k = r3 & 127;
      const float* src = (op == 0) ? Wq : (op == 1) ? Wk : (op == 2) ? Wv : Wd;
      v = src[u * 16384 + k * 128 + n];
      if (op == 0) v *= QSCALE;
    } else if (idx < WB_WHH) {
      int r = idx - WB_WIH;
      int r3 = r % 49152;  // within rec: [384 n][128 k]
      int gate = (r3 >> 7) >> 7;
      v = gWih[r] * (gate < 2 ? LOG2E : 2.f * LOG2E);
    } else {
      int r = idx - WB_WHH;
      int r3 = r % 49152;
      int gate = (r3 >> 7) >> 7;
      v = gWhh[r] * (gate < 2 ? LOG2E : 2.f * LOG2E);
    }
    WB[idx] = f2b(v);
  }
  for (int idx = blockIdx.x * 256 + threadIdx.x; idx < 6 * 384;
       idx += gridDim.x * 256) {
    int gate = (idx % 384) >> 7;
    gbihs[idx] = gbih[idx] * (gate < 2 ? LOG2E : 2.f * LOG2E);
  }
  for (int idx = blockIdx.x * 256 + threadIdx.x; idx < 6 * 128;
       idx += gridDim.x * 256) {
    bqs[idx] = bq[idx] * QSCALE;
  }
}

// ---------------------------------------------------------------------------
// Batched MFMA GEMM: C[32768, N] = A[32768,Ka] @ W^T + bias, per blockIdx.z.
// mode 0: row-major C.  mode 1: GX2 chunked store for gru5:
//   [bg16][sc=s>>3][tid512][24], step pre-reversed by dirf.
//   tid = (unit>>4)<<6 | (b&3)<<4 | (unit&15);  idx = (s&7)*3 + gate.
// ---------------------------------------------------------------------------
struct GArg {
  const void* A; const unsigned short* W; const float* bias; void* C;
  int Ka, Kp, abf, cbf, mode, dirf;
};
struct GArgs { GArg g[18]; };

__global__ __launch_bounds__(256) void gemm_b(GArgs args) {
  const GArg ga = args.g[blockIdx.z];
  const int ny = blockIdx.y;
  __shared__ unsigned short As[128 * 40];
  __shared__ unsigned short Ws[128 * 40];
  const int t = threadIdx.x;
  const int w = t >> 6, lane = t & 63, q = lane >> 4, lm = lane & 15;
  const int wm = w >> 1, wn = w & 1;
  const int m0 = blockIdx.x * 128;
  const int row = t >> 1, cb = (t & 1) * 16;
  f32x4 acc[4][4];
#pragma unroll
  for (int i = 0; i < 4; ++i)
#pragma unroll
    for (int j = 0; j < 4; ++j) acc[i][j] = (f32x4){0.f, 0.f, 0.f, 0.f};

  for (int kt = 0; kt < ga.Kp; kt += 32) {
    if (ga.abf) {
      const unsigned short* Ag =
          (const unsigned short*)ga.A + (size_t)(m0 + row) * ga.Ka + kt + cb;
      short8 v0 = *reinterpret_cast<const short8*>(Ag);
      short8 v1 = *reinterpret_cast<const short8*>(Ag + 8);
      *reinterpret_cast<short8*>(&As[row * 40 + cb]) = v0;
      *reinterpret_cast<short8*>(&As[row * 40 + cb + 8]) = v1;
    } else {
      const float* Ag = (const float*)ga.A + (size_t)(m0 + row) * ga.Ka + kt + cb;
      unsigned short tmp[16];
#pragma unroll
      for (int j = 0; j < 16; ++j) {
        int k = kt + cb + j;
        tmp[j] = (k < ga.Ka) ? f2b(Ag[j]) : 0;
      }
      *reinterpret_cast<short8*>(&As[row * 40 + cb]) =
          *reinterpret_cast<short8*>(&tmp[0]);
      *reinterpret_cast<short8*>(&As[row * 40 + cb + 8]) =
          *reinterpret_cast<short8*>(&tmp[8]);
    }
    {
      const unsigned short* Wg =
          ga.W + (size_t)(ny * 128 + row) * ga.Kp + kt + cb;
      short8 v0 = *reinterpret_cast<const short8*>(Wg);
      short8 v1 = *reinterpret_cast<const short8*>(Wg + 8);
      *reinterpret_cast<short8*>(&Ws[row * 40 + cb]) = v0;
      *reinterpret_cast<short8*>(&Ws[row * 40 + cb + 8]) = v1;
    }
    __syncthreads();
    short8 af[4], bfv[4];
#pragma unroll
    for (int mi = 0; mi < 4; ++mi)
      af[mi] = *reinterpret_cast<const short8*>(
          &As[(wm * 64 + mi * 16 + lm) * 40 + q * 8]);
#pragma unroll
    for (int ni = 0; ni < 4; ++ni)
      bfv[ni] = *reinterpret_cast<const short8*>(
          &Ws[(wn * 64 + ni * 16 + lm) * 40 + q * 8]);
#pragma unroll
    for (int mi = 0; mi < 4; ++mi)
#pragma unroll
      for (int ni = 0; ni < 4; ++ni)
        acc[mi][ni] = __builtin_amdgcn_mfma_f32_16x16x32_bf16(
            af[mi], bfv[ni], acc[mi][ni], 0, 0, 0);
    __syncthreads();
  }
#pragma unroll
  for (int ni = 0; ni < 4; ++ni) {
    const int colg = ny * 128 + wn * 64 + ni * 16 + lm;
    const float bv = ga.bias[colg];
#pragma unroll
    for (int mi = 0; mi < 4; ++mi) {
      const int rg = m0 + wm * 64 + mi * 16 + q * 4;
#pragma unroll
      for (int r = 0; r < 4; ++r) {
        float v = acc[mi][ni][r] + bv;
        if (ga.mode == 1) {
          int m = rg + r, b = m >> 9, ss = m & 511;
          int s = ga.dirf ? (511 - ss) : ss;
          int unit = colg & 127, gate = colg >> 7;
          int tid = ((unit >> 4) << 6) | ((b & 3) << 4) | (unit & 15);
          ((unsigned short*)ga.C)[((((size_t)(b >> 2)) * 64 + (s >> 3)) * 512 + tid) * 24 +
                                  (s & 7) * 3 + gate] = f2b(v);
        } else if (ga.cbf) {
          ((unsigned short*)ga.C)[(size_t)(rg + r) * 128 + colg] = f2b(v);
        } else {
          ((float*)ga.C)[(size_t)(rg + r) * 128 + colg] = v;
        }
      }
    }
  }
}

// ---------------------------------------------------------------------------
// V column sums: VS[z][b][128] = sum_s V_z[b][s][:]   (V bf16)
// ---------------------------------------------------------------------------
__global__ __launch_bounds__(128) void vsum_kernel(
    const unsigned short* __restrict__ QKV, float* __restrict__ VS) {
  int b = blockIdx.x, z = blockIdx.y, d = threadIdx.x;
  const unsigned short* p = QKV + (size_t)(z * 3 + 2) * SZ + (size_t)b * SS * DD + d;
  float s = 0.f;
  for (int k = 0; k < SS; ++k) s += b2f(p[(size_t)k * DD]);
  VS[(z * BB + b) * DD + d] = s;
}

// ---------------------------------------------------------------------------
// MFMA attention (probs = 1 - softmax): ctx = Vsum - softmax(QK^T/8) @ V.
// Q/bq pre-scaled by 0.125*log2e -> scores are log2-domain -> raw exp2.
// ---------------------------------------------------------------------------
__global__ __launch_bounds__(256) void attn_mfma(
    const unsigned short* __restrict__ QKV, const float* __restrict__ VS,
    unsigned short* __restrict__ CTX) {
  __shared__ unsigned short Vt[64 * 72];       // [d][k ^ (d&56)]
  __shared__ unsigned short Pt[4][16 * 72];    // per-wave [q][k]
  const int t = threadIdx.x;
  const int w = t >> 6, lane = t & 63, quad = lane >> 4, lm = lane & 15;
  const int z = blockIdx.z;
  const int bh = blockIdx.y, b = bh >> 1, h = bh & 1;
  const int q0 = blockIdx.x * 64;

  const unsigned short* Qg = QKV + (size_t)(z * 3 + 0) * SZ;
  const unsigned short* Kg = QKV + (size_t)(z * 3 + 1) * SZ;
  const unsigned short* Vg = QKV + (size_t)(z * 3 + 2) * SZ;

  short8 aq[2];
#pragma unroll
  for (int c = 0; c < 2; ++c)
    aq[c] = *reinterpret_cast<const short8*>(
        Qg + ((size_t)(b * SS + q0 + w * 16 + lm)) * DD + h * 64 + c * 32 + quad * 8);

  f32x4 o[4];
#pragma unroll
  for (int i = 0; i < 4; ++i) o[i] = (f32x4){0.f, 0.f, 0.f, 0.f};
  float suml[4] = {0.f, 0.f, 0.f, 0.f};

  const int vk = t >> 3, vd0 = (t & 7) * 8;

  for (int kt = 0; kt < 8; ++kt) {
    const int k0 = kt * 64;
    __syncthreads();
#pragma unroll
    for (int i = 0; i < 2; ++i) {
      const int k = vk + i * 32;
      short8 vv = *reinterpret_cast<const short8*>(
          Vg + ((size_t)(b * SS + k0 + k)) * DD + h * 64 + vd0);
#pragma unroll
      for (int j = 0; j < 8; ++j) {
        const int d = vd0 + j;
        Vt[d * 72 + (k ^ (d & 56))] = (unsigned short)vv[j];
      }
    }
    __syncthreads();

    f32x4 sacc[4];
#pragma unroll
    for (int nt = 0; nt < 4; ++nt) sacc[nt] = (f32x4){0.f, 0.f, 0.f, 0.f};
#pragma unroll
    for (int c = 0; c < 2; ++c) {
#pragma unroll
      for (int nt = 0; nt < 4; ++nt) {
        short8 bk = *reinterpret_cast<const short8*>(
            Kg + ((size_t)(b * SS + k0 + nt * 16 + lm)) * DD + h * 64 + c * 32 + quad * 8);
        sacc[nt] = __builtin_amdgcn_mfma_f32_16x16x32_bf16(aq[c], bk, sacc[nt], 0, 0, 0);
      }
    }
#pragma unroll
    for (int nt = 0; nt < 4; ++nt) {
#pragma unroll
      for (int r = 0; r < 4; ++r) {
        float p = fexp2_(sacc[nt][r]);
        suml[r] += p;
        Pt[w][(quad * 4 + r) * 72 + nt * 16 + lm] = f2b_trunc(p);
      }
    }
#pragma unroll
    for (int c = 0; c < 2; ++c) {
      short8 ap = *reinterpret_cast<const short8*>(&Pt[w][lm * 72 + c * 32 + quad * 8]);
#pragma unroll
      for (int dt = 0; dt < 4; ++dt) {
        const int d = dt * 16 + lm;
        short8 bv = *reinterpret_cast<const short8*>(
            &Vt[d * 72 + ((c * 32 + quad * 8) ^ (d & 56))]);
        o[dt] = __builtin_amdgcn_mfma_f32_16x16x32_bf16(ap, bv, o[dt], 0, 0, 0);
      }
    }
  }
#pragma unroll
  for (int r = 0; r < 4; ++r) {
#pragma unroll
    for (int m = 1; m < 16; m <<= 1) suml[r] += __shfl_xor(suml[r], m);
  }
  const float* vsp = VS + (size_t)(z * BB + b) * DD + h * 64;
#pragma unroll
  for (int dt = 0; dt < 4; ++dt) {
    const int col = dt * 16 + lm;
    const float vs = vsp[col];
#pragma unroll
    for (int r = 0; r < 4; ++r) {
      const int row = q0 + w * 16 + quad * 4 + r;
      CTX[(size_t)z * SZ + ((size_t)(b * SS + row)) * DD + h * 64 + col] =
          f2b(vs - o[dt][r] * frcp_(suml[r]));
    }
  }
}

// ---------------------------------------------------------------------------
// Fused LN pair, 4 rows/block (1 wave per row).
// ---------------------------------------------------------------------------
__global__ __launch_bounds__(256) void ln_pair(
    const unsigned short* __restrict__ DOUT, const float* __restrict__ lng,
    const float* __restrict__ lnb, unsigned short* __restrict__ GRUIN) {
  const int g = blockIdx.y;
  const int row = blockIdx.x * 4 + (threadIdx.x >> 6);
  const int t = threadIdx.x & 63;
  const int u1t[3] = {1, 2, 0};
  const int u2t[3] = {3, 5, 4};
  float outA = 0.f, outB = 0.f;
#pragma unroll
  for (int half = 0; half < 2; ++half) {
    const int u = half == 0 ? u1t[g] : u2t[g];
    const unsigned short* x = DOUT + (size_t)u * SZ + (size_t)row * DD;
    float a = b2f(x[t]), c = b2f(x[t + 64]);
    float s = a + c, sq = a * a + c * c;
#pragma unroll
    for (int off = 32; off > 0; off >>= 1) {
      s += __shfl_down(s, off);
      sq += __shfl_down(sq, off);
    }
    s = __shfl(s, 0); sq = __shfl(sq, 0);
    float mean = s * (1.f / 128.f);
    float var = sq * (1.f / 128.f) - mean * mean;
    float rs = rsqrtf(var + 1e-5f);
    const float* gg = lng + u * 128;
    const float* bb = lnb + u * 128;
    outA += (a - mean) * rs * gg[t] + bb[t];
    outB += (c - mean) * rs * gg[t + 64] + bb[t + 64];
  }
  unsigned short* op = GRUIN + (size_t)g * SZ + (size_t)row * DD;
  op[t] = f2b(0.5f * outA);
  op[t + 64] = f2b(0.5f * outB);
}

// ---------------------------------------------------------------------------
// GRU v7: lgkm-only barrier (gx prefetch survives), gx in 8-step register
// chunks (3 dwordx4 per 8 steps, double buffered), MFMA chains split 2+2.
// grid = (16 bg, 6 rec), block = 512 (8 waves).  batch <-> quad, A-row 4q.
// ---------------------------------------------------------------------------
#define AST 136

#define DWX(I, A0, A1, A2) \
  ((I) < 4 ? (A0)[(I)] : (I) < 8 ? (A1)[(I) - 4] : (A2)[(I) - 8])
#define GXU(I, A0, A1, A2)                          \
  (((I) & 1) ? b2f_hi(DWX((I) >> 1, A0, A1, A2))    \
             : b2f_lo(DWX((I) >> 1, A0, A1, A2)))

#define GRU_STEP(J, A0, A1, A2) {                                              \
  const int p_ = (J) & 1;                                                      \
  short8 ah0 = *reinterpret_cast<const short8*>(&Abuf[p_][lm * AST + 0 + q * 8]);   \
  short8 ah1 = *reinterpret_cast<const short8*>(&Abuf[p_][lm * AST + 32 + q * 8]);  \
  short8 ah2 = *reinterpret_cast<const short8*>(&Abuf[p_][lm * AST + 64 + q * 8]);  \
  short8 ah3 = *reinterpret_cast<const short8*>(&Abuf[p_][lm * AST + 96 + q * 8]);  \
  f32x4 r0 = {br, 0.f, 0.f, 0.f}, r1 = {0.f, 0.f, 0.f, 0.f};                   \
  f32x4 z0 = {bz, 0.f, 0.f, 0.f}, z1 = {0.f, 0.f, 0.f, 0.f};                   \
  f32x4 n0 = {bhn, 0.f, 0.f, 0.f}, n1 = {0.f, 0.f, 0.f, 0.f};                  \
  r0 = __builtin_amdgcn_mfma_f32_16x16x32_bf16(ah0, Bh[0][0], r0, 0, 0, 0);    \
  r1 = __builtin_amdgcn_mfma_f32_16x16x32_bf16(ah2, Bh[0][2], r1, 0, 0, 0);    \
  z0 = __builtin_amdgcn_mfma_f32_16x16x32_bf16(ah0, Bh[1][0], z0, 0, 0, 0);    \
  z1 = __builtin_amdgcn_mfma_f32_16x16x32_bf16(ah2, Bh[1][2], z1, 0, 0, 0);    \
  n0 = __builtin_amdgcn_mfma_f32_16x16x32_bf16(ah0, Bh[2][0], n0, 0, 0, 0);    \
  n1 = __builtin_amdgcn_mfma_f32_16x16x32_bf16(ah2, Bh[2][2], n1, 0, 0, 0);    \
  r0 = __builtin_amdgcn_mfma_f32_16x16x32_bf16(ah1, Bh[0][1], r0, 0, 0, 0);    \
  r1 = __builtin_amdgcn_mfma_f32_16x16x32_bf16(ah3, Bh[0][3], r1, 0, 0, 0);    \
  z0 = __builtin_amdgcn_mfma_f32_16x16x32_bf16(ah1, Bh[1][1], z0, 0, 0, 0);    \
  z1 = __builtin_amdgcn_mfma_f32_16x16x32_bf16(ah3, Bh[1][3], z1, 0, 0, 0);    \
  n0 = __builtin_amdgcn_mfma_f32_16x16x32_bf16(ah1, Bh[2][1], n0, 0, 0, 0);    \
  n1 = __builtin_amdgcn_mfma_f32_16x16x32_bf16(ah3, Bh[2][3], n1, 0, 0, 0);    \
  const float gr_ = GXU(3 * (J) + 0, A0, A1, A2);                              \
  const float gz_ = GXU(3 * (J) + 1, A0, A1, A2);                              \
  const float gn_ = GXU(3 * (J) + 2, A0, A1, A2);                              \
  float rr_ = frcp_(1.f + fexp2_(-(gr_ + r0[0] + r1[0])));                     \
  float zz_ = frcp_(1.f + fexp2_(-(gz_ + z0[0] + z1[0])));                     \
  float nn_ = 1.f - 2.f * frcp_(fexp2_(gn_ + rr_ * (n0[0] + n1[0])) + 1.f);    \
  h = nn_ + zz_ * (h - nn_);                                                   \
  hsum += h;                                                                   \
  Abuf[p_ ^ 1][(q * 4) * AST + o] = f2b_trunc(h);                              \
  asm volatile("s_waitcnt lgkmcnt(0)\n\ts_barrier" ::: "memory");              \
}

#define GRU_CHUNK(A0, A1, A2, C0) {                                            \
  GRU_STEP(0, A0, A1, A2) GRU_STEP(1, A0, A1, A2)                              \
  GRU_STEP(2, A0, A1, A2) GRU_STEP(3, A0, A1, A2)                              \
  GRU_STEP(4, A0, A1, A2) GRU_STEP(5, A0, A1, A2)                              \
  GRU_STEP(6, A0, A1, A2) GRU_STEP(7, A0, A1, A2)                              \
  int cn_ = (C0) + 2; if (cn_ > 63) cn_ = 63;                                  \
  const u32x4* gp_ = reinterpret_cast<const u32x4*>(gxt + (size_t)cn_ * 12288);\
  A0 = gp_[0]; A1 = gp_[1]; A2 = gp_[2];                                       \
}

__global__ __launch_bounds__(512, 1) void gru5(
    const unsigned short* __restrict__ GX2, const unsigned short* __restrict__ WB,
    const float* __restrict__ gbhh, float* __restrict__ HS) {
  __shared__ unsigned short Abuf[2][16 * AST];
  const int rec = blockIdx.y, bg = blockIdx.x;
  const int t = threadIdx.x;
  const int w = t >> 6, lane = t & 63, q = lane >> 4, lm = lane & 15;
  const int o = w * 16 + lm;

  short8 Bh[3][4];
  const unsigned short* whh = WB + WB_WHH + (size_t)rec * 49152;
#pragma unroll
  for (int gate = 0; gate < 3; ++gate)
#pragma unroll
    for (int c = 0; c < 4; ++c)
      Bh[gate][c] = *reinterpret_cast<const short8*>(
          whh + (size_t)(gate * 128 + o) * 128 + c * 32 + q * 8);
  const float br = gbhh[rec * 384 + o] * LOG2E;
  const float bz = gbhh[rec * 384 + 128 + o] * LOG2E;
  const float bhn = gbhh[rec * 384 + 256 + o] * (2.f * LOG2E);

  float h = 0.f, hsum = 0.f;
  for (int i = t; i < 2 * 16 * AST; i += 512)
    (&Abuf[0][0])[i] = 0;

  // chunked gx: [64 chunks][512 tid][24 ushorts]; chunk stride 12288 ushorts
  const unsigned short* gxt =
      GX2 + (size_t)(rec * 16 + bg) * 786432 + (size_t)t * 24;

  u32x4 g0a, g0b, g0c, g1a, g1b, g1c;
  {
    const u32x4* gp = reinterpret_cast<const u32x4*>(gxt);
    g0a = gp[0]; g0b = gp[1]; g0c = gp[2];
    const u32x4* gp2 = reinterpret_cast<const u32x4*>(gxt + 12288);
    g1a = gp2[0]; g1b = gp2[1]; g1c = gp2[2];
  }
  __syncthreads();

  for (int scp = 0; scp < 32; ++scp) {
    GRU_CHUNK(g0a, g0b, g0c, scp * 2);
    GRU_CHUNK(g1a, g1b, g1c, scp * 2 + 1);
  }
  HS[((size_t)rec * BB + bg * 4 + q) * 128 + o] = hsum;
}

// ---------------------------------------------------------------------------
// Head: pooled -> Linear -> BN(eval) -> ReLU6 -> Linear.  grid=64, block=256.
// ---------------------------------------------------------------------------
__global__ __launch_bounds__(256) void head_kernel(
    const float* __restrict__ HS, const float* __restrict__ fW1,
    const float* __restrict__ fb1, const float* __restrict__ bng,
    const float* __restrict__ bnb, const float* __restrict__ fW2,
    const float* __restrict__ fb2, float* __restrict__ out) {
  __shared__ float pl[384];
  __shared__ float h1[256];
  int b = blockIdx.x, n = threadIdx.x;
  {
    int j = n;
    int seg = j >> 7, oo = j & 127;
    pl[j] = (HS[((size_t)seg * BB + b) * 128 + oo] +
             HS[((size_t)(seg + 3) * BB + b) * 128 + oo]) * (0.5f / 512.f);
  }
  if (n < 128) {
    int j = 256 + n;
    int seg = j >> 7, oo = j & 127;
    pl[j] = (HS[((size_t)seg * BB + b) * 128 + oo] +
             HS[((size_t)(seg + 3) * BB + b) * 128 + oo]) * (0.5f / 512.f);
  }
  __syncthreads();
  float acc = fb1[n];
  for (int k = 0; k < 384; ++k) acc += pl[k] * fW1[k * 256 + n];
  float hv = acc * rsqrtf(1.f + 1e-5f) * bng[n] + bnb[n];
  hv = fminf(fmaxf(hv, 0.f), 6.f);
  h1[n] = hv;
  __syncthreads();
  if (n < 8) {
    float a2 = fb2[n];
    for (int k = 0; k < 256; ++k) a2 += h1[k] * fW2[k * 8 + n];
    out[b * 8 + n] = a2;
  }
}

// ---------------------------------------------------------------------------
extern "C" void kernel_launch(void* const* d_in, const int* in_sizes, int n_in,
                              void* d_out, int out_size, void* d_ws,
                              size_t ws_size, hipStream_t stream) {
  (void)in_sizes; (void)n_in; (void)out_size; (void)ws_size;
  const float* text = (const float*)d_in[0];
  const float* vis  = (const float*)d_in[1];
  const float* aud  = (const float*)d_in[2];
  const float* fc1W = (const float*)d_in[3];
  const float* fc1b = (const float*)d_in[4];
  const float* fc2W = (const float*)d_in[5];
  const float* fc2b = (const float*)d_in[6];
  const float* fc3W = (const float*)d_in[7];
  const float* fc3b = (const float*)d_in[8];
  const float* Wq = (const float*)d_in[9];
  const float* bq = (const float*)d_in[10];
  const float* Wk = (const float*)d_in[11];
  const float* bk = (const float*)d_in[12];
  const float* Wv = (const float*)d_in[13];
  const float* bv = (const float*)d_in[14];
  const float* Wd = (const float*)d_in[15];
  const float* bd = (const float*)d_in[16];
  const float* lng = (const float*)d_in[17];
  const float* lnb = (const float*)d_in[18];
  const float* gWih = (const float*)d_in[19];
  const float* gWhh = (const float*)d_in[20];
  const float* gbih = (const float*)d_in[21];
  const float* gbhh = (const float*)d_in[22];
  const float* fW1 = (const float*)d_in[23];
  const float* fb1 = (const float*)d_in[24];
  const float* bng = (const float*)d_in[25];
  const float* bnb = (const float*)d_in[26];
  const float* fW2 = (const float*)d_in[27];
  const float* fb2 = (const float*)d_in[28];
  float* out = (float*)d_out;

  unsigned short* WSB = (unsigned short*)d_ws;
  unsigned short* T   = WSB;
  unsigned short* Vv  = WSB + SZ;
  unsigned short* Aa  = WSB + 2 * SZ;
  unsigned short* QKV = WSB + 3 * SZ;
  unsigned short* CTX = WSB + 12 * SZ;
  unsigned short* DOUT = WSB;
  unsigned short* GX2 = WSB;              // slices 0..17 (75.5M elems)
  unsigned short* GRUIN = WSB + 18 * SZ;  // slices 18..20
  unsigned short* WB  = WSB + 21 * SZ;
  float* VS = (float*)(WSB + 21 * SZ + 1048576);
  float* HS = VS + 6 * 64 * 128;
  float* gbihs = HS + 6 * 64 * 128;       // 2304 floats
  float* bqs = gbihs + 6 * 384;           // 768 floats

  prep_kernel<<<dim3(1024), dim3(256), 0, stream>>>(
      fc1W, fc2W, fc3W, Wq, Wk, Wv, Wd, gWih, gWhh, gbih, bq, WB, gbihs, bqs);

  {
    GArgs ga{};
    ga.g[0] = {text, WB + WB_P1, fc1b, T, 300, 320, 0, 1, 0, 0};
    ga.g[1] = {vis,  WB + WB_P2, fc2b, Vv, 35, 64, 0, 1, 0, 0};
    ga.g[2] = {aud,  WB + WB_P3, fc3b, Aa, 74, 96, 0, 1, 0, 0};
    gemm_b<<<dim3(256, 1, 3), dim3(256), 0, stream>>>(ga);
  }

  const int qsel[6] = {0, 2, 0, 1, 1, 2};
  const int ksel[6] = {2, 0, 1, 0, 2, 1};
  unsigned short* proj[3] = {T, Vv, Aa};

  for (int phase = 0; phase < 2; ++phase) {
    GArgs ga{};
    for (int ul = 0; ul < 3; ++ul) {
      int u = phase * 3 + ul;
      for (int op = 0; op < 3; ++op) {
        int z = ul * 3 + op;
        const float* bias = (op == 0) ? (bqs + u * 128)
                          : (op == 1) ? (bk + u * 128) : (bv + u * 128);
        ga.g[z] = {proj[op == 0 ? qsel[u] : ksel[u]],
                   WB + WB_QKVD + op * 98304 + u * 16384, bias,
                   QKV + (size_t)z * SZ, 128, 128, 1, 1, 0, 0};
      }
    }
    gemm_b<<<dim3(256, 1, 9), dim3(256), 0, stream>>>(ga);
    vsum_kernel<<<dim3(BB, 3), dim3(128), 0, stream>>>(QKV, VS + phase * 3 * BB * DD);
    attn_mfma<<<dim3(8, 128, 3), dim3(256), 0, stream>>>(
        QKV, VS + phase * 3 * BB * DD, CTX + (size_t)phase * 3 * SZ);
  }

  {
    GArgs ga{};
    for (int u = 0; u < 6; ++u)
      ga.g[u] = {CTX + (size_t)u * SZ, WB + WB_QKVD + 3 * 98304 + u * 16384,
                 bd + u * 128, DOUT + (size_t)u * SZ, 128, 128, 1, 1, 0, 0};
    gemm_b<<<dim3(256, 1, 6), dim3(256), 0, stream>>>(ga);
  }

  ln_pair<<<dim3(NROW / 4, 3), dim3(256), 0, stream>>>(DOUT, lng, lnb, GRUIN);

  // gx = GRUIN[g] @ Wih[rec]^T + gbih_scaled[rec], stored chunked into GX2
  {
    GArgs ga{};
    for (int r6 = 0; r6 < 6; ++r6) {
      int g = r6 >> 1;
      ga.g[r6] = {GRUIN + (size_t)g * SZ, WB + WB_WIH + r6 * 49152,
                  gbihs + r6 * 384, GX2 + (size_t)r6 * 12582912,
                  128, 128, 1, 1, 1, r6 & 1};
    }
    gemm_b<<<dim3(256, 3, 6), dim3(256), 0, stream>>>(ga);
  }

  gru5<<<dim3(16, 6), dim3(512), 0, stream>>>(GX2, WB, gbhh, HS);
  head_kernel<<<dim3(BB), dim3(256), 0, stream>>>(HS, fW1, fb1, bng, bnb, fW2, fb2, out);
}

// Round 9
// 781.503 us; speedup vs baseline: 5.4457x; 1.2380x over previous
//
#include <hip/hip_runtime.h>
#include <hip/hip_bf16.h>

// Problem constants
#define BB 64
#define SS 512
#define DD 128
#define NROW (BB * SS)          // 32768
#define SZ ((size_t)NROW * DD)  // 4,194,304 elems per [B,S,128] slice

#define LOG2E 1.4426950408889634f
#define QSCALE (0.125f * LOG2E)

typedef __attribute__((ext_vector_type(8))) short short8;
typedef __attribute__((ext_vector_type(4))) float f32x4;

// WB (converted-weight buffer) element offsets, all bf16:
#define WB_P1 0          // fc1W^T [128][320] (K=300 pad 320)
#define WB_P2 40960      // fc2W^T [128][64]  (K=35 pad 64)
#define WB_P3 49152      // fc3W^T [128][96]  (K=74 pad 96)
#define WB_QKVD 61440    // [4 op][6 u][128 n][128 k]  (op0=Wq prescaled by QSCALE)
#define WB_WIH 454656    // [6 rec][384 n][128 k]  (prescaled by log2e/2log2e)
#define WB_WHH 749568    // [6 rec][384 n][128 k]  (prescaled by log2e/2log2e)
#define WB_TOTAL 1044480

__device__ __forceinline__ float frcp_(float x) { return __builtin_amdgcn_rcpf(x); }
__device__ __forceinline__ float fexp2_(float x) { return __builtin_amdgcn_exp2f(x); }
__device__ __forceinline__ float b2f(unsigned short u) {
  union { unsigned int i; float f; } x; x.i = ((unsigned int)u) << 16; return x.f;
}
__device__ __forceinline__ unsigned short f2b(float f) {
  __hip_bfloat16 b = __float2bfloat16(f);
  return *reinterpret_cast<unsigned short*>(&b);
}
__device__ __forceinline__ unsigned short f2b_trunc(float f) {
  union { float f; unsigned int i; } x; x.f = f; return (unsigned short)(x.i >> 16);
}

// ---------------------------------------------------------------------------
// Weight prep: transpose/convert all weights into WB (bf16, [N][Kpad]).
// Wq prescaled by QSCALE; GRU weights prescaled by log2e (r,z) / 2log2e (n).
// ---------------------------------------------------------------------------
__global__ __launch_bounds__(256) void prep_kernel(
    const float* __restrict__ fc1W, const float* __restrict__ fc2W,
    const float* __restrict__ fc3W, const float* __restrict__ Wq,
    const float* __restrict__ Wk, const float* __restrict__ Wv,
    const float* __restrict__ Wd, const float* __restrict__ gWih,
    const float* __restrict__ gWhh, const float* __restrict__ gbih,
    const float* __restrict__ bq, unsigned short* __restrict__ WB,
    float* __restrict__ gbihs, float* __restrict__ bqs) {
  for (int idx = blockIdx.x * 256 + threadIdx.x; idx < WB_TOTAL;
       idx += gridDim.x * 256) {
    float v;
    if (idx < WB_P2) {
      int n = idx / 320, k = idx % 320;
      v = (k < 300) ? fc1W[k * 128 + n] : 0.f;
    } else if (idx < WB_P3) {
      int r = idx - WB_P2; int n = r >> 6, k = r & 63;
      v = (k < 35) ? fc2W[k * 128 + n] : 0.f;
    } else if (idx < WB_QKVD) {
      int r = idx - WB_P3; int n = r / 96, k = r % 96;
      v = (k < 74) ? fc3W[k * 128 + n] : 0.f;
    } else if (idx < WB_WIH) {
      int r = idx - WB_QKVD;
      int op = r / 98304; int r2 = r % 98304;
      int u = r2 >> 14; int r3 = r2 & 16383;
      int n = r3 >> 7, k = r3 & 127;
      const float* src = (op == 0) ? Wq : (op == 1) ? Wk : (op == 2) ? Wv : Wd;
      v = src[u * 16384 + k * 128 + n];
      if (op == 0) v *= QSCALE;
    } else if (idx < WB_WHH) {
      int r = idx - WB_WIH;
      int r3 = r % 49152;  // within rec: [384 n][128 k]
      int gate = (r3 >> 7) >> 7;
      v = gWih[r] * (gate < 2 ? LOG2E : 2.f * LOG2E);
    } else {
      int r = idx - WB_WHH;
      int r3 = r % 49152;
      int gate = (r3 >> 7) >> 7;
      v = gWhh[r] * (gate < 2 ? LOG2E : 2.f * LOG2E);
    }
    WB[idx] = f2b(v);
  }
  for (int idx = blockIdx.x * 256 + threadIdx.x; idx < 6 * 384;
       idx += gridDim.x * 256) {
    int gate = (idx % 384) >> 7;
    gbihs[idx] = gbih[idx] * (gate < 2 ? LOG2E : 2.f * LOG2E);
  }
  for (int idx = blockIdx.x * 256 + threadIdx.x; idx < 6 * 128;
       idx += gridDim.x * 256) {
    bqs[idx] = bq[idx] * QSCALE;
  }
}

// ---------------------------------------------------------------------------
// Batched MFMA GEMM: C[32768, ...] = A[32768,Ka] @ W^T + bias, per blockIdx.z.
// Row-major C with column stride cs (128 normal, 384 for the GX gemm).
// All stores coalesced (consecutive lanes -> consecutive columns).
// ---------------------------------------------------------------------------
struct GArg {
  const void* A; const unsigned short* W; const float* bias; void* C;
  int Ka, Kp, abf, cbf, cs;
};
struct GArgs { GArg g[18]; };

__global__ __launch_bounds__(256) void gemm_b(GArgs args) {
  const GArg ga = args.g[blockIdx.z];
  const int ny = blockIdx.y;
  __shared__ unsigned short As[128 * 40];
  __shared__ unsigned short Ws[128 * 40];
  const int t = threadIdx.x;
  const int w = t >> 6, lane = t & 63, q = lane >> 4, lm = lane & 15;
  const int wm = w >> 1, wn = w & 1;
  const int m0 = blockIdx.x * 128;
  const int row = t >> 1, cb = (t & 1) * 16;
  f32x4 acc[4][4];
#pragma unroll
  for (int i = 0; i < 4; ++i)
#pragma unroll
    for (int j = 0; j < 4; ++j) acc[i][j] = (f32x4){0.f, 0.f, 0.f, 0.f};

  for (int kt = 0; kt < ga.Kp; kt += 32) {
    if (ga.abf) {
      const unsigned short* Ag =
          (const unsigned short*)ga.A + (size_t)(m0 + row) * ga.Ka + kt + cb;
      short8 v0 = *reinterpret_cast<const short8*>(Ag);
      short8 v1 = *reinterpret_cast<const short8*>(Ag + 8);
      *reinterpret_cast<short8*>(&As[row * 40 + cb]) = v0;
      *reinterpret_cast<short8*>(&As[row * 40 + cb + 8]) = v1;
    } else {
      const float* Ag = (const float*)ga.A + (size_t)(m0 + row) * ga.Ka + kt + cb;
      unsigned short tmp[16];
#pragma unroll
      for (int j = 0; j < 16; ++j) {
        int k = kt + cb + j;
        tmp[j] = (k < ga.Ka) ? f2b(Ag[j]) : 0;
      }
      *reinterpret_cast<short8*>(&As[row * 40 + cb]) =
          *reinterpret_cast<short8*>(&tmp[0]);
      *reinterpret_cast<short8*>(&As[row * 40 + cb + 8]) =
          *reinterpret_cast<short8*>(&tmp[8]);
    }
    {
      const unsigned short* Wg =
          ga.W + (size_t)(ny * 128 + row) * ga.Kp + kt + cb;
      short8 v0 = *reinterpret_cast<const short8*>(Wg);
      short8 v1 = *reinterpret_cast<const short8*>(Wg + 8);
      *reinterpret_cast<short8*>(&Ws[row * 40 + cb]) = v0;
      *reinterpret_cast<short8*>(&Ws[row * 40 + cb + 8]) = v1;
    }
    __syncthreads();
    short8 af[4], bfv[4];
#pragma unroll
    for (int mi = 0; mi < 4; ++mi)
      af[mi] = *reinterpret_cast<const short8*>(
          &As[(wm * 64 + mi * 16 + lm) * 40 + q * 8]);
#pragma unroll
    for (int ni = 0; ni < 4; ++ni)
      bfv[ni] = *reinterpret_cast<const short8*>(
          &Ws[(wn * 64 + ni * 16 + lm) * 40 + q * 8]);
#pragma unroll
    for (int mi = 0; mi < 4; ++mi)
#pragma unroll
      for (int ni = 0; ni < 4; ++ni)
        acc[mi][ni] = __builtin_amdgcn_mfma_f32_16x16x32_bf16(
            af[mi], bfv[ni], acc[mi][ni], 0, 0, 0);
    __syncthreads();
  }
#pragma unroll
  for (int ni = 0; ni < 4; ++ni) {
    const int colg = ny * 128 + wn * 64 + ni * 16 + lm;
    const float bv = ga.bias[colg];
#pragma unroll
    for (int mi = 0; mi < 4; ++mi) {
      const int rg = m0 + wm * 64 + mi * 16 + q * 4;
#pragma unroll
      for (int r = 0; r < 4; ++r) {
        float v = acc[mi][ni][r] + bv;
        if (ga.cbf)
          ((unsigned short*)ga.C)[(size_t)(rg + r) * ga.cs + colg] = f2b(v);
        else
          ((float*)ga.C)[(size_t)(rg + r) * ga.cs + colg] = v;
      }
    }
  }
}

// ---------------------------------------------------------------------------
// V column sums: VS[z][b][128] = sum_s V_z[b][s][:]   (V bf16)
// ---------------------------------------------------------------------------
__global__ __launch_bounds__(128) void vsum_kernel(
    const unsigned short* __restrict__ QKV, float* __restrict__ VS) {
  int b = blockIdx.x, z = blockIdx.y, d = threadIdx.x;
  const unsigned short* p = QKV + (size_t)(z * 3 + 2) * SZ + (size_t)b * SS * DD + d;
  float s = 0.f;
  for (int k = 0; k < SS; ++k) s += b2f(p[(size_t)k * DD]);
  VS[(z * BB + b) * DD + d] = s;
}

// ---------------------------------------------------------------------------
// MFMA attention v2 (probs = 1 - softmax): ctx = Vsum - softmax(QK^T/8) @ V.
// grid = (2 q-halves, 128 = b*2+h, 3 units), block = 256 (4 waves).
// Each block handles 4 q-tiles of 64 rows over all 512 keys: V staged once
// per k-tile (was 8x), K and V B-frags register-resident, reused across the
// 4 q-tiles.  Q/bq pre-scaled by 0.125*log2e -> raw exp2 probabilities.
// ---------------------------------------------------------------------------
__global__ __launch_bounds__(256) void attn2(
    const unsigned short* __restrict__ QKV, const float* __restrict__ VS,
    unsigned short* __restrict__ CTX) {
  __shared__ unsigned short Vt[64 * 72];       // [d][k ^ (d&56)]
  __shared__ unsigned short Pt[4][16 * 72];    // per-wave [q][k]
  const int t = threadIdx.x;
  const int w = t >> 6, lane = t & 63, quad = lane >> 4, lm = lane & 15;
  const int z = blockIdx.z;
  const int bh = blockIdx.y, b = bh >> 1, h = bh & 1;
  const int qbase = blockIdx.x * 256;

  const unsigned short* Qg = QKV + (size_t)(z * 3 + 0) * SZ;
  const unsigned short* Kg = QKV + (size_t)(z * 3 + 1) * SZ;
  const unsigned short* Vg = QKV + (size_t)(z * 3 + 2) * SZ;

  short8 aq[4][2];
#pragma unroll
  for (int qt = 0; qt < 4; ++qt)
#pragma unroll
    for (int c = 0; c < 2; ++c)
      aq[qt][c] = *reinterpret_cast<const short8*>(
          Qg + ((size_t)(b * SS + qbase + qt * 64 + w * 16 + lm)) * DD +
          h * 64 + c * 32 + quad * 8);

  f32x4 o[4][4];  // [qt][dt]
#pragma unroll
  for (int i = 0; i < 4; ++i)
#pragma unroll
    for (int j = 0; j < 4; ++j) o[i][j] = (f32x4){0.f, 0.f, 0.f, 0.f};
  float suml[4][4];  // [qt][r]
#pragma unroll
  for (int i = 0; i < 4; ++i)
#pragma unroll
    for (int j = 0; j < 4; ++j) suml[i][j] = 0.f;

  const int vk = t >> 3, vd0 = (t & 7) * 8;

  for (int kt = 0; kt < 8; ++kt) {
    const int k0 = kt * 64;
    __syncthreads();  // prior Vt fully consumed (bv regs read)
#pragma unroll
    for (int i = 0; i < 2; ++i) {
      const int k = vk + i * 32;
      short8 vv = *reinterpret_cast<const short8*>(
          Vg + ((size_t)(b * SS + k0 + k)) * DD + h * 64 + vd0);
#pragma unroll
      for (int j = 0; j < 8; ++j) {
        const int d = vd0 + j;
        Vt[d * 72 + (k ^ (d & 56))] = (unsigned short)vv[j];
      }
    }
    __syncthreads();

    // K fragments for this k-tile (reused across all 4 q-tiles)
    short8 bk[4][2];
#pragma unroll
    for (int nt = 0; nt < 4; ++nt)
#pragma unroll
      for (int c = 0; c < 2; ++c)
        bk[nt][c] = *reinterpret_cast<const short8*>(
            Kg + ((size_t)(b * SS + k0 + nt * 16 + lm)) * DD + h * 64 +
            c * 32 + quad * 8);
    // V B-fragments from swizzled LDS (reused across all 4 q-tiles)
    short8 bvv[4][2];
#pragma unroll
    for (int dt = 0; dt < 4; ++dt) {
      const int d = dt * 16 + lm;
#pragma unroll
      for (int c = 0; c < 2; ++c)
        bvv[dt][c] = *reinterpret_cast<const short8*>(
            &Vt[d * 72 + ((c * 32 + quad * 8) ^ (d & 56))]);
    }

#pragma unroll
    for (int qt = 0; qt < 4; ++qt) {
      f32x4 sacc[4];
#pragma unroll
      for (int nt = 0; nt < 4; ++nt) sacc[nt] = (f32x4){0.f, 0.f, 0.f, 0.f};
#pragma unroll
      for (int c = 0; c < 2; ++c)
#pragma unroll
        for (int nt = 0; nt < 4; ++nt)
          sacc[nt] = __builtin_amdgcn_mfma_f32_16x16x32_bf16(
              aq[qt][c], bk[nt][c], sacc[nt], 0, 0, 0);
#pragma unroll
      for (int nt = 0; nt < 4; ++nt) {
#pragma unroll
        for (int r = 0; r < 4; ++r) {
          float p = fexp2_(sacc[nt][r]);
          suml[qt][r] += p;
          Pt[w][(quad * 4 + r) * 72 + nt * 16 + lm] = f2b_trunc(p);
        }
      }
#pragma unroll
      for (int c = 0; c < 2; ++c) {
        short8 ap = *reinterpret_cast<const short8*>(
            &Pt[w][lm * 72 + c * 32 + quad * 8]);
#pragma unroll
        for (int dt = 0; dt < 4; ++dt)
          o[qt][dt] = __builtin_amdgcn_mfma_f32_16x16x32_bf16(
              ap, bvv[dt][c], o[qt][dt], 0, 0, 0);
      }
    }
  }
#pragma unroll
  for (int qt = 0; qt < 4; ++qt)
#pragma unroll
    for (int r = 0; r < 4; ++r) {
#pragma unroll
      for (int m = 1; m < 16; m <<= 1)
        suml[qt][r] += __shfl_xor(suml[qt][r], m);
    }
  const float* vsp = VS + (size_t)(z * BB + b) * DD + h * 64;
#pragma unroll
  for (int qt = 0; qt < 4; ++qt)
#pragma unroll
    for (int dt = 0; dt < 4; ++dt) {
      const int col = dt * 16 + lm;
      const float vs = vsp[col];
#pragma unroll
      for (int r = 0; r < 4; ++r) {
        const int row = qbase + qt * 64 + w * 16 + quad * 4 + r;
        CTX[(size_t)z * SZ + ((size_t)(b * SS + row)) * DD + h * 64 + col] =
            f2b(vs - o[qt][dt][r] * frcp_(suml[qt][r]));
      }
    }
}

// ---------------------------------------------------------------------------
// Fused LN pair, 4 rows/block (1 wave per row).
// ---------------------------------------------------------------------------
__global__ __launch_bounds__(256) void ln_pair(
    const unsigned short* __restrict__ DOUT, const float* __restrict__ lng,
    const float* __restrict__ lnb, unsigned short* __restrict__ GRUIN) {
  const int g = blockIdx.y;
  const int row = blockIdx.x * 4 + (threadIdx.x >> 6);
  const int t = threadIdx.x & 63;
  const int u1t[3] = {1, 2, 0};
  const int u2t[3] = {3, 5, 4};
  float outA = 0.f, outB = 0.f;
#pragma unroll
  for (int half = 0; half < 2; ++half) {
    const int u = half == 0 ? u1t[g] : u2t[g];
    const unsigned short* x = DOUT + (size_t)u * SZ + (size_t)row * DD;
    float a = b2f(x[t]), c = b2f(x[t + 64]);
    float s = a + c, sq = a * a + c * c;
#pragma unroll
    for (int off = 32; off > 0; off >>= 1) {
      s += __shfl_down(s, off);
      sq += __shfl_down(sq, off);
    }
    s = __shfl(s, 0); sq = __shfl(sq, 0);
    float mean = s * (1.f / 128.f);
    float var = sq * (1.f / 128.f) - mean * mean;
    float rs = rsqrtf(var + 1e-5f);
    const float* gg = lng + u * 128;
    const float* bb = lnb + u * 128;
    outA += (a - mean) * rs * gg[t] + bb[t];
    outB += (c - mean) * rs * gg[t + 64] + bb[t + 64];
  }
  unsigned short* op = GRUIN + (size_t)g * SZ + (size_t)row * DD;
  op[t] = f2b(0.5f * outA);
  op[t + 64] = f2b(0.5f * outB);
}

// ---------------------------------------------------------------------------
// GRU v8: reads row-major GXR directly (coalesced 32-B-per-quad gate loads,
// ring prefetch 4 ahead; lgkm-only barrier keeps them in flight).  Direction
// handled by a signed row stride.  MFMA chains split 2+2; rcp/exp2 gates.
// grid = (16 bg, 6 rec), block = 512 (8 waves).  batch <-> quad, A-row 4q.
// ---------------------------------------------------------------------------
#define AST 136

__global__ __launch_bounds__(512, 1) void gru6(
    const unsigned short* __restrict__ GXR, const unsigned short* __restrict__ WB,
    const float* __restrict__ gbhh, float* __restrict__ HS) {
  __shared__ unsigned short Abuf[2][16 * AST];
  const int rec = blockIdx.y, bg = blockIdx.x;
  const int dir = rec & 1;
  const int t = threadIdx.x;
  const int w = t >> 6, lane = t & 63, q = lane >> 4, lm = lane & 15;
  const int o = w * 16 + lm;
  const int b = bg * 4 + q;

  short8 Bh[3][4];
  const unsigned short* whh = WB + WB_WHH + (size_t)rec * 49152;
#pragma unroll
  for (int gate = 0; gate < 3; ++gate)
#pragma unroll
    for (int c = 0; c < 4; ++c)
      Bh[gate][c] = *reinterpret_cast<const short8*>(
          whh + (size_t)(gate * 128 + o) * 128 + c * 32 + q * 8);
  const float br = gbhh[rec * 384 + o] * LOG2E;
  const float bz = gbhh[rec * 384 + 128 + o] * LOG2E;
  const float bhn = gbhh[rec * 384 + 256 + o] * (2.f * LOG2E);

  float h = 0.f, hsum = 0.f;
  for (int i = t; i < 2 * 16 * AST; i += 512)
    (&Abuf[0][0])[i] = 0;

  // gx: 3 ushort loads/step from GXR[rec][b*512 + tt][384] at cols g*128+o.
  // tt = dir ? 511-s : s  ->  base + s*st with signed stride st.
  const unsigned short* gx0 = GXR + (size_t)rec * 12582912 +
      ((size_t)b * 512 + (dir ? 511 : 0)) * 384 + o;
  const ptrdiff_t st = dir ? -384 : 384;

  unsigned short ring[4][3];
#pragma unroll
  for (int pp = 0; pp < 4; ++pp) {
    const unsigned short* gp = gx0 + (ptrdiff_t)pp * st;
#pragma unroll
    for (int j = 0; j < 3; ++j) ring[pp][j] = gp[j * 128];
  }
  __syncthreads();

#pragma unroll 4
  for (int s = 0; s < SS; ++s) {
    const int p = s & 1, slot = s & 3;
    const float gxr = b2f(ring[slot][0]);
    const float gxz = b2f(ring[slot][1]);
    const float gxn = b2f(ring[slot][2]);
    // prefetch step s+4 (clamped)
    int sp = s + 4; if (sp > SS - 1) sp = SS - 1;
    const unsigned short* gp = gx0 + (ptrdiff_t)sp * st;
#pragma unroll
    for (int j = 0; j < 3; ++j) ring[slot][j] = gp[j * 128];

    short8 ah0 = *reinterpret_cast<const short8*>(&Abuf[p][lm * AST + 0 + q * 8]);
    short8 ah1 = *reinterpret_cast<const short8*>(&Abuf[p][lm * AST + 32 + q * 8]);
    short8 ah2 = *reinterpret_cast<const short8*>(&Abuf[p][lm * AST + 64 + q * 8]);
    short8 ah3 = *reinterpret_cast<const short8*>(&Abuf[p][lm * AST + 96 + q * 8]);
    f32x4 r0 = {br, 0.f, 0.f, 0.f}, r1 = {0.f, 0.f, 0.f, 0.f};
    f32x4 z0 = {bz, 0.f, 0.f, 0.f}, z1 = {0.f, 0.f, 0.f, 0.f};
    f32x4 n0 = {bhn, 0.f, 0.f, 0.f}, n1 = {0.f, 0.f, 0.f, 0.f};
    r0 = __builtin_amdgcn_mfma_f32_16x16x32_bf16(ah0, Bh[0][0], r0, 0, 0, 0);
    r1 = __builtin_amdgcn_mfma_f32_16x16x32_bf16(ah2, Bh[0][2], r1, 0, 0, 0);
    z0 = __builtin_amdgcn_mfma_f32_16x16x32_bf16(ah0, Bh[1][0], z0, 0, 0, 0);
    z1 = __builtin_amdgcn_mfma_f32_16x16x32_bf16(ah2, Bh[1][2], z1, 0, 0, 0);
    n0 = __builtin_amdgcn_mfma_f32_16x16x32_bf16(ah0, Bh[2][0], n0, 0, 0, 0);
    n1 = __builtin_amdgcn_mfma_f32_16x16x32_bf16(ah2, Bh[2][2], n1, 0, 0, 0);
    r0 = __builtin_amdgcn_mfma_f32_16x16x32_bf16(ah1, Bh[0][1], r0, 0, 0, 0);
    r1 = __builtin_amdgcn_mfma_f32_16x16x32_bf16(ah3, Bh[0][3], r1, 0, 0, 0);
    z0 = __builtin_amdgcn_mfma_f32_16x16x32_bf16(ah1, Bh[1][1], z0, 0, 0, 0);
    z1 = __builtin_amdgcn_mfma_f32_16x16x32_bf16(ah3, Bh[1][3], z1, 0, 0, 0);
    n0 = __builtin_amdgcn_mfma_f32_16x16x32_bf16(ah1, Bh[2][1], n0, 0, 0, 0);
    n1 = __builtin_amdgcn_mfma_f32_16x16x32_bf16(ah3, Bh[2][3], n1, 0, 0, 0);

    float rr = frcp_(1.f + fexp2_(-(gxr + r0[0] + r1[0])));
    float zz = frcp_(1.f + fexp2_(-(gxz + z0[0] + z1[0])));
    float nn = 1.f - 2.f * frcp_(fexp2_(gxn + rr * (n0[0] + n1[0])) + 1.f);
    h = nn + zz * (h - nn);
    hsum += h;
    Abuf[p ^ 1][(q * 4) * AST + o] = f2b_trunc(h);
    asm volatile("s_waitcnt lgkmcnt(0)\n\ts_barrier" ::: "memory");
  }
  HS[((size_t)rec * BB + bg * 4 + q) * 128 + o] = hsum;
}

// ---------------------------------------------------------------------------
// Head: pooled -> Linear -> BN(eval) -> ReLU6 -> Linear.  grid=64, block=256.
// ---------------------------------------------------------------------------
__global__ __launch_bounds__(256) void head_kernel(
    const float* __restrict__ HS, const float* __restrict__ fW1,
    const float* __restrict__ fb1, const float* __restrict__ bng,
    const float* __restrict__ bnb, const float* __restrict__ fW2,
    const float* __restrict__ fb2, float* __restrict__ out) {
  __shared__ float pl[384];
  __shared__ float h1[256];
  int b = blockIdx.x, n = threadIdx.x;
  {
    int j = n;
    int seg = j >> 7, oo = j & 127;
    pl[j] = (HS[((size_t)seg * BB + b) * 128 + oo] +
             HS[((size_t)(seg + 3) * BB + b) * 128 + oo]) * (0.5f / 512.f);
  }
  if (n < 128) {
    int j = 256 + n;
    int seg = j >> 7, oo = j & 127;
    pl[j] = (HS[((size_t)seg * BB + b) * 128 + oo] +
             HS[((size_t)(seg + 3) * BB + b) * 128 + oo]) * (0.5f / 512.f);
  }
  __syncthreads();
  float acc = fb1[n];
  for (int k = 0; k < 384; ++k) acc += pl[k] * fW1[k * 256 + n];
  float hv = acc * rsqrtf(1.f + 1e-5f) * bng[n] + bnb[n];
  hv = fminf(fmaxf(hv, 0.f), 6.f);
  h1[n] = hv;
  __syncthreads();
  if (n < 8) {
    float a2 = fb2[n];
    for (int k = 0; k < 256; ++k) a2 += h1[k] * fW2[k * 8 + n];
    out[b * 8 + n] = a2;
  }
}

// ---------------------------------------------------------------------------
extern "C" void kernel_launch(void* const* d_in, const int* in_sizes, int n_in,
                              void* d_out, int out_size, void* d_ws,
                              size_t ws_size, hipStream_t stream) {
  (void)in_sizes; (void)n_in; (void)out_size; (void)ws_size;
  const float* text = (const float*)d_in[0];
  const float* vis  = (const float*)d_in[1];
  const float* aud  = (const float*)d_in[2];
  const float* fc1W = (const float*)d_in[3];
  const float* fc1b = (const float*)d_in[4];
  const float* fc2W = (const float*)d_in[5];
  const float* fc2b = (const float*)d_in[6];
  const float* fc3W = (const float*)d_in[7];
  const float* fc3b = (const float*)d_in[8];
  const float* Wq = (const float*)d_in[9];
  const float* bq = (const float*)d_in[10];
  const float* Wk = (const float*)d_in[11];
  const float* bk = (const float*)d_in[12];
  const float* Wv = (const float*)d_in[13];
  const float* bv = (const float*)d_in[14];
  const float* Wd = (const float*)d_in[15];
  const float* bd = (const float*)d_in[16];
  const float* lng = (const float*)d_in[17];
  const float* lnb = (const float*)d_in[18];
  const float* gWih = (const float*)d_in[19];
  const float* gWhh = (const float*)d_in[20];
  const float* gbih = (const float*)d_in[21];
  const float* gbhh = (const float*)d_in[22];
  const float* fW1 = (const float*)d_in[23];
  const float* fb1 = (const float*)d_in[24];
  const float* bng = (const float*)d_in[25];
  const float* bnb = (const float*)d_in[26];
  const float* fW2 = (const float*)d_in[27];
  const float* fb2 = (const float*)d_in[28];
  float* out = (float*)d_out;

  unsigned short* WSB = (unsigned short*)d_ws;
  unsigned short* T   = WSB;
  unsigned short* Vv  = WSB + SZ;
  unsigned short* Aa  = WSB + 2 * SZ;
  unsigned short* QKV = WSB + 3 * SZ;
  unsigned short* CTX = WSB + 12 * SZ;
  unsigned short* DOUT = WSB;
  unsigned short* GXR = WSB;              // slices 0..17 ([6][32768][384])
  unsigned short* GRUIN = WSB + 18 * SZ;  // slices 18..20
  unsigned short* WB  = WSB + 21 * SZ;
  float* VS = (float*)(WSB + 21 * SZ + 1048576);
  float* HS = VS + 6 * 64 * 128;
  float* gbihs = HS + 6 * 64 * 128;       // 2304 floats
  float* bqs = gbihs + 6 * 384;           // 768 floats

  prep_kernel<<<dim3(1024), dim3(256), 0, stream>>>(
      fc1W, fc2W, fc3W, Wq, Wk, Wv, Wd, gWih, gWhh, gbih, bq, WB, gbihs, bqs);

  {
    GArgs ga{};
    ga.g[0] = {text, WB + WB_P1, fc1b, T, 300, 320, 0, 1, 128};
    ga.g[1] = {vis,  WB + WB_P2, fc2b, Vv, 35, 64, 0, 1, 128};
    ga.g[2] = {aud,  WB + WB_P3, fc3b, Aa, 74, 96, 0, 1, 128};
    gemm_b<<<dim3(256, 1, 3), dim3(256), 0, stream>>>(ga);
  }

  const int qsel[6] = {0, 2, 0, 1, 1, 2};
  const int ksel[6] = {2, 0, 1, 0, 2, 1};
  unsigned short* proj[3] = {T, Vv, Aa};

  for (int phase = 0; phase < 2; ++phase) {
    GArgs ga{};
    for (int ul = 0; ul < 3; ++ul) {
      int u = phase * 3 + ul;
      for (int op = 0; op < 3; ++op) {
        int z = ul * 3 + op;
        const float* bias = (op == 0) ? (bqs + u * 128)
                          : (op == 1) ? (bk + u * 128) : (bv + u * 128);
        ga.g[z] = {proj[op == 0 ? qsel[u] : ksel[u]],
                   WB + WB_QKVD + op * 98304 + u * 16384, bias,
                   QKV + (size_t)z * SZ, 128, 128, 1, 1, 128};
      }
    }
    gemm_b<<<dim3(256, 1, 9), dim3(256), 0, stream>>>(ga);
    vsum_kernel<<<dim3(BB, 3), dim3(128), 0, stream>>>(QKV, VS + phase * 3 * BB * DD);
    attn2<<<dim3(2, 128, 3), dim3(256), 0, stream>>>(
        QKV, VS + phase * 3 * BB * DD, CTX + (size_t)phase * 3 * SZ);
  }

  {
    GArgs ga{};
    for (int u = 0; u < 6; ++u)
      ga.g[u] = {CTX + (size_t)u * SZ, WB + WB_QKVD + 3 * 98304 + u * 16384,
                 bd + u * 128, DOUT + (size_t)u * SZ, 128, 128, 1, 1, 128};
    gemm_b<<<dim3(256, 1, 6), dim3(256), 0, stream>>>(ga);
  }

  ln_pair<<<dim3(NROW / 4, 3), dim3(256), 0, stream>>>(DOUT, lng, lnb, GRUIN);

  // gx = GRUIN[g] @ Wih[rec]^T + gbih_scaled[rec] -> row-major GXR (coalesced)
  {
    GArgs ga{};
    for (int r6 = 0; r6 < 6; ++r6) {
      int g = r6 >> 1;
      ga.g[r6] = {GRUIN + (size_t)g * SZ, WB + WB_WIH + r6 * 49152,
                  gbihs + r6 * 384, GXR + (size_t)r6 * 12582912,
                  128, 128, 1, 1, 384};
    }
    gemm_b<<<dim3(256, 3, 6), dim3(256), 0, stream>>>(ga);
  }

  gru6<<<dim3(16, 6), dim3(512), 0, stream>>>(GXR, WB, gbhh, HS);
  head_kernel<<<dim3(BB), dim3(256), 0, stream>>>(HS, fW1, fb1, bng, bnb, fW2, fb2, out);
}